// Round 1
// baseline (2362.591 us; speedup 1.0000x reference)
//
#include <hip/hip_runtime.h>
#include <math.h>
#include <stddef.h>

// ---------------------------------------------------------------------------
// BiDiGemma forward, fp32 correctness-first implementation.
// B=4 S=4096 D=256 H=4 HD=64 E=768 W_ATT=256 TW=4
// ---------------------------------------------------------------------------

#define BB   4
#define SS   4096
#define DD   256
#define HH   4
#define HDIM 64
#define EE   768
#define RR   (BB*SS)      // 16384 rows per branch pass
#define WNN  256          // attention window / chunk
#define CH   64           // scan chunk length
#define NCH  (SS/CH)      // 64 chunks per sequence

__device__ __forceinline__ float geluf(float x){
  return 0.5f*x*(1.0f + erff(x*0.70710678118654752f));
}
__device__ __forceinline__ float sigm(float x){ return 1.0f/(1.0f+expf(-x)); }

__device__ __forceinline__ float wredSum(float v){
#pragma unroll
  for(int o=32;o>0;o>>=1) v += __shfl_xor(v,o,64);
  return v;
}

// ---------------------------------------------------------------------------
// LayerNorm(skip) -> out ; z = sigmoid(mean(silu(skip)))   (one wave per row)
// ---------------------------------------------------------------------------
__global__ __launch_bounds__(256) void ln_z_k(const float* __restrict__ skip,
    const float* __restrict__ g, const float* __restrict__ b,
    float* __restrict__ out, float* __restrict__ z)
{
  int row  = blockIdx.x*4 + (threadIdx.x>>6);
  int lane = threadIdx.x & 63;
  float4 v = ((const float4*)(skip + (size_t)row*DD))[lane];
  float s  = v.x+v.y+v.z+v.w;
  float sq = v.x*v.x+v.y*v.y+v.z*v.z+v.w*v.w;
  float si = v.x*sigm(v.x)+v.y*sigm(v.y)+v.z*sigm(v.z)+v.w*sigm(v.w);
  s = wredSum(s); sq = wredSum(sq); si = wredSum(si);
  float mean = s*(1.0f/DD);
  float var  = sq*(1.0f/DD) - mean*mean;
  float inv  = rsqrtf(var + 1e-5f);
  float4 gv = ((const float4*)g)[lane];
  float4 bv = ((const float4*)b)[lane];
  float4 o;
  o.x = (v.x-mean)*inv*gv.x + bv.x;
  o.y = (v.y-mean)*inv*gv.y + bv.y;
  o.z = (v.z-mean)*inv*gv.z + bv.z;
  o.w = (v.w-mean)*inv*gv.w + bv.w;
  ((float4*)(out + (size_t)row*DD))[lane] = o;
  if(lane==0) z[row] = sigm(si*(1.0f/DD));
}

// ---------------------------------------------------------------------------
// RMSNorm: out = x * rsqrt(mean(x^2)+1e-6) * (1+t)
// ---------------------------------------------------------------------------
__global__ __launch_bounds__(256) void rms_k(const float* __restrict__ x,
    const float* __restrict__ t, float* __restrict__ out)
{
  int row  = blockIdx.x*4 + (threadIdx.x>>6);
  int lane = threadIdx.x & 63;
  float4 v = ((const float4*)(x + (size_t)row*DD))[lane];
  float sq = v.x*v.x+v.y*v.y+v.z*v.z+v.w*v.w;
  sq = wredSum(sq);
  float inv = rsqrtf(sq*(1.0f/DD) + 1e-6f);
  float4 tv = ((const float4*)t)[lane];
  float4 o;
  o.x = v.x*inv*(1.0f+tv.x);
  o.y = v.y*inv*(1.0f+tv.y);
  o.z = v.z*inv*(1.0f+tv.z);
  o.w = v.w*inv*(1.0f+tv.w);
  ((float4*)(out + (size_t)row*DD))[lane] = o;
}

// ---------------------------------------------------------------------------
// fp32 GEMM: C = op(A @ B + bias [+ Res]), A [M,K] row-major, B [K,N] row-major.
// BM=128, BN in {128,64}. 256 threads, 8 rows x (BN/16) cols per thread.
// MODE bits: 1=bias0, 2=gelu, 4=A elementwise-multiplied by A2, 8=+Res.
// DUAL=1 (BN=64 only): C = gelu(A@B0+bias0) * (A@B1+bias1)   (MLP up).
// blockIdx.z batching (block-diagonal linear): base offsets bat{A,B,C,Bias}.
// LDS: A stored k-major with scalar scatter so compute reads are b128,
// conflict-free (<=2-way); B k-major rows, f4 col reads split in 64-halves.
// ---------------------------------------------------------------------------
template<int BN, int MODE, int DUAL>
__global__ __launch_bounds__(256) void gemm_k(
    const float* __restrict__ A, const float* __restrict__ A2,
    const float* __restrict__ B0, const float* __restrict__ B1,
    const float* __restrict__ bias0, const float* __restrict__ bias1,
    const float* __restrict__ Res, float* __restrict__ C,
    int M, int N, int K, int lda, int ldb, int ldc,
    int batA, int batB, int batC, int batBias)
{
  constexpr int BK = 16;
  constexpr int TN = BN/16;   // 8 or 4
  constexpr int NH = BN/64;   // 2 or 1
  __shared__ float Ask[BK][132];
  __shared__ float Bs [BK][BN+4];
  __shared__ float Bs2[DUAL?BK:1][DUAL?(BN+4):4];

  const int bz = blockIdx.z;
  const float* Ab  = A  + (size_t)bz*batA;
  const float* A2b = (MODE&4) ? (A2 + (size_t)bz*batA) : (const float*)nullptr;
  const float* Bb  = B0 + (size_t)bz*batB;
  float* Cb = C + (size_t)bz*batC;

  const int bm = blockIdx.y*128, bn = blockIdx.x*BN;
  const int tid = threadIdx.x;
  const int tx = tid & 15, ty = tid >> 4;
  const int ar = tid >> 1, ac = (tid & 1)*8;
  const int br = tid >> 4;

  float acc[8][TN];
  float acc2[DUAL?8:1][DUAL?TN:1];
#pragma unroll
  for(int i=0;i<8;i++)
#pragma unroll
    for(int j=0;j<TN;j++) acc[i][j]=0.f;
  if(DUAL){
#pragma unroll
    for(int i=0;i<(DUAL?8:1);i++)
#pragma unroll
      for(int j=0;j<(DUAL?TN:1);j++) acc2[i][j]=0.f;
  }

  for(int k0=0;k0<K;k0+=BK){
#pragma unroll
    for(int hf=0;hf<2;hf++){
      float4 av = *(const float4*)(Ab + (size_t)(bm+ar)*lda + (k0+ac+hf*4));
      if(MODE&4){
        float4 a2 = *(const float4*)(A2b + (size_t)(bm+ar)*lda + (k0+ac+hf*4));
        av.x*=a2.x; av.y*=a2.y; av.z*=a2.z; av.w*=a2.w;
      }
      Ask[ac+hf*4+0][ar]=av.x; Ask[ac+hf*4+1][ar]=av.y;
      Ask[ac+hf*4+2][ar]=av.z; Ask[ac+hf*4+3][ar]=av.w;
    }
    if(BN==128){
      const int bc = (tid&15)*8;
#pragma unroll
      for(int hf=0;hf<2;hf++)
        *(float4*)&Bs[br][bc+hf*4] = *(const float4*)(Bb + (size_t)(k0+br)*ldb + (bn+bc+hf*4));
    } else {
      const int bc = (tid&15)*4;
      *(float4*)&Bs[br][bc] = *(const float4*)(Bb + (size_t)(k0+br)*ldb + (bn+bc));
      if(DUAL)
        *(float4*)&Bs2[br][bc] = *(const float4*)(B1 + (size_t)(k0+br)*ldb + (bn+bc));
    }
    __syncthreads();
#pragma unroll
    for(int k=0;k<BK;k++){
      float a[8];
      *(float4*)&a[0] = *(const float4*)&Ask[k][ty*8];
      *(float4*)&a[4] = *(const float4*)&Ask[k][ty*8+4];
      float bv[TN];
#pragma unroll
      for(int hh=0;hh<NH;hh++)
        *(float4*)&bv[hh*4] = *(const float4*)&Bs[k][hh*64 + tx*4];
#pragma unroll
      for(int i=0;i<8;i++)
#pragma unroll
        for(int j=0;j<TN;j++)
          acc[i][j] = fmaf(a[i], bv[j], acc[i][j]);
      if(DUAL){
        float b2[TN];
        *(float4*)&b2[0] = *(const float4*)&Bs2[k][tx*4];
#pragma unroll
        for(int i=0;i<8;i++)
#pragma unroll
          for(int j=0;j<TN;j++)
            acc2[i][j] = fmaf(a[i], b2[j], acc2[i][j]);
      }
    }
    __syncthreads();
  }

#pragma unroll
  for(int i=0;i<8;i++){
    const int row = bm + ty*8 + i;
#pragma unroll
    for(int hh=0;hh<NH;hh++){
      const int col = bn + hh*64 + tx*4;
      float v0=acc[i][hh*4+0], v1=acc[i][hh*4+1], v2=acc[i][hh*4+2], v3=acc[i][hh*4+3];
      if(MODE&1){
        float4 bbv = *(const float4*)(bias0 + (size_t)bz*batBias + col);
        v0+=bbv.x; v1+=bbv.y; v2+=bbv.z; v3+=bbv.w;
      }
      if(DUAL){
        float4 b2v = *(const float4*)(bias1 + col);
        float w0=acc2[i][0]+b2v.x, w1=acc2[i][1]+b2v.y, w2=acc2[i][2]+b2v.z, w3=acc2[i][3]+b2v.w;
        v0=geluf(v0)*w0; v1=geluf(v1)*w1; v2=geluf(v2)*w2; v3=geluf(v3)*w3;
      } else if(MODE&2){
        v0=geluf(v0); v1=geluf(v1); v2=geluf(v2); v3=geluf(v3);
      }
      if(MODE&8){
        float4 rv = *(const float4*)(Res + (size_t)bz*batC + (size_t)row*ldc + col);
        v0+=rv.x; v1+=rv.y; v2+=rv.z; v3+=rv.w;
      }
      float4 ov; ov.x=v0; ov.y=v1; ov.z=v2; ov.w=v3;
      *(float4*)(Cb + (size_t)row*ldc + col) = ov;
    }
  }
}

// ---------------------------------------------------------------------------
// Depthwise causal conv1d, width 4, w[3] multiplies current token.
// ---------------------------------------------------------------------------
__global__ __launch_bounds__(256) void conv_k(const float* __restrict__ x,
    const float* __restrict__ w, const float* __restrict__ b, float* __restrict__ out)
{
  int idx = blockIdx.x*256 + threadIdx.x;   // < RR*DD
  int d = idx & (DD-1);
  int r = idx >> 8;
  int s = r & (SS-1);
  float acc = b[d];
#pragma unroll
  for(int i=0;i<4;i++){
    int t = s - 3 + i;
    if(t >= 0) acc += w[i*DD + d] * x[(size_t)(r-3+i)*DD + d];
  }
  out[idx] = acc;
}

// ---------------------------------------------------------------------------
// RG-LRU gates: in-place ig<-a, ag<-bterm.  x = conv output.
// ---------------------------------------------------------------------------
__global__ __launch_bounds__(256) void gate_k(const float* __restrict__ x,
    float* __restrict__ ig, float* __restrict__ ag, const float* __restrict__ ap)
{
  int idx = blockIdx.x*256 + threadIdx.x;
  int d = idx & (DD-1);
  int r = idx >> 8;
  int s = r & (SS-1);
  float gx = sigm(ig[idx]);
  float ga = sigm(ag[idx]);
  float a_ = ap[d];
  float sp = (a_ > 20.f) ? a_ : log1pf(expf(a_));
  float la = -8.f * ga * sp;
  float a  = expf(la);
  float mult = (s==0) ? 1.f : sqrtf(fmaxf(-expm1f(2.f*la), 0.f));
  float bt = x[idx] * gx * mult;
  ig[idx] = a;
  ag[idx] = bt;
}

// ---------------------------------------------------------------------------
// Blocked linear-recurrence scan: h_t = a_t*h_{t-1} + b_t   (per b,d channel)
// ---------------------------------------------------------------------------
__global__ __launch_bounds__(256) void scan1_k(const float* __restrict__ A,
    const float* __restrict__ Bv, float* __restrict__ csa, float* __restrict__ csb)
{
  int idx = blockIdx.x*256 + threadIdx.x;   // < BB*NCH*DD
  int d = idx & (DD-1);
  int c = (idx >> 8) & (NCH-1);
  int b = idx >> 14;
  size_t base = ((size_t)b*SS + (size_t)c*CH)*DD + d;
  float Aa = 1.f, Bb_ = 0.f;
  for(int t=0;t<CH;t++){
    float a  = A [base + (size_t)t*DD];
    float bb = Bv[base + (size_t)t*DD];
    Aa  = a*Aa;
    Bb_ = a*Bb_ + bb;
  }
  csa[idx] = Aa; csb[idx] = Bb_;
}

__global__ __launch_bounds__(256) void scan2_k(const float* __restrict__ csa,
    float* __restrict__ csb)
{
  int idx = blockIdx.x*256 + threadIdx.x;   // < BB*DD
  int d = idx & (DD-1);
  int b = idx >> 8;
  float h = 0.f;
  for(int c=0;c<NCH;c++){
    size_t i = ((size_t)b*NCH + c)*DD + d;
    float Aa = csa[i], Bb_ = csb[i];
    csb[i] = h;            // exclusive carry-in for chunk c
    h = Aa*h + Bb_;
  }
}

__global__ __launch_bounds__(256) void scan3_k(const float* __restrict__ A,
    float* __restrict__ Bv, const float* __restrict__ csb)
{
  int idx = blockIdx.x*256 + threadIdx.x;
  int d = idx & (DD-1);
  int c = (idx >> 8) & (NCH-1);
  int b = idx >> 14;
  size_t base = ((size_t)b*SS + (size_t)c*CH)*DD + d;
  float h = csb[idx];
  for(int t=0;t<CH;t++){
    float a  = A [base + (size_t)t*DD];
    float bb = Bv[base + (size_t)t*DD];
    h = a*h + bb;
    Bv[base + (size_t)t*DD] = h;
  }
}

// ---------------------------------------------------------------------------
// Partial RoPE (first 32 of 64 dims) + 1/sqrt(HD) scale for Q.
// ---------------------------------------------------------------------------
__global__ __launch_bounds__(256) void rope_q_k(float* __restrict__ q)
{
  int idx = blockIdx.x*256 + threadIdx.x;   // < RR*HH*16
  int p = idx & 15;
  int h = (idx>>4) & 3;
  int r = idx >> 6;
  int s = r & (SS-1);
  float inv = expf(-(float)p * 0.575646273248511f);  // ln(10000)/16
  float t = (float)s * inv;
  float sn, cs; __sincosf(t, &sn, &cs);
  float* base = q + (size_t)r*DD + h*HDIM;
  float x1 = base[p], x2 = base[p+16];
  const float sc = 0.125f;                 // HD^-0.5
  base[p]    = (x1*cs - x2*sn)*sc;
  base[p+16] = (x2*cs + x1*sn)*sc;
  base[p+32] *= sc;
  base[p+48] *= sc;
}

__global__ __launch_bounds__(256) void rope_k_k(float* __restrict__ kk)
{
  int idx = blockIdx.x*256 + threadIdx.x;   // < RR*16
  int p = idx & 15;
  int r = idx >> 4;
  int s = r & (SS-1);
  float inv = expf(-(float)p * 0.575646273248511f);
  float t = (float)s * inv;
  float sn, cs; __sincosf(t, &sn, &cs);
  float* base = kk + (size_t)r*HDIM;
  float x1 = base[p], x2 = base[p+16];
  base[p]    = x1*cs - x2*sn;
  base[p+16] = x2*cs + x1*sn;
}

// ---------------------------------------------------------------------------
// Sliding-window MQA attention (flash-style), 64 q-rows per block.
// grid: (nb*4, H, B). Only k-tiles [max(qt, 4 if n==0), qt+4] are visited.
// LDS tiles XOR-swizzled: elem (r,d) at r*64 + ((d/4 ^ (r&15))*4 + d%4).
// ---------------------------------------------------------------------------
__device__ __forceinline__ int sw4(int r, int g){ return r*64 + (((g ^ (r & 15)) & 15) << 2); }

__global__ __launch_bounds__(256) void attn_k(const float* __restrict__ Q,
    const float* __restrict__ K, const float* __restrict__ V, float* __restrict__ O)
{
  __shared__ float Qs[64*64];
  __shared__ float Ks[64*64];   // reused for V
  __shared__ float Ps[64*64];
  int qt = blockIdx.x & 3, n = blockIdx.x >> 2;
  int h = blockIdx.y, b = blockIdx.z;
  int tid = threadIdx.x, tx = tid & 15, ty = tid >> 4;
  int s0 = n*WNN + qt*64;

#pragma unroll
  for(int rep=0; rep<4; rep++){
    int f4i = rep*256 + tid;
    int r = f4i >> 4, g = f4i & 15;
    *(float4*)&Qs[sw4(r,g)] =
      *(const float4*)(Q + ((size_t)(b*SS + s0 + r))*DD + h*HDIM + g*4);
  }

  float m[4], l[4], o[4][4];
#pragma unroll
  for(int i=0;i<4;i++){ m[i]=-3.0e38f; l[i]=0.f;
#pragma unroll
    for(int j=0;j<4;j++) o[i][j]=0.f; }

  int ktlo = (n==0) ? 4 : qt;
  int kthi = qt + 4;
  for(int kt=ktlo; kt<=kthi; kt++){
    int kbase = (n-1)*WNN + kt*64;     // >= 0 for visited tiles
#pragma unroll
    for(int rep=0;rep<4;rep++){
      int f4i = rep*256 + tid;
      int r = f4i >> 4, g = f4i & 15;
      *(float4*)&Ks[sw4(r,g)] =
        *(const float4*)(K + (size_t)(b*SS + kbase + r)*HDIM + g*4);
    }
    __syncthreads();

    float sc[4][4];
#pragma unroll
    for(int i=0;i<4;i++)
#pragma unroll
      for(int j=0;j<4;j++) sc[i][j]=0.f;
    for(int d=0; d<64; d+=4){
      int g = d>>2;
      float qv[4][4], kv[4][4];
#pragma unroll
      for(int i=0;i<4;i++) *(float4*)&qv[i][0] = *(const float4*)&Qs[sw4(ty*4+i, g)];
#pragma unroll
      for(int j=0;j<4;j++) *(float4*)&kv[j][0] = *(const float4*)&Ks[sw4(tx*4+j, g)];
#pragma unroll
      for(int i=0;i<4;i++)
#pragma unroll
        for(int j=0;j<4;j++)
#pragma unroll
          for(int dd=0;dd<4;dd++)
            sc[i][j] = fmaf(qv[i][dd], kv[j][dd], sc[i][j]);
    }

    // masking + online softmax (per q row)
#pragma unroll
    for(int i=0;i<4;i++){
      int qp = qt*64 + ty*4 + i;             // local q pos in chunk
      float tm = -3.0e38f;
      bool val[4];
#pragma unroll
      for(int j=0;j<4;j++){
        int kj = kt*64 + tx*4 + j;           // 0..511
        int diff = qp + WNN - kj;            // q_pos - k_pos
        val[j] = (diff >= 0) && (diff <= WNN);
        if(!val[j]) sc[i][j] = -3.0e38f;
        tm = fmaxf(tm, sc[i][j]);
      }
#pragma unroll
      for(int off=1; off<16; off<<=1) tm = fmaxf(tm, __shfl_xor(tm, off, 64));
      float mn = fmaxf(m[i], tm);
      float alpha = expf(m[i]-mn);
      float rs = 0.f, pv[4];
#pragma unroll
      for(int j=0;j<4;j++){
        float p = val[j] ? expf(sc[i][j]-mn) : 0.f;
        pv[j]=p; rs += p;
      }
#pragma unroll
      for(int off=1; off<16; off<<=1) rs += __shfl_xor(rs, off, 64);
      l[i] = l[i]*alpha + rs;
      m[i] = mn;
#pragma unroll
      for(int j=0;j<4;j++) o[i][j] *= alpha;
      int rr = ty*4+i;
#pragma unroll
      for(int j=0;j<4;j++) Ps[sw4(rr,tx)+j] = pv[j];
    }
    __syncthreads();

    // V tile into Ks
#pragma unroll
    for(int rep=0;rep<4;rep++){
      int f4i = rep*256 + tid;
      int r = f4i >> 4, g = f4i & 15;
      *(float4*)&Ks[sw4(r,g)] =
        *(const float4*)(V + (size_t)(b*SS + kbase + r)*HDIM + g*4);
    }
    __syncthreads();

    // O += P @ V
    for(int k=0;k<64;k++){
      float4 vk = *(const float4*)&Ks[sw4(k, tx)];
      float pk[4];
#pragma unroll
      for(int i=0;i<4;i++) pk[i] = Ps[sw4(ty*4+i, k>>2) + (k&3)];
#pragma unroll
      for(int i=0;i<4;i++){
        o[i][0] = fmaf(pk[i], vk.x, o[i][0]);
        o[i][1] = fmaf(pk[i], vk.y, o[i][1]);
        o[i][2] = fmaf(pk[i], vk.z, o[i][2]);
        o[i][3] = fmaf(pk[i], vk.w, o[i][3]);
      }
    }
    __syncthreads();
  }

#pragma unroll
  for(int i=0;i<4;i++){
    float invl = 1.f/l[i];
    float4 ov;
    ov.x=o[i][0]*invl; ov.y=o[i][1]*invl; ov.z=o[i][2]*invl; ov.w=o[i][3]*invl;
    *(float4*)(O + (size_t)(b*SS + s0 + ty*4 + i)*DD + h*HDIM + tx*4) = ov;
  }
}

// ---------------------------------------------------------------------------
// out = z * (fwd + bwd) + skip
// ---------------------------------------------------------------------------
__global__ __launch_bounds__(256) void comb_k(const float* __restrict__ of,
    const float* __restrict__ ob, const float* __restrict__ z,
    const float* __restrict__ skip, float* __restrict__ out)
{
  int idx = blockIdx.x*256 + threadIdx.x;
  int r = idx >> 8;
  out[idx] = z[r]*(of[idx]+ob[idx]) + skip[idx];
}

// ---------------------------------------------------------------------------
// Host side
// ---------------------------------------------------------------------------
struct Params {
  const float *ln_gamma,*ln_beta,*proj_w,*proj_b,*fconv_w,*fconv_b,*bconv_w,*bconv_b,
    *rn0_t,*rn0_c,*ly_w,*ly_b,*lx_w,*lx_b,*lo_w,*lo_b,*c1d_w,*c1d_b,*a_param,
    *ig_w,*ig_b,*ag_w,*ag_b,*mlp0_up_w,*mlp0_up_b,*mlp0_dn_w,*mlp0_dn_b,
    *rn1_t,*rn1_c,*q_w,*k_w,*v_w,*o_w,*o_b,*mlp1_up_w,*mlp1_up_b,*mlp1_dn_w,*mlp1_dn_b;
};

static void run_block(const Params& p, float* XB, float* N, float* Y, float* XR,
                      float* CV, float* ACT, float* KB, float* VB,
                      float* CSA, float* CSB, float* OUT, hipStream_t stream)
{
  dim3 blk(256);
  dim3 g2(2,128,1), g64(1,128,1), gbd(1,128,4), gdual(12,128,1);

  // rms0 -> N
  rms_k<<<RR/4, blk, 0, stream>>>(XB, p.rn0_t, N);
  // y = gelu(N@ly_w + ly_b) -> Y
  gemm_k<128,3,0><<<g2,blk,0,stream>>>(N,nullptr,p.ly_w,nullptr,p.ly_b,nullptr,nullptr,Y,
      RR,DD,DD, DD,DD,DD, 0,0,0,0);
  // xr = N@lx_w + lx_b -> XR
  gemm_k<128,1,0><<<g2,blk,0,stream>>>(N,nullptr,p.lx_w,nullptr,p.lx_b,nullptr,nullptr,XR,
      RR,DD,DD, DD,DD,DD, 0,0,0,0);
  // causal conv -> CV
  conv_k<<<RR*DD/256, blk, 0, stream>>>(XR, p.c1d_w, p.c1d_b, CV);
  // block-diag gates (batched over heads): ig_lin -> N, ag_lin -> XR
  gemm_k<64,1,0><<<gbd,blk,0,stream>>>(CV,nullptr,p.ig_w,nullptr,p.ig_b,nullptr,nullptr,N,
      RR,HDIM,HDIM, DD,HDIM,DD, HDIM, HDIM*HDIM, HDIM, HDIM);
  gemm_k<64,1,0><<<gbd,blk,0,stream>>>(CV,nullptr,p.ag_w,nullptr,p.ag_b,nullptr,nullptr,XR,
      RR,HDIM,HDIM, DD,HDIM,DD, HDIM, HDIM*HDIM, HDIM, HDIM);
  // gates -> a in N, bterm in XR
  gate_k<<<RR*DD/256, blk, 0, stream>>>(CV, N, XR, p.a_param);
  // blocked scan -> h in XR
  scan1_k<<<BB*NCH*DD/256, blk,0,stream>>>(N, XR, CSA, CSB);
  scan2_k<<<BB*DD/256, blk,0,stream>>>(CSA, CSB);
  scan3_k<<<BB*NCH*DD/256, blk,0,stream>>>(N, XR, CSB);
  // (h*y)@lo_w + lo_b + XB -> CV   (residual)
  gemm_k<128,13,0><<<g2,blk,0,stream>>>(XR, Y, p.lo_w, nullptr, p.lo_b, nullptr, XB, CV,
      RR,DD,DD, DD,DD,DD, 0,0,0,0);
  // rms c -> N
  rms_k<<<RR/4,blk,0,stream>>>(CV, p.rn0_c, N);
  // mlp0 up (dual) -> ACT
  gemm_k<64,1,1><<<gdual,blk,0,stream>>>(N,nullptr, p.mlp0_up_w, p.mlp0_up_w + DD*EE,
      p.mlp0_up_b, p.mlp0_up_b+EE, nullptr, ACT, RR,EE,DD, DD,EE,EE, 0,0,0,0);
  // mlp0 down + residual CV -> XB  (x2)
  gemm_k<128,9,0><<<g2,blk,0,stream>>>(ACT,nullptr,p.mlp0_dn_w,nullptr,p.mlp0_dn_b,nullptr,CV,XB,
      RR,DD,EE, EE,DD,DD, 0,0,0,0);
  // rms1 -> N
  rms_k<<<RR/4,blk,0,stream>>>(XB, p.rn1_t, N);
  // q,k,v
  gemm_k<128,0,0><<<g2,blk,0,stream>>>(N,nullptr,p.q_w,nullptr,nullptr,nullptr,nullptr,Y,
      RR,DD,DD, DD,DD,DD, 0,0,0,0);
  gemm_k<64,0,0><<<g64,blk,0,stream>>>(N,nullptr,p.k_w,nullptr,nullptr,nullptr,nullptr,KB,
      RR,HDIM,DD, DD,HDIM,HDIM, 0,0,0,0);
  gemm_k<64,0,0><<<g64,blk,0,stream>>>(N,nullptr,p.v_w,nullptr,nullptr,nullptr,nullptr,VB,
      RR,HDIM,DD, DD,HDIM,HDIM, 0,0,0,0);
  rope_q_k<<<RR*HH*16/256, blk,0,stream>>>(Y);
  rope_k_k<<<RR*16/256, blk,0,stream>>>(KB);
  // attention -> XR
  attn_k<<<dim3(64,4,4),blk,0,stream>>>(Y, KB, VB, XR);
  // o proj + residual XB -> CV
  gemm_k<128,9,0><<<g2,blk,0,stream>>>(XR,nullptr,p.o_w,nullptr,p.o_b,nullptr,XB,CV,
      RR,DD,DD, DD,DD,DD, 0,0,0,0);
  rms_k<<<RR/4,blk,0,stream>>>(CV, p.rn1_c, N);
  gemm_k<64,1,1><<<gdual,blk,0,stream>>>(N,nullptr, p.mlp1_up_w, p.mlp1_up_w + DD*EE,
      p.mlp1_up_b, p.mlp1_up_b+EE, nullptr, ACT, RR,EE,DD, DD,EE,EE, 0,0,0,0);
  gemm_k<128,9,0><<<g2,blk,0,stream>>>(ACT,nullptr,p.mlp1_dn_w,nullptr,p.mlp1_dn_b,nullptr,CV,OUT,
      RR,DD,EE, EE,DD,DD, 0,0,0,0);
}

extern "C" void kernel_launch(void* const* d_in, const int* in_sizes, int n_in,
                              void* d_out, int out_size, void* d_ws, size_t ws_size,
                              hipStream_t stream)
{
  (void)in_sizes; (void)n_in; (void)out_size; (void)ws_size;
  const float* skip = (const float*)d_in[0];
  Params p;
  p.ln_gamma  =(const float*)d_in[1];  p.ln_beta  =(const float*)d_in[2];
  p.proj_w    =(const float*)d_in[3];  p.proj_b   =(const float*)d_in[4];
  p.fconv_w   =(const float*)d_in[5];  p.fconv_b  =(const float*)d_in[6];
  p.bconv_w   =(const float*)d_in[7];  p.bconv_b  =(const float*)d_in[8];
  p.rn0_t     =(const float*)d_in[9];  p.rn0_c    =(const float*)d_in[10];
  p.ly_w      =(const float*)d_in[11]; p.ly_b     =(const float*)d_in[12];
  p.lx_w      =(const float*)d_in[13]; p.lx_b     =(const float*)d_in[14];
  p.lo_w      =(const float*)d_in[15]; p.lo_b     =(const float*)d_in[16];
  p.c1d_w     =(const float*)d_in[17]; p.c1d_b    =(const float*)d_in[18];
  p.a_param   =(const float*)d_in[19];
  p.ig_w      =(const float*)d_in[20]; p.ig_b     =(const float*)d_in[21];
  p.ag_w      =(const float*)d_in[22]; p.ag_b     =(const float*)d_in[23];
  p.mlp0_up_w =(const float*)d_in[24]; p.mlp0_up_b=(const float*)d_in[25];
  p.mlp0_dn_w =(const float*)d_in[26]; p.mlp0_dn_b=(const float*)d_in[27];
  p.rn1_t     =(const float*)d_in[28]; p.rn1_c    =(const float*)d_in[29];
  p.q_w       =(const float*)d_in[30]; p.k_w      =(const float*)d_in[31];
  p.v_w       =(const float*)d_in[32]; p.o_w      =(const float*)d_in[33];
  p.o_b       =(const float*)d_in[34];
  p.mlp1_up_w =(const float*)d_in[35]; p.mlp1_up_b=(const float*)d_in[36];
  p.mlp1_dn_w =(const float*)d_in[37]; p.mlp1_dn_b=(const float*)d_in[38];

  float* ws = (float*)d_ws;
  const size_t RD = (size_t)RR*DD;
  size_t off = 0;
  float* Z   = ws + off; off += 16384;
  float* X0  = ws + off; off += RD;
  float* XB  = ws + off; off += RD;
  float* N   = ws + off; off += RD;
  float* Y   = ws + off; off += RD;
  float* XR  = ws + off; off += RD;
  float* CV  = ws + off; off += RD;
  float* OF  = ws + off; off += RD;
  float* OB  = ws + off; off += RD;
  float* ACT = ws + off; off += (size_t)RR*EE;
  float* KB  = ws + off; off += (size_t)RR*HDIM;
  float* VB  = ws + off; off += (size_t)RR*HDIM;
  float* CSA = ws + off; off += (size_t)BB*NCH*DD;
  float* CSB = ws + off; off += (size_t)BB*NCH*DD;
  // total ~48.4M floats ~194 MB

  dim3 blk(256);
  dim3 g2(2,128,1);

  // LN(skip) -> N ; z gate -> Z
  ln_z_k<<<RR/4, blk, 0, stream>>>(skip, p.ln_gamma, p.ln_beta, N, Z);
  // x = N@proj_w + proj_b -> X0
  gemm_k<128,1,0><<<g2,blk,0,stream>>>(N,nullptr,p.proj_w,nullptr,p.proj_b,nullptr,nullptr,X0,
      RR,DD,DD, DD,DD,DD, 0,0,0,0);
  // fwd branch
  gemm_k<128,1,0><<<g2,blk,0,stream>>>(X0,nullptr,p.fconv_w,nullptr,p.fconv_b,nullptr,nullptr,XB,
      RR,DD,DD, DD,DD,DD, 0,0,0,0);
  run_block(p, XB, N, Y, XR, CV, ACT, KB, VB, CSA, CSB, OF, stream);
  // bwd branch
  gemm_k<128,1,0><<<g2,blk,0,stream>>>(X0,nullptr,p.bconv_w,nullptr,p.bconv_b,nullptr,nullptr,XB,
      RR,DD,DD, DD,DD,DD, 0,0,0,0);
  run_block(p, XB, N, Y, XR, CV, ACT, KB, VB, CSA, CSB, OB, stream);
  // out = z*(fwd+bwd) + skip
  comb_k<<<RR*DD/256, blk, 0, stream>>>(OF, OB, Z, skip, (float*)d_out);
}

// Round 2
// 1462.943 us; speedup vs baseline: 1.6150x; 1.6150x over previous
//
#include <hip/hip_runtime.h>
#include <math.h>
#include <stddef.h>

// ---------------------------------------------------------------------------
// BiDiGemma forward. Round 2: split-bf16 (3-term) MFMA GEMMs for all heavy
// matmuls; weights pre-transposed+split per launch; fp32 elsewhere.
// ---------------------------------------------------------------------------

#define BB   4
#define SS   4096
#define DD   256
#define HH   4
#define HDIM 64
#define EE   768
#define RR   (BB*SS)
#define WNN  256
#define CH   64
#define NCH  (SS/CH)

typedef __attribute__((ext_vector_type(8))) short bfrag;
typedef __attribute__((ext_vector_type(4))) float f4acc;

__device__ __forceinline__ float geluf(float x){
  return 0.5f*x*(1.0f + erff(x*0.70710678118654752f));
}
__device__ __forceinline__ float sigm(float x){ return 1.0f/(1.0f+expf(-x)); }

__device__ __forceinline__ unsigned short f2bf(float x){
  unsigned u = __float_as_uint(x);
  return (unsigned short)((u + 0x7FFFu + ((u>>16)&1u)) >> 16);
}
__device__ __forceinline__ float bf2f(unsigned short h){
  return __uint_as_float(((unsigned)h) << 16);
}

__device__ __forceinline__ float wredSum(float v){
#pragma unroll
  for(int o=32;o>0;o>>=1) v += __shfl_xor(v,o,64);
  return v;
}

__global__ __launch_bounds__(256) void ln_z_k(const float* __restrict__ skip,
    const float* __restrict__ g, const float* __restrict__ b,
    float* __restrict__ out, float* __restrict__ z)
{
  int row  = blockIdx.x*4 + (threadIdx.x>>6);
  int lane = threadIdx.x & 63;
  float4 v = ((const float4*)(skip + (size_t)row*DD))[lane];
  float s  = v.x+v.y+v.z+v.w;
  float sq = v.x*v.x+v.y*v.y+v.z*v.z+v.w*v.w;
  float si = v.x*sigm(v.x)+v.y*sigm(v.y)+v.z*sigm(v.z)+v.w*sigm(v.w);
  s = wredSum(s); sq = wredSum(sq); si = wredSum(si);
  float mean = s*(1.0f/DD);
  float var  = sq*(1.0f/DD) - mean*mean;
  float inv  = rsqrtf(var + 1e-5f);
  float4 gv = ((const float4*)g)[lane];
  float4 bv = ((const float4*)b)[lane];
  float4 o;
  o.x = (v.x-mean)*inv*gv.x + bv.x;
  o.y = (v.y-mean)*inv*gv.y + bv.y;
  o.z = (v.z-mean)*inv*gv.z + bv.z;
  o.w = (v.w-mean)*inv*gv.w + bv.w;
  ((float4*)(out + (size_t)row*DD))[lane] = o;
  if(lane==0) z[row] = sigm(si*(1.0f/DD));
}

__global__ __launch_bounds__(256) void rms_k(const float* __restrict__ x,
    const float* __restrict__ t, float* __restrict__ out)
{
  int row  = blockIdx.x*4 + (threadIdx.x>>6);
  int lane = threadIdx.x & 63;
  float4 v = ((const float4*)(x + (size_t)row*DD))[lane];
  float sq = v.x*v.x+v.y*v.y+v.z*v.z+v.w*v.w;
  sq = wredSum(sq);
  float inv = rsqrtf(sq*(1.0f/DD) + 1e-6f);
  float4 tv = ((const float4*)t)[lane];
  float4 o;
  o.x = v.x*inv*(1.0f+tv.x);
  o.y = v.y*inv*(1.0f+tv.y);
  o.z = v.z*inv*(1.0f+tv.z);
  o.w = v.w*inv*(1.0f+tv.w);
  ((float4*)(out + (size_t)row*DD))[lane] = o;
}

struct TS  { const float* s; unsigned short* h; unsigned short* l; int K; int N; };
struct TS8 { TS t[8]; };

__global__ __launch_bounds__(256) void tsplit8_k(TS8 g){
  TS tt = g.t[blockIdx.y];
  int idx = blockIdx.x*256 + threadIdx.x;
  int tot = tt.K*tt.N;
  if(idx >= tot) return;
  int k = idx / tt.N;
  int n = idx - k*tt.N;
  float x = tt.s[idx];
  unsigned short hb = f2bf(x);
  unsigned short lb = f2bf(x - bf2f(hb));
  tt.h[(size_t)n*tt.K + k] = hb;
  tt.l[(size_t)n*tt.K + k] = lb;
}

// ---------------------------------------------------------------------------
// Split-bf16 MFMA GEMM (see header comment in round notes).
// ---------------------------------------------------------------------------
template<int BN, int MODE, int DUAL>
__global__ __launch_bounds__(256) void gemm_mfma(
    const float* __restrict__ A, const float* __restrict__ A2,
    const unsigned short* __restrict__ B0h, const unsigned short* __restrict__ B0l,
    const unsigned short* __restrict__ B1h, const unsigned short* __restrict__ B1l,
    const float* __restrict__ bias0, const float* __restrict__ bias1,
    const float* __restrict__ Res, float* __restrict__ C,
    int K, int lda, int ldc)
{
  constexpr int NT = BN/32;
  constexpr int ST = 56;
  __shared__ unsigned short Ah[128*ST], Al[128*ST];
  __shared__ unsigned short Bh[BN*ST],  Bl[BN*ST];
  __shared__ unsigned short B2h[DUAL?BN*ST:8], B2l[DUAL?BN*ST:8];

  const int tid  = threadIdx.x;
  const int lane = tid & 63, wave = tid >> 6;
  const int wm = wave >> 1, wn = wave & 1;
  const int bm = blockIdx.y*128, bn = blockIdx.x*BN;
  const int m16 = lane & 15, q = lane >> 4;

  f4acc acc[4][NT];
  f4acc acc2[DUAL?4:1][DUAL?NT:1];
#pragma unroll
  for(int i=0;i<4;i++)
#pragma unroll
    for(int j=0;j<NT;j++){
      acc[i][j] = (f4acc)0.f;
      if constexpr(DUAL) acc2[i][j] = (f4acc)0.f;
    }

  const int s_row  = tid >> 1;
  const int s_half = tid & 1;
  const float* Arow  = A + (size_t)(bm + s_row)*lda + s_half*16;
  const float* A2row = (MODE&4) ? (A2 + (size_t)(bm + s_row)*lda + s_half*16)
                                : (const float*)nullptr;

  for(int k0 = 0; k0 < K; k0 += 32){
#pragma unroll
    for(int c=0;c<4;c++){
      float4 v = *(const float4*)(Arow + k0 + c*4);
      if(MODE&4){
        float4 u = *(const float4*)(A2row + k0 + c*4);
        v.x*=u.x; v.y*=u.y; v.z*=u.z; v.w*=u.w;
      }
      ushort4 hi, lo;
      hi.x=f2bf(v.x); lo.x=f2bf(v.x-bf2f(hi.x));
      hi.y=f2bf(v.y); lo.y=f2bf(v.y-bf2f(hi.y));
      hi.z=f2bf(v.z); lo.z=f2bf(v.z-bf2f(hi.z));
      hi.w=f2bf(v.w); lo.w=f2bf(v.w-bf2f(hi.w));
      *(ushort4*)&Ah[s_row*ST + s_half*16 + c*4] = hi;
      *(ushort4*)&Al[s_row*ST + s_half*16 + c*4] = lo;
    }
    {
      constexpr int CH16 = BN*4;
#pragma unroll
      for(int s0 = 0; s0 < CH16; s0 += 256){
        int s = s0 + tid;
        int n = s >> 2, c = s & 3;
        *(float4*)(Bh + n*ST + c*8) = *(const float4*)(B0h + (size_t)(bn+n)*K + k0 + c*8);
        *(float4*)(Bl + n*ST + c*8) = *(const float4*)(B0l + (size_t)(bn+n)*K + k0 + c*8);
        if constexpr(DUAL){
          *(float4*)(B2h + n*ST + c*8) = *(const float4*)(B1h + (size_t)(bn+n)*K + k0 + c*8);
          *(float4*)(B2l + n*ST + c*8) = *(const float4*)(B1l + (size_t)(bn+n)*K + k0 + c*8);
        }
      }
    }
    __syncthreads();

    bfrag ah[4], al[4], b0hf[NT], b0lf[NT];
    bfrag b1hf[DUAL?NT:1], b1lf[DUAL?NT:1];
#pragma unroll
    for(int mi=0;mi<4;mi++){
      int row = wm*64 + mi*16 + m16;
      ah[mi] = *(const bfrag*)&Ah[row*ST + q*8];
      al[mi] = *(const bfrag*)&Al[row*ST + q*8];
    }
#pragma unroll
    for(int ni=0;ni<NT;ni++){
      int n = wn*(BN/2) + ni*16 + m16;
      b0hf[ni] = *(const bfrag*)&Bh[n*ST + q*8];
      b0lf[ni] = *(const bfrag*)&Bl[n*ST + q*8];
      if constexpr(DUAL){
        b1hf[ni] = *(const bfrag*)&B2h[n*ST + q*8];
        b1lf[ni] = *(const bfrag*)&B2l[n*ST + q*8];
      }
    }
#pragma unroll
    for(int mi=0;mi<4;mi++)
#pragma unroll
      for(int ni=0;ni<NT;ni++){
        acc[mi][ni] = __builtin_amdgcn_mfma_f32_16x16x32_bf16(ah[mi], b0hf[ni], acc[mi][ni],0,0,0);
        acc[mi][ni] = __builtin_amdgcn_mfma_f32_16x16x32_bf16(ah[mi], b0lf[ni], acc[mi][ni],0,0,0);
        acc[mi][ni] = __builtin_amdgcn_mfma_f32_16x16x32_bf16(al[mi], b0hf[ni], acc[mi][ni],0,0,0);
        if constexpr(DUAL){
          acc2[mi][ni] = __builtin_amdgcn_mfma_f32_16x16x32_bf16(ah[mi], b1hf[ni], acc2[mi][ni],0,0,0);
          acc2[mi][ni] = __builtin_amdgcn_mfma_f32_16x16x32_bf16(ah[mi], b1lf[ni], acc2[mi][ni],0,0,0);
          acc2[mi][ni] = __builtin_amdgcn_mfma_f32_16x16x32_bf16(al[mi], b1hf[ni], acc2[mi][ni],0,0,0);
        }
      }
    __syncthreads();
  }

#pragma unroll
  for(int ni=0;ni<NT;ni++){
    const int col = bn + wn*(BN/2) + ni*16 + m16;
    float bv0 = (MODE&1) ? bias0[col] : 0.f;
    float bv1 = DUAL ? bias1[col] : 0.f;
#pragma unroll
    for(int mi=0;mi<4;mi++){
#pragma unroll
      for(int r=0;r<4;r++){
        const int row = bm + wm*64 + mi*16 + q*4 + r;
        float v = acc[mi][ni][r] + bv0;
        if constexpr(DUAL){
          float v2 = acc2[mi][ni][r] + bv1;
          v = geluf(v) * v2;
        } else if(MODE&2){
          v = geluf(v);
        }
        if(MODE&8) v += Res[(size_t)row*ldc + col];
        C[(size_t)row*ldc + col] = v;
      }
    }
  }
}

// fp32 GEMM kept for the block-diagonal gate linears.
template<int BN, int MODE>
__global__ __launch_bounds__(256) void gemm_k(
    const float* __restrict__ A,
    const float* __restrict__ B0,
    const float* __restrict__ bias0,
    float* __restrict__ C,
    int M, int N, int K, int lda, int ldb, int ldc,
    int batA, int batB, int batC, int batBias)
{
  constexpr int BK = 16;
  constexpr int TN = BN/16;
  constexpr int NH = BN/64;
  __shared__ float Ask[BK][132];
  __shared__ float Bs [BK][BN+4];

  const int bz = blockIdx.z;
  const float* Ab  = A  + (size_t)bz*batA;
  const float* Bb  = B0 + (size_t)bz*batB;
  float* Cb = C + (size_t)bz*batC;

  const int bm = blockIdx.y*128, bn = blockIdx.x*BN;
  const int tid = threadIdx.x;
  const int tx = tid & 15, ty = tid >> 4;
  const int ar = tid >> 1, ac = (tid & 1)*8;
  const int br = tid >> 4;

  float acc[8][TN];
#pragma unroll
  for(int i=0;i<8;i++)
#pragma unroll
    for(int j=0;j<TN;j++) acc[i][j]=0.f;

  for(int k0=0;k0<K;k0+=BK){
#pragma unroll
    for(int hf=0;hf<2;hf++){
      float4 av = *(const float4*)(Ab + (size_t)(bm+ar)*lda + (k0+ac+hf*4));
      Ask[ac+hf*4+0][ar]=av.x; Ask[ac+hf*4+1][ar]=av.y;
      Ask[ac+hf*4+2][ar]=av.z; Ask[ac+hf*4+3][ar]=av.w;
    }
    {
      const int bc = (tid&15)*4;
      *(float4*)&Bs[br][bc] = *(const float4*)(Bb + (size_t)(k0+br)*ldb + (bn+bc));
    }
    __syncthreads();
#pragma unroll
    for(int k=0;k<BK;k++){
      float a[8];
      *(float4*)&a[0] = *(const float4*)&Ask[k][ty*8];
      *(float4*)&a[4] = *(const float4*)&Ask[k][ty*8+4];
      float bv[TN];
#pragma unroll
      for(int hh=0;hh<NH;hh++)
        *(float4*)&bv[hh*4] = *(const float4*)&Bs[k][hh*64 + tx*4];
#pragma unroll
      for(int i=0;i<8;i++)
#pragma unroll
        for(int j=0;j<TN;j++)
          acc[i][j] = fmaf(a[i], bv[j], acc[i][j]);
    }
    __syncthreads();
  }

#pragma unroll
  for(int i=0;i<8;i++){
    const int row = bm + ty*8 + i;
#pragma unroll
    for(int hh=0;hh<NH;hh++){
      const int col = bn + hh*64 + tx*4;
      float v0=acc[i][hh*4+0], v1=acc[i][hh*4+1], v2=acc[i][hh*4+2], v3=acc[i][hh*4+3];
      if(MODE&1){
        float4 bbv = *(const float4*)(bias0 + (size_t)bz*batBias + col);
        v0+=bbv.x; v1+=bbv.y; v2+=bbv.z; v3+=bbv.w;
      }
      float4 ov; ov.x=v0; ov.y=v1; ov.z=v2; ov.w=v3;
      *(float4*)(Cb + (size_t)row*ldc + col) = ov;
    }
  }
}

__global__ __launch_bounds__(256) void conv_k(const float* __restrict__ x,
    const float* __restrict__ w, const float* __restrict__ b, float* __restrict__ out)
{
  int idx = blockIdx.x*256 + threadIdx.x;
  int d = idx & (DD-1);
  int r = idx >> 8;
  int s = r & (SS-1);
  float acc = b[d];
#pragma unroll
  for(int i=0;i<4;i++){
    int t = s - 3 + i;
    if(t >= 0) acc += w[i*DD + d] * x[(size_t)(r-3+i)*DD + d];
  }
  out[idx] = acc;
}

__global__ __launch_bounds__(256) void gate_k(const float* __restrict__ x,
    float* __restrict__ ig, float* __restrict__ ag, const float* __restrict__ ap)
{
  int idx = blockIdx.x*256 + threadIdx.x;
  int d = idx & (DD-1);
  int r = idx >> 8;
  int s = r & (SS-1);
  float gx = sigm(ig[idx]);
  float ga = sigm(ag[idx]);
  float a_ = ap[d];
  float sp = (a_ > 20.f) ? a_ : log1pf(expf(a_));
  float la = -8.f * ga * sp;
  float a  = expf(la);
  float mult = (s==0) ? 1.f : sqrtf(fmaxf(-expm1f(2.f*la), 0.f));
  float bt = x[idx] * gx * mult;
  ig[idx] = a;
  ag[idx] = bt;
}

__global__ __launch_bounds__(256) void scan1_k(const float* __restrict__ A,
    const float* __restrict__ Bv, float* __restrict__ csa, float* __restrict__ csb)
{
  int idx = blockIdx.x*256 + threadIdx.x;
  int d = idx & (DD-1);
  int c = (idx >> 8) & (NCH-1);
  int b = idx >> 14;
  size_t base = ((size_t)b*SS + (size_t)c*CH)*DD + d;
  float Aa = 1.f, Bb_ = 0.f;
  for(int t=0;t<CH;t++){
    float a  = A [base + (size_t)t*DD];
    float bb = Bv[base + (size_t)t*DD];
    Aa  = a*Aa;
    Bb_ = a*Bb_ + bb;
  }
  csa[idx] = Aa; csb[idx] = Bb_;
}

__global__ __launch_bounds__(256) void scan2_k(const float* __restrict__ csa,
    float* __restrict__ csb)
{
  int idx = blockIdx.x*256 + threadIdx.x;
  int d = idx & (DD-1);
  int b = idx >> 8;
  float h = 0.f;
  for(int c=0;c<NCH;c++){
    size_t i = ((size_t)b*NCH + c)*DD + d;
    float Aa = csa[i], Bb_ = csb[i];
    csb[i] = h;
    h = Aa*h + Bb_;
  }
}

__global__ __launch_bounds__(256) void scan3_k(const float* __restrict__ A,
    float* __restrict__ Bv, const float* __restrict__ csb)
{
  int idx = blockIdx.x*256 + threadIdx.x;
  int d = idx & (DD-1);
  int c = (idx >> 8) & (NCH-1);
  int b = idx >> 14;
  size_t base = ((size_t)b*SS + (size_t)c*CH)*DD + d;
  float h = csb[idx];
  for(int t=0;t<CH;t++){
    float a  = A [base + (size_t)t*DD];
    float bb = Bv[base + (size_t)t*DD];
    h = a*h + bb;
    Bv[base + (size_t)t*DD] = h;
  }
}

__global__ __launch_bounds__(256) void rope_q_k(float* __restrict__ q)
{
  int idx = blockIdx.x*256 + threadIdx.x;
  int p = idx & 15;
  int h = (idx>>4) & 3;
  int r = idx >> 6;
  int s = r & (SS-1);
  float inv = expf(-(float)p * 0.575646273248511f);
  float t = (float)s * inv;
  float sn, cs; __sincosf(t, &sn, &cs);
  float* base = q + (size_t)r*DD + h*HDIM;
  float x1 = base[p], x2 = base[p+16];
  const float sc = 0.125f;
  base[p]    = (x1*cs - x2*sn)*sc;
  base[p+16] = (x2*cs + x1*sn)*sc;
  base[p+32] *= sc;
  base[p+48] *= sc;
}

__global__ __launch_bounds__(256) void rope_k_k(float* __restrict__ kk)
{
  int idx = blockIdx.x*256 + threadIdx.x;
  int p = idx & 15;
  int r = idx >> 4;
  int s = r & (SS-1);
  float inv = expf(-(float)p * 0.575646273248511f);
  float t = (float)s * inv;
  float sn, cs; __sincosf(t, &sn, &cs);
  float* base = kk + (size_t)r*HDIM;
  float x1 = base[p], x2 = base[p+16];
  base[p]    = x1*cs - x2*sn;
  base[p+16] = x2*cs + x1*sn;
}

__device__ __forceinline__ int sw4(int r, int g){ return r*64 + (((g ^ (r & 15)) & 15) << 2); }

__global__ __launch_bounds__(256) void attn_k(const float* __restrict__ Q,
    const float* __restrict__ K, const float* __restrict__ V, float* __restrict__ O)
{
  __shared__ float Qs[64*64];
  __shared__ float Ks[64*64];
  __shared__ float Ps[64*64];
  int qt = blockIdx.x & 3, n = blockIdx.x >> 2;
  int h = blockIdx.y, b = blockIdx.z;
  int tid = threadIdx.x, tx = tid & 15, ty = tid >> 4;
  int s0 = n*WNN + qt*64;

#pragma unroll
  for(int rep=0; rep<4; rep++){
    int f4i = rep*256 + tid;
    int r = f4i >> 4, g = f4i & 15;
    *(float4*)&Qs[sw4(r,g)] =
      *(const float4*)(Q + ((size_t)(b*SS + s0 + r))*DD + h*HDIM + g*4);
  }

  float m[4], l[4], o[4][4];
#pragma unroll
  for(int i=0;i<4;i++){ m[i]=-3.0e38f; l[i]=0.f;
#pragma unroll
    for(int j=0;j<4;j++) o[i][j]=0.f; }

  int ktlo = (n==0) ? 4 : qt;
  int kthi = qt + 4;
  for(int kt=ktlo; kt<=kthi; kt++){
    int kbase = (n-1)*WNN + kt*64;
#pragma unroll
    for(int rep=0;rep<4;rep++){
      int f4i = rep*256 + tid;
      int r = f4i >> 4, g = f4i & 15;
      *(float4*)&Ks[sw4(r,g)] =
        *(const float4*)(K + (size_t)(b*SS + kbase + r)*HDIM + g*4);
    }
    __syncthreads();

    float sc[4][4];
#pragma unroll
    for(int i=0;i<4;i++)
#pragma unroll
      for(int j=0;j<4;j++) sc[i][j]=0.f;
    for(int d=0; d<64; d+=4){
      int g = d>>2;
      float qv[4][4], kv[4][4];
#pragma unroll
      for(int i=0;i<4;i++) *(float4*)&qv[i][0] = *(const float4*)&Qs[sw4(ty*4+i, g)];
#pragma unroll
      for(int j=0;j<4;j++) *(float4*)&kv[j][0] = *(const float4*)&Ks[sw4(tx*4+j, g)];
#pragma unroll
      for(int i=0;i<4;i++)
#pragma unroll
        for(int j=0;j<4;j++)
#pragma unroll
          for(int dd=0;dd<4;dd++)
            sc[i][j] = fmaf(qv[i][dd], kv[j][dd], sc[i][j]);
    }

#pragma unroll
    for(int i=0;i<4;i++){
      int qp = qt*64 + ty*4 + i;
      float tm = -3.0e38f;
      bool val[4];
#pragma unroll
      for(int j=0;j<4;j++){
        int kj = kt*64 + tx*4 + j;
        int diff = qp + WNN - kj;
        val[j] = (diff >= 0) && (diff <= WNN);
        if(!val[j]) sc[i][j] = -3.0e38f;
        tm = fmaxf(tm, sc[i][j]);
      }
#pragma unroll
      for(int off=1; off<16; off<<=1) tm = fmaxf(tm, __shfl_xor(tm, off, 64));
      float mn = fmaxf(m[i], tm);
      float alpha = expf(m[i]-mn);
      float rs = 0.f, pv[4];
#pragma unroll
      for(int j=0;j<4;j++){
        float p = val[j] ? expf(sc[i][j]-mn) : 0.f;
        pv[j]=p; rs += p;
      }
#pragma unroll
      for(int off=1; off<16; off<<=1) rs += __shfl_xor(rs, off, 64);
      l[i] = l[i]*alpha + rs;
      m[i] = mn;
#pragma unroll
      for(int j=0;j<4;j++) o[i][j] *= alpha;
      int rr = ty*4+i;
#pragma unroll
      for(int j=0;j<4;j++) Ps[sw4(rr,tx)+j] = pv[j];
    }
    __syncthreads();

#pragma unroll
    for(int rep=0;rep<4;rep++){
      int f4i = rep*256 + tid;
      int r = f4i >> 4, g = f4i & 15;
      *(float4*)&Ks[sw4(r,g)] =
        *(const float4*)(V + (size_t)(b*SS + kbase + r)*HDIM + g*4);
    }
    __syncthreads();

    for(int k=0;k<64;k++){
      float4 vk = *(const float4*)&Ks[sw4(k, tx)];
      float pk[4];
#pragma unroll
      for(int i=0;i<4;i++) pk[i] = Ps[sw4(ty*4+i, k>>2) + (k&3)];
#pragma unroll
      for(int i=0;i<4;i++){
        o[i][0] = fmaf(pk[i], vk.x, o[i][0]);
        o[i][1] = fmaf(pk[i], vk.y, o[i][1]);
        o[i][2] = fmaf(pk[i], vk.z, o[i][2]);
        o[i][3] = fmaf(pk[i], vk.w, o[i][3]);
      }
    }
    __syncthreads();
  }

#pragma unroll
  for(int i=0;i<4;i++){
    float invl = 1.f/l[i];
    float4 ov;
    ov.x=o[i][0]*invl; ov.y=o[i][1]*invl; ov.z=o[i][2]*invl; ov.w=o[i][3]*invl;
    *(float4*)(O + (size_t)(b*SS + s0 + ty*4 + i)*DD + h*HDIM + tx*4) = ov;
  }
}

__global__ __launch_bounds__(256) void comb_k(const float* __restrict__ of,
    const float* __restrict__ ob, const float* __restrict__ z,
    const float* __restrict__ skip, float* __restrict__ out)
{
  int idx = blockIdx.x*256 + threadIdx.x;
  int r = idx >> 8;
  out[idx] = z[r]*(of[idx]+ob[idx]) + skip[idx];
}

// ---------------------------------------------------------------------------
struct Params {
  const float *ln_gamma,*ln_beta,*proj_w,*proj_b,*fconv_w,*fconv_b,*bconv_w,*bconv_b,
    *rn0_t,*rn0_c,*ly_w,*ly_b,*lx_w,*lx_b,*lo_w,*lo_b,*c1d_w,*c1d_b,*a_param,
    *ig_w,*ig_b,*ag_w,*ag_b,*mlp0_up_w,*mlp0_up_b,*mlp0_dn_w,*mlp0_dn_b,
    *rn1_t,*rn1_c,*q_w,*k_w,*v_w,*o_w,*o_b,*mlp1_up_w,*mlp1_up_b,*mlp1_dn_w,*mlp1_dn_b;
};

struct WSplit {
  unsigned short *proj_h,*proj_l,*fconv_h,*fconv_l,*bconv_h,*bconv_l,
    *ly_h,*ly_l,*lx_h,*lx_l,*lo_h,*lo_l,*q_h,*q_l,*o_h,*o_l,
    *k_h,*k_l,*v_h,*v_l,
    *up0a_h,*up0a_l,*up0b_h,*up0b_l,*up1a_h,*up1a_l,*up1b_h,*up1b_l,
    *dn0_h,*dn0_l,*dn1_h,*dn1_l;
};

static void run_block(const Params& p, const WSplit& w,
                      float* XB, float* N, float* Y, float* XR,
                      float* CV, float* ACT, float* KB, float* VB,
                      float* CSA, float* CSB, float* OUT, hipStream_t stream)
{
  dim3 blk(256);
  dim3 g2(2,128,1), g64(1,128,1), gbd(1,128,4), gdual(12,128,1);

  // ---- residual block 0: recurrent ----
  rms_k<<<RR/4, blk, 0, stream>>>(XB, p.rn0_t, N);
  gemm_mfma<128,3,0><<<g2,blk,0,stream>>>(N,nullptr,w.ly_h,w.ly_l,nullptr,nullptr,
      p.ly_b,nullptr,nullptr,Y, DD,DD,DD);
  gemm_mfma<128,1,0><<<g2,blk,0,stream>>>(N,nullptr,w.lx_h,w.lx_l,nullptr,nullptr,
      p.lx_b,nullptr,nullptr,XR, DD,DD,DD);
  conv_k<<<RR*DD/256, blk, 0, stream>>>(XR, p.c1d_w, p.c1d_b, CV);
  gemm_k<64,1><<<gbd,blk,0,stream>>>(CV,p.ig_w,p.ig_b,N,
      RR,HDIM,HDIM, DD,HDIM,DD, HDIM, HDIM*HDIM, HDIM, HDIM);
  gemm_k<64,1><<<gbd,blk,0,stream>>>(CV,p.ag_w,p.ag_b,XR,
      RR,HDIM,HDIM, DD,HDIM,DD, HDIM, HDIM*HDIM, HDIM, HDIM);
  gate_k<<<RR*DD/256, blk, 0, stream>>>(CV, N, XR, p.a_param);
  scan1_k<<<BB*NCH*DD/256, blk,0,stream>>>(N, XR, CSA, CSB);
  scan2_k<<<BB*DD/256, blk,0,stream>>>(CSA, CSB);
  scan3_k<<<BB*NCH*DD/256, blk,0,stream>>>(N, XR, CSB);
  gemm_mfma<128,13,0><<<g2,blk,0,stream>>>(XR, Y, w.lo_h,w.lo_l,nullptr,nullptr,
      p.lo_b,nullptr,XB,CV, DD,DD,DD);
  rms_k<<<RR/4,blk,0,stream>>>(CV, p.rn0_c, N);
  gemm_mfma<64,1,1><<<gdual,blk,0,stream>>>(N,nullptr, w.up0a_h,w.up0a_l, w.up0b_h,w.up0b_l,
      p.mlp0_up_b, p.mlp0_up_b+EE, nullptr, ACT, DD,DD,EE);
  gemm_mfma<128,9,0><<<g2,blk,0,stream>>>(ACT,nullptr, w.dn0_h,w.dn0_l,nullptr,nullptr,
      p.mlp0_dn_b,nullptr,CV,XB, EE,EE,DD);

  // ---- residual block 1: local attention ----
  rms_k<<<RR/4,blk,0,stream>>>(XB, p.rn1_t, N);
  gemm_mfma<128,0,0><<<g2,blk,0,stream>>>(N,nullptr,w.q_h,w.q_l,nullptr,nullptr,
      nullptr,nullptr,nullptr,Y, DD,DD,DD);
  gemm_mfma<64,0,0><<<g64,blk,0,stream>>>(N,nullptr,w.k_h,w.k_l,nullptr,nullptr,
      nullptr,nullptr,nullptr,KB, DD,DD,HDIM);
  gemm_mfma<64,0,0><<<g64,blk,0,stream>>>(N,nullptr,w.v_h,w.v_l,nullptr,nullptr,
      nullptr,nullptr,nullptr,VB, DD,DD,HDIM);
  rope_q_k<<<RR*HH*16/256, blk,0,stream>>>(Y);
  rope_k_k<<<RR*16/256, blk,0,stream>>>(KB);
  attn_k<<<dim3(64,4,4),blk,0,stream>>>(Y, KB, VB, XR);
  gemm_mfma<128,9,0><<<g2,blk,0,stream>>>(XR,nullptr,w.o_h,w.o_l,nullptr,nullptr,
      p.o_b,nullptr,XB,CV, DD,DD,DD);
  rms_k<<<RR/4,blk,0,stream>>>(CV, p.rn1_c, N);
  gemm_mfma<64,1,1><<<gdual,blk,0,stream>>>(N,nullptr, w.up1a_h,w.up1a_l, w.up1b_h,w.up1b_l,
      p.mlp1_up_b, p.mlp1_up_b+EE, nullptr, ACT, DD,DD,EE);
  gemm_mfma<128,9,0><<<g2,blk,0,stream>>>(ACT,nullptr, w.dn1_h,w.dn1_l,nullptr,nullptr,
      p.mlp1_dn_b,nullptr,CV,OUT, EE,EE,DD);
}

extern "C" void kernel_launch(void* const* d_in, const int* in_sizes, int n_in,
                              void* d_out, int out_size, void* d_ws, size_t ws_size,
                              hipStream_t stream)
{
  (void)in_sizes; (void)n_in; (void)out_size; (void)ws_size;
  const float* skip = (const float*)d_in[0];
  Params p;
  p.ln_gamma  =(const float*)d_in[1];  p.ln_beta  =(const float*)d_in[2];
  p.proj_w    =(const float*)d_in[3];  p.proj_b   =(const float*)d_in[4];
  p.fconv_w   =(const float*)d_in[5];  p.fconv_b  =(const float*)d_in[6];
  p.bconv_w   =(const float*)d_in[7];  p.bconv_b  =(const float*)d_in[8];
  p.rn0_t     =(const float*)d_in[9];  p.rn0_c    =(const float*)d_in[10];
  p.ly_w      =(const float*)d_in[11]; p.ly_b     =(const float*)d_in[12];
  p.lx_w      =(const float*)d_in[13]; p.lx_b     =(const float*)d_in[14];
  p.lo_w      =(const float*)d_in[15]; p.lo_b     =(const float*)d_in[16];
  p.c1d_w     =(const float*)d_in[17]; p.c1d_b    =(const float*)d_in[18];
  p.a_param   =(const float*)d_in[19];
  p.ig_w      =(const float*)d_in[20]; p.ig_b     =(const float*)d_in[21];
  p.ag_w      =(const float*)d_in[22]; p.ag_b     =(const float*)d_in[23];
  p.mlp0_up_w =(const float*)d_in[24]; p.mlp0_up_b=(const float*)d_in[25];
  p.mlp0_dn_w =(const float*)d_in[26]; p.mlp0_dn_b=(const float*)d_in[27];
  p.rn1_t     =(const float*)d_in[28]; p.rn1_c    =(const float*)d_in[29];
  p.q_w       =(const float*)d_in[30]; p.k_w      =(const float*)d_in[31];
  p.v_w       =(const float*)d_in[32]; p.o_w      =(const float*)d_in[33];
  p.o_b       =(const float*)d_in[34];
  p.mlp1_up_w =(const float*)d_in[35]; p.mlp1_up_b=(const float*)d_in[36];
  p.mlp1_dn_w =(const float*)d_in[37]; p.mlp1_dn_b=(const float*)d_in[38];

  float* ws = (float*)d_ws;
  const size_t RD = (size_t)RR*DD;
  size_t off = 0;
  float* Z   = ws + off; off += 16384;
  float* X0  = ws + off; off += RD;
  float* XB  = ws + off; off += RD;
  float* N   = ws + off; off += RD;
  float* Y   = ws + off; off += RD;
  float* XR  = ws + off; off += RD;
  float* CV  = ws + off; off += RD;
  float* OF  = ws + off; off += RD;
  float* OB  = ws + off; off += RD;
  float* ACT = ws + off; off += (size_t)RR*EE;
  float* KB  = ws + off; off += (size_t)RR*HDIM;
  float* VB  = ws + off; off += (size_t)RR*HDIM;
  float* CSA = ws + off; off += (size_t)BB*NCH*DD;
  float* CSB = ws + off; off += (size_t)BB*NCH*DD;
  off = (off + 3) & ~(size_t)3;

  unsigned short* sp = (unsigned short*)(ws + off);
  WSplit w;
  auto alloc_s = [&](size_t n){ unsigned short* r = sp; sp += n; return r; };
  const size_t SDD = (size_t)DD*DD, SKV = (size_t)DD*HDIM, SUP = (size_t)DD*EE;
  w.proj_h=alloc_s(SDD);  w.proj_l=alloc_s(SDD);
  w.fconv_h=alloc_s(SDD); w.fconv_l=alloc_s(SDD);
  w.bconv_h=alloc_s(SDD); w.bconv_l=alloc_s(SDD);
  w.ly_h=alloc_s(SDD);    w.ly_l=alloc_s(SDD);
  w.lx_h=alloc_s(SDD);    w.lx_l=alloc_s(SDD);
  w.lo_h=alloc_s(SDD);    w.lo_l=alloc_s(SDD);
  w.q_h=alloc_s(SDD);     w.q_l=alloc_s(SDD);
  w.o_h=alloc_s(SDD);     w.o_l=alloc_s(SDD);
  w.k_h=alloc_s(SKV);     w.k_l=alloc_s(SKV);
  w.v_h=alloc_s(SKV);     w.v_l=alloc_s(SKV);
  w.up0a_h=alloc_s(SUP);  w.up0a_l=alloc_s(SUP);
  w.up0b_h=alloc_s(SUP);  w.up0b_l=alloc_s(SUP);
  w.up1a_h=alloc_s(SUP);  w.up1a_l=alloc_s(SUP);
  w.up1b_h=alloc_s(SUP);  w.up1b_l=alloc_s(SUP);
  w.dn0_h=alloc_s(SUP);   w.dn0_l=alloc_s(SUP);
  w.dn1_h=alloc_s(SUP);   w.dn1_l=alloc_s(SUP);

  dim3 blk(256);
  dim3 g2(2,128,1);

  {
    TS8 ga;
    ga.t[0] = {p.proj_w,  w.proj_h,  w.proj_l,  DD, DD};
    ga.t[1] = {p.fconv_w, w.fconv_h, w.fconv_l, DD, DD};
    ga.t[2] = {p.bconv_w, w.bconv_h, w.bconv_l, DD, DD};
    ga.t[3] = {p.ly_w,    w.ly_h,    w.ly_l,    DD, DD};
    ga.t[4] = {p.lx_w,    w.lx_h,    w.lx_l,    DD, DD};
    ga.t[5] = {p.lo_w,    w.lo_h,    w.lo_l,    DD, DD};
    ga.t[6] = {p.q_w,     w.q_h,     w.q_l,     DD, DD};
    ga.t[7] = {p.o_w,     w.o_h,     w.o_l,     DD, DD};
    tsplit8_k<<<dim3(DD*DD/256, 8), blk, 0, stream>>>(ga);
    TS8 gb;
    gb.t[0] = {p.k_w,              w.k_h,    w.k_l,    DD, HDIM};
    gb.t[1] = {p.v_w,              w.v_h,    w.v_l,    DD, HDIM};
    gb.t[2] = {p.mlp0_up_w,        w.up0a_h, w.up0a_l, DD, EE};
    gb.t[3] = {p.mlp0_up_w+(size_t)DD*EE, w.up0b_h, w.up0b_l, DD, EE};
    gb.t[4] = {p.mlp1_up_w,        w.up1a_h, w.up1a_l, DD, EE};
    gb.t[5] = {p.mlp1_up_w+(size_t)DD*EE, w.up1b_h, w.up1b_l, DD, EE};
    gb.t[6] = {p.mlp0_dn_w,        w.dn0_h,  w.dn0_l,  EE, DD};
    gb.t[7] = {p.mlp1_dn_w,        w.dn1_h,  w.dn1_l,  EE, DD};
    tsplit8_k<<<dim3(DD*EE/256, 8), blk, 0, stream>>>(gb);
  }

  ln_z_k<<<RR/4, blk, 0, stream>>>(skip, p.ln_gamma, p.ln_beta, N, Z);
  gemm_mfma<128,1,0><<<g2,blk,0,stream>>>(N,nullptr,w.proj_h,w.proj_l,nullptr,nullptr,
      p.proj_b,nullptr,nullptr,X0, DD,DD,DD);

  gemm_mfma<128,1,0><<<g2,blk,0,stream>>>(X0,nullptr,w.fconv_h,w.fconv_l,nullptr,nullptr,
      p.fconv_b,nullptr,nullptr,XB, DD,DD,DD);
  run_block(p, w, XB, N, Y, XR, CV, ACT, KB, VB, CSA, CSB, OF, stream);

  gemm_mfma<128,1,0><<<g2,blk,0,stream>>>(X0,nullptr,w.bconv_h,w.bconv_l,nullptr,nullptr,
      p.bconv_b,nullptr,nullptr,XB, DD,DD,DD);
  run_block(p, w, XB, N, Y, XR, CV, ACT, KB, VB, CSA, CSB, OB, stream);

  comb_k<<<RR*DD/256, blk, 0, stream>>>(OF, OB, Z, skip, (float*)d_out);
}

// Round 3
// 1436.585 us; speedup vs baseline: 1.6446x; 1.0183x over previous
//
#include <hip/hip_runtime.h>
#include <math.h>
#include <stddef.h>

// ---------------------------------------------------------------------------
// BiDiGemma forward. Round 3: MFMA flash attention (split-bf16 QK^T, bf16 P,
// split V); split-bf16 MFMA GEMMs elsewhere (unchanged from R2).
// ---------------------------------------------------------------------------

#define BB   4
#define SS   4096
#define DD   256
#define HH   4
#define HDIM 64
#define EE   768
#define RR   (BB*SS)
#define WNN  256
#define CH   64
#define NCH  (SS/CH)

typedef __attribute__((ext_vector_type(8))) short bfrag;
typedef __attribute__((ext_vector_type(4))) float f4acc;

__device__ __forceinline__ float geluf(float x){
  return 0.5f*x*(1.0f + erff(x*0.70710678118654752f));
}
__device__ __forceinline__ float sigm(float x){ return 1.0f/(1.0f+expf(-x)); }

__device__ __forceinline__ unsigned short f2bf(float x){
  unsigned u = __float_as_uint(x);
  return (unsigned short)((u + 0x7FFFu + ((u>>16)&1u)) >> 16);
}
__device__ __forceinline__ float bf2f(unsigned short h){
  return __uint_as_float(((unsigned)h) << 16);
}

__device__ __forceinline__ float wredSum(float v){
#pragma unroll
  for(int o=32;o>0;o>>=1) v += __shfl_xor(v,o,64);
  return v;
}

__global__ __launch_bounds__(256) void ln_z_k(const float* __restrict__ skip,
    const float* __restrict__ g, const float* __restrict__ b,
    float* __restrict__ out, float* __restrict__ z)
{
  int row  = blockIdx.x*4 + (threadIdx.x>>6);
  int lane = threadIdx.x & 63;
  float4 v = ((const float4*)(skip + (size_t)row*DD))[lane];
  float s  = v.x+v.y+v.z+v.w;
  float sq = v.x*v.x+v.y*v.y+v.z*v.z+v.w*v.w;
  float si = v.x*sigm(v.x)+v.y*sigm(v.y)+v.z*sigm(v.z)+v.w*sigm(v.w);
  s = wredSum(s); sq = wredSum(sq); si = wredSum(si);
  float mean = s*(1.0f/DD);
  float var  = sq*(1.0f/DD) - mean*mean;
  float inv  = rsqrtf(var + 1e-5f);
  float4 gv = ((const float4*)g)[lane];
  float4 bv = ((const float4*)b)[lane];
  float4 o;
  o.x = (v.x-mean)*inv*gv.x + bv.x;
  o.y = (v.y-mean)*inv*gv.y + bv.y;
  o.z = (v.z-mean)*inv*gv.z + bv.z;
  o.w = (v.w-mean)*inv*gv.w + bv.w;
  ((float4*)(out + (size_t)row*DD))[lane] = o;
  if(lane==0) z[row] = sigm(si*(1.0f/DD));
}

__global__ __launch_bounds__(256) void rms_k(const float* __restrict__ x,
    const float* __restrict__ t, float* __restrict__ out)
{
  int row  = blockIdx.x*4 + (threadIdx.x>>6);
  int lane = threadIdx.x & 63;
  float4 v = ((const float4*)(x + (size_t)row*DD))[lane];
  float sq = v.x*v.x+v.y*v.y+v.z*v.z+v.w*v.w;
  sq = wredSum(sq);
  float inv = rsqrtf(sq*(1.0f/DD) + 1e-6f);
  float4 tv = ((const float4*)t)[lane];
  float4 o;
  o.x = v.x*inv*(1.0f+tv.x);
  o.y = v.y*inv*(1.0f+tv.y);
  o.z = v.z*inv*(1.0f+tv.z);
  o.w = v.w*inv*(1.0f+tv.w);
  ((float4*)(out + (size_t)row*DD))[lane] = o;
}

struct TS  { const float* s; unsigned short* h; unsigned short* l; int K; int N; };
struct TS8 { TS t[8]; };

__global__ __launch_bounds__(256) void tsplit8_k(TS8 g){
  TS tt = g.t[blockIdx.y];
  int idx = blockIdx.x*256 + threadIdx.x;
  int tot = tt.K*tt.N;
  if(idx >= tot) return;
  int k = idx / tt.N;
  int n = idx - k*tt.N;
  float x = tt.s[idx];
  unsigned short hb = f2bf(x);
  unsigned short lb = f2bf(x - bf2f(hb));
  tt.h[(size_t)n*tt.K + k] = hb;
  tt.l[(size_t)n*tt.K + k] = lb;
}

// ---------------------------------------------------------------------------
// Split-bf16 MFMA GEMM (unchanged from R2).
// ---------------------------------------------------------------------------
template<int BN, int MODE, int DUAL>
__global__ __launch_bounds__(256) void gemm_mfma(
    const float* __restrict__ A, const float* __restrict__ A2,
    const unsigned short* __restrict__ B0h, const unsigned short* __restrict__ B0l,
    const unsigned short* __restrict__ B1h, const unsigned short* __restrict__ B1l,
    const float* __restrict__ bias0, const float* __restrict__ bias1,
    const float* __restrict__ Res, float* __restrict__ C,
    int K, int lda, int ldc)
{
  constexpr int NT = BN/32;
  constexpr int ST = 56;
  __shared__ unsigned short Ah[128*ST], Al[128*ST];
  __shared__ unsigned short Bh[BN*ST],  Bl[BN*ST];
  __shared__ unsigned short B2h[DUAL?BN*ST:8], B2l[DUAL?BN*ST:8];

  const int tid  = threadIdx.x;
  const int lane = tid & 63, wave = tid >> 6;
  const int wm = wave >> 1, wn = wave & 1;
  const int bm = blockIdx.y*128, bn = blockIdx.x*BN;
  const int m16 = lane & 15, q = lane >> 4;

  f4acc acc[4][NT];
  f4acc acc2[DUAL?4:1][DUAL?NT:1];
#pragma unroll
  for(int i=0;i<4;i++)
#pragma unroll
    for(int j=0;j<NT;j++){
      acc[i][j] = (f4acc)0.f;
      if constexpr(DUAL) acc2[i][j] = (f4acc)0.f;
    }

  const int s_row  = tid >> 1;
  const int s_half = tid & 1;
  const float* Arow  = A + (size_t)(bm + s_row)*lda + s_half*16;
  const float* A2row = (MODE&4) ? (A2 + (size_t)(bm + s_row)*lda + s_half*16)
                                : (const float*)nullptr;

  for(int k0 = 0; k0 < K; k0 += 32){
#pragma unroll
    for(int c=0;c<4;c++){
      float4 v = *(const float4*)(Arow + k0 + c*4);
      if(MODE&4){
        float4 u = *(const float4*)(A2row + k0 + c*4);
        v.x*=u.x; v.y*=u.y; v.z*=u.z; v.w*=u.w;
      }
      ushort4 hi, lo;
      hi.x=f2bf(v.x); lo.x=f2bf(v.x-bf2f(hi.x));
      hi.y=f2bf(v.y); lo.y=f2bf(v.y-bf2f(hi.y));
      hi.z=f2bf(v.z); lo.z=f2bf(v.z-bf2f(hi.z));
      hi.w=f2bf(v.w); lo.w=f2bf(v.w-bf2f(hi.w));
      *(ushort4*)&Ah[s_row*ST + s_half*16 + c*4] = hi;
      *(ushort4*)&Al[s_row*ST + s_half*16 + c*4] = lo;
    }
    {
      constexpr int CH16 = BN*4;
#pragma unroll
      for(int s0 = 0; s0 < CH16; s0 += 256){
        int s = s0 + tid;
        int n = s >> 2, c = s & 3;
        *(float4*)(Bh + n*ST + c*8) = *(const float4*)(B0h + (size_t)(bn+n)*K + k0 + c*8);
        *(float4*)(Bl + n*ST + c*8) = *(const float4*)(B0l + (size_t)(bn+n)*K + k0 + c*8);
        if constexpr(DUAL){
          *(float4*)(B2h + n*ST + c*8) = *(const float4*)(B1h + (size_t)(bn+n)*K + k0 + c*8);
          *(float4*)(B2l + n*ST + c*8) = *(const float4*)(B1l + (size_t)(bn+n)*K + k0 + c*8);
        }
      }
    }
    __syncthreads();

    bfrag ah[4], al[4], b0hf[NT], b0lf[NT];
    bfrag b1hf[DUAL?NT:1], b1lf[DUAL?NT:1];
#pragma unroll
    for(int mi=0;mi<4;mi++){
      int row = wm*64 + mi*16 + m16;
      ah[mi] = *(const bfrag*)&Ah[row*ST + q*8];
      al[mi] = *(const bfrag*)&Al[row*ST + q*8];
    }
#pragma unroll
    for(int ni=0;ni<NT;ni++){
      int n = wn*(BN/2) + ni*16 + m16;
      b0hf[ni] = *(const bfrag*)&Bh[n*ST + q*8];
      b0lf[ni] = *(const bfrag*)&Bl[n*ST + q*8];
      if constexpr(DUAL){
        b1hf[ni] = *(const bfrag*)&B2h[n*ST + q*8];
        b1lf[ni] = *(const bfrag*)&B2l[n*ST + q*8];
      }
    }
#pragma unroll
    for(int mi=0;mi<4;mi++)
#pragma unroll
      for(int ni=0;ni<NT;ni++){
        acc[mi][ni] = __builtin_amdgcn_mfma_f32_16x16x32_bf16(ah[mi], b0hf[ni], acc[mi][ni],0,0,0);
        acc[mi][ni] = __builtin_amdgcn_mfma_f32_16x16x32_bf16(ah[mi], b0lf[ni], acc[mi][ni],0,0,0);
        acc[mi][ni] = __builtin_amdgcn_mfma_f32_16x16x32_bf16(al[mi], b0hf[ni], acc[mi][ni],0,0,0);
        if constexpr(DUAL){
          acc2[mi][ni] = __builtin_amdgcn_mfma_f32_16x16x32_bf16(ah[mi], b1hf[ni], acc2[mi][ni],0,0,0);
          acc2[mi][ni] = __builtin_amdgcn_mfma_f32_16x16x32_bf16(ah[mi], b1lf[ni], acc2[mi][ni],0,0,0);
          acc2[mi][ni] = __builtin_amdgcn_mfma_f32_16x16x32_bf16(al[mi], b1hf[ni], acc2[mi][ni],0,0,0);
        }
      }
    __syncthreads();
  }

#pragma unroll
  for(int ni=0;ni<NT;ni++){
    const int col = bn + wn*(BN/2) + ni*16 + m16;
    float bv0 = (MODE&1) ? bias0[col] : 0.f;
    float bv1 = DUAL ? bias1[col] : 0.f;
#pragma unroll
    for(int mi=0;mi<4;mi++){
#pragma unroll
      for(int r=0;r<4;r++){
        const int row = bm + wm*64 + mi*16 + q*4 + r;
        float v = acc[mi][ni][r] + bv0;
        if constexpr(DUAL){
          float v2 = acc2[mi][ni][r] + bv1;
          v = geluf(v) * v2;
        } else if(MODE&2){
          v = geluf(v);
        }
        if(MODE&8) v += Res[(size_t)row*ldc + col];
        C[(size_t)row*ldc + col] = v;
      }
    }
  }
}

// fp32 GEMM kept for the block-diagonal gate linears.
template<int BN, int MODE>
__global__ __launch_bounds__(256) void gemm_k(
    const float* __restrict__ A,
    const float* __restrict__ B0,
    const float* __restrict__ bias0,
    float* __restrict__ C,
    int M, int N, int K, int lda, int ldb, int ldc,
    int batA, int batB, int batC, int batBias)
{
  constexpr int BK = 16;
  constexpr int TN = BN/16;
  constexpr int NH = BN/64;
  __shared__ float Ask[BK][132];
  __shared__ float Bs [BK][BN+4];

  const int bz = blockIdx.z;
  const float* Ab  = A  + (size_t)bz*batA;
  const float* Bb  = B0 + (size_t)bz*batB;
  float* Cb = C + (size_t)bz*batC;

  const int bm = blockIdx.y*128, bn = blockIdx.x*BN;
  const int tid = threadIdx.x;
  const int tx = tid & 15, ty = tid >> 4;
  const int ar = tid >> 1, ac = (tid & 1)*8;
  const int br = tid >> 4;

  float acc[8][TN];
#pragma unroll
  for(int i=0;i<8;i++)
#pragma unroll
    for(int j=0;j<TN;j++) acc[i][j]=0.f;

  for(int k0=0;k0<K;k0+=BK){
#pragma unroll
    for(int hf=0;hf<2;hf++){
      float4 av = *(const float4*)(Ab + (size_t)(bm+ar)*lda + (k0+ac+hf*4));
      Ask[ac+hf*4+0][ar]=av.x; Ask[ac+hf*4+1][ar]=av.y;
      Ask[ac+hf*4+2][ar]=av.z; Ask[ac+hf*4+3][ar]=av.w;
    }
    {
      const int bc = (tid&15)*4;
      *(float4*)&Bs[br][bc] = *(const float4*)(Bb + (size_t)(k0+br)*ldb + (bn+bc));
    }
    __syncthreads();
#pragma unroll
    for(int k=0;k<BK;k++){
      float a[8];
      *(float4*)&a[0] = *(const float4*)&Ask[k][ty*8];
      *(float4*)&a[4] = *(const float4*)&Ask[k][ty*8+4];
      float bv[TN];
#pragma unroll
      for(int hh=0;hh<NH;hh++)
        *(float4*)&bv[hh*4] = *(const float4*)&Bs[k][hh*64 + tx*4];
#pragma unroll
      for(int i=0;i<8;i++)
#pragma unroll
        for(int j=0;j<TN;j++)
          acc[i][j] = fmaf(a[i], bv[j], acc[i][j]);
    }
    __syncthreads();
  }

#pragma unroll
  for(int i=0;i<8;i++){
    const int row = bm + ty*8 + i;
#pragma unroll
    for(int hh=0;hh<NH;hh++){
      const int col = bn + hh*64 + tx*4;
      float v0=acc[i][hh*4+0], v1=acc[i][hh*4+1], v2=acc[i][hh*4+2], v3=acc[i][hh*4+3];
      if(MODE&1){
        float4 bbv = *(const float4*)(bias0 + (size_t)bz*batBias + col);
        v0+=bbv.x; v1+=bbv.y; v2+=bbv.z; v3+=bbv.w;
      }
      float4 ov; ov.x=v0; ov.y=v1; ov.z=v2; ov.w=v3;
      *(float4*)(Cb + (size_t)row*ldc + col) = ov;
    }
  }
}

__global__ __launch_bounds__(256) void conv_k(const float* __restrict__ x,
    const float* __restrict__ w, const float* __restrict__ b, float* __restrict__ out)
{
  int idx = blockIdx.x*256 + threadIdx.x;
  int d = idx & (DD-1);
  int r = idx >> 8;
  int s = r & (SS-1);
  float acc = b[d];
#pragma unroll
  for(int i=0;i<4;i++){
    int t = s - 3 + i;
    if(t >= 0) acc += w[i*DD + d] * x[(size_t)(r-3+i)*DD + d];
  }
  out[idx] = acc;
}

__global__ __launch_bounds__(256) void gate_k(const float* __restrict__ x,
    float* __restrict__ ig, float* __restrict__ ag, const float* __restrict__ ap)
{
  int idx = blockIdx.x*256 + threadIdx.x;
  int d = idx & (DD-1);
  int r = idx >> 8;
  int s = r & (SS-1);
  float gx = sigm(ig[idx]);
  float ga = sigm(ag[idx]);
  float a_ = ap[d];
  float sp = (a_ > 20.f) ? a_ : log1pf(expf(a_));
  float la = -8.f * ga * sp;
  float a  = expf(la);
  float mult = (s==0) ? 1.f : sqrtf(fmaxf(-expm1f(2.f*la), 0.f));
  float bt = x[idx] * gx * mult;
  ig[idx] = a;
  ag[idx] = bt;
}

__global__ __launch_bounds__(256) void scan1_k(const float* __restrict__ A,
    const float* __restrict__ Bv, float* __restrict__ csa, float* __restrict__ csb)
{
  int idx = blockIdx.x*256 + threadIdx.x;
  int d = idx & (DD-1);
  int c = (idx >> 8) & (NCH-1);
  int b = idx >> 14;
  size_t base = ((size_t)b*SS + (size_t)c*CH)*DD + d;
  float Aa = 1.f, Bb_ = 0.f;
  for(int t=0;t<CH;t++){
    float a  = A [base + (size_t)t*DD];
    float bb = Bv[base + (size_t)t*DD];
    Aa  = a*Aa;
    Bb_ = a*Bb_ + bb;
  }
  csa[idx] = Aa; csb[idx] = Bb_;
}

__global__ __launch_bounds__(256) void scan2_k(const float* __restrict__ csa,
    float* __restrict__ csb)
{
  int idx = blockIdx.x*256 + threadIdx.x;
  int d = idx & (DD-1);
  int b = idx >> 8;
  float h = 0.f;
  for(int c=0;c<NCH;c++){
    size_t i = ((size_t)b*NCH + c)*DD + d;
    float Aa = csa[i], Bb_ = csb[i];
    csb[i] = h;
    h = Aa*h + Bb_;
  }
}

__global__ __launch_bounds__(256) void scan3_k(const float* __restrict__ A,
    float* __restrict__ Bv, const float* __restrict__ csb)
{
  int idx = blockIdx.x*256 + threadIdx.x;
  int d = idx & (DD-1);
  int c = (idx >> 8) & (NCH-1);
  int b = idx >> 14;
  size_t base = ((size_t)b*SS + (size_t)c*CH)*DD + d;
  float h = csb[idx];
  for(int t=0;t<CH;t++){
    float a  = A [base + (size_t)t*DD];
    float bb = Bv[base + (size_t)t*DD];
    h = a*h + bb;
    Bv[base + (size_t)t*DD] = h;
  }
}

__global__ __launch_bounds__(256) void rope_q_k(float* __restrict__ q)
{
  int idx = blockIdx.x*256 + threadIdx.x;
  int p = idx & 15;
  int h = (idx>>4) & 3;
  int r = idx >> 6;
  int s = r & (SS-1);
  float inv = expf(-(float)p * 0.575646273248511f);
  float t = (float)s * inv;
  float sn, cs; __sincosf(t, &sn, &cs);
  float* base = q + (size_t)r*DD + h*HDIM;
  float x1 = base[p], x2 = base[p+16];
  const float sc = 0.125f;
  base[p]    = (x1*cs - x2*sn)*sc;
  base[p+16] = (x2*cs + x1*sn)*sc;
  base[p+32] *= sc;
  base[p+48] *= sc;
}

__global__ __launch_bounds__(256) void rope_k_k(float* __restrict__ kk)
{
  int idx = blockIdx.x*256 + threadIdx.x;
  int p = idx & 15;
  int r = idx >> 4;
  int s = r & (SS-1);
  float inv = expf(-(float)p * 0.575646273248511f);
  float t = (float)s * inv;
  float sn, cs; __sincosf(t, &sn, &cs);
  float* base = kk + (size_t)r*HDIM;
  float x1 = base[p], x2 = base[p+16];
  base[p]    = x1*cs - x2*sn;
  base[p+16] = x2*cs + x1*sn;
}

// ---------------------------------------------------------------------------
// MFMA flash attention. 64 q-rows/block, 4 waves (16 rows each).
// QK^T: split-bf16 3-term. P: bf16-hi only. PV: P x (Vhi,Vlo) 2-term.
// LDS rows padded to 72 shorts (36 dw; 9 == 1 mod 8 -> b128 frags
// conflict-free per 8-lane phase). P: C-layout -> LDS -> A-layout.
// ---------------------------------------------------------------------------
#define AST 72
__global__ __launch_bounds__(256) void attn_k(const float* __restrict__ Q,
    const float* __restrict__ K, const float* __restrict__ V, float* __restrict__ O)
{
  __shared__ unsigned short Qh[64*AST], Ql[64*AST];
  __shared__ unsigned short Kh[64*AST], Kl[64*AST];
  __shared__ unsigned short Vh[64*AST], Vl[64*AST];
  __shared__ unsigned short Ps[4*16*AST];      // per-wave 16x64, hi only

  const int qt = blockIdx.x & 3, n = blockIdx.x >> 2;
  const int h = blockIdx.y, b = blockIdx.z;
  const int tid = threadIdx.x;
  const int lane = tid & 63, w = tid >> 6;
  const int m16 = lane & 15, q = lane >> 4;
  const int s0 = n*WNN + qt*64;

  // ---- stage Q (64 x 64, hi/lo) ----
#pragma unroll
  for(int rep=0; rep<4; rep++){
    int f4i = rep*256 + tid;
    int r = f4i >> 4, g = f4i & 15;
    float4 v = *(const float4*)(Q + ((size_t)(b*SS + s0 + r))*DD + h*HDIM + g*4);
    ushort4 hi, lo;
    hi.x=f2bf(v.x); lo.x=f2bf(v.x-bf2f(hi.x));
    hi.y=f2bf(v.y); lo.y=f2bf(v.y-bf2f(hi.y));
    hi.z=f2bf(v.z); lo.z=f2bf(v.z-bf2f(hi.z));
    hi.w=f2bf(v.w); lo.w=f2bf(v.w-bf2f(hi.w));
    *(ushort4*)&Qh[r*AST + g*4] = hi;
    *(ushort4*)&Ql[r*AST + g*4] = lo;
  }

  float mrow[4], lrow[4];
  f4acc oacc[4];
#pragma unroll
  for(int i=0;i<4;i++){ mrow[i]=-3.0e38f; lrow[i]=0.f; oacc[i]=(f4acc)0.f; }

  const int ktlo = (n==0) ? 4 : qt;
  const int kthi = qt + 4;
  const int vkg = tid & 15, vdg = tid >> 4;   // V transpose staging coords

  for(int kt=ktlo; kt<=kthi; kt++){
    const int kbase = (n-1)*WNN + kt*64;      // >= 0 for visited tiles
    // ---- stage K (row-major hi/lo) ----
#pragma unroll
    for(int rep=0;rep<4;rep++){
      int f4i = rep*256 + tid;
      int r = f4i >> 4, g = f4i & 15;
      float4 v = *(const float4*)(K + (size_t)(b*SS + kbase + r)*HDIM + g*4);
      ushort4 hi, lo;
      hi.x=f2bf(v.x); lo.x=f2bf(v.x-bf2f(hi.x));
      hi.y=f2bf(v.y); lo.y=f2bf(v.y-bf2f(hi.y));
      hi.z=f2bf(v.z); lo.z=f2bf(v.z-bf2f(hi.z));
      hi.w=f2bf(v.w); lo.w=f2bf(v.w-bf2f(hi.w));
      *(ushort4*)&Kh[r*AST + g*4] = hi;
      *(ushort4*)&Kl[r*AST + g*4] = lo;
    }
    // ---- stage V transposed: Vt[d][key] (4x4 block per thread) ----
    {
      float4 rv[4];
#pragma unroll
      for(int i=0;i<4;i++)
        rv[i] = *(const float4*)(V + (size_t)(b*SS + kbase + vkg*4 + i)*HDIM + vdg*4);
      float c0[4] = {rv[0].x, rv[1].x, rv[2].x, rv[3].x};
      float c1[4] = {rv[0].y, rv[1].y, rv[2].y, rv[3].y};
      float c2[4] = {rv[0].z, rv[1].z, rv[2].z, rv[3].z};
      float c3[4] = {rv[0].w, rv[1].w, rv[2].w, rv[3].w};
      float* cols[4] = {c0, c1, c2, c3};
#pragma unroll
      for(int j=0;j<4;j++){
        ushort4 hi, lo;
        hi.x=f2bf(cols[j][0]); lo.x=f2bf(cols[j][0]-bf2f(hi.x));
        hi.y=f2bf(cols[j][1]); lo.y=f2bf(cols[j][1]-bf2f(hi.y));
        hi.z=f2bf(cols[j][2]); lo.z=f2bf(cols[j][2]-bf2f(hi.z));
        hi.w=f2bf(cols[j][3]); lo.w=f2bf(cols[j][3]-bf2f(hi.w));
        *(ushort4*)&Vh[(vdg*4+j)*AST + vkg*4] = hi;
        *(ushort4*)&Vl[(vdg*4+j)*AST + vkg*4] = lo;
      }
    }
    __syncthreads();

    // ---- S = Q K^T (16 x 64 per wave), 3-term split ----
    f4acc sacc[4];
#pragma unroll
    for(int nt=0;nt<4;nt++) sacc[nt] = (f4acc)0.f;
#pragma unroll
    for(int s=0;s<2;s++){
      bfrag qh_ = *(const bfrag*)&Qh[(w*16+m16)*AST + s*32 + q*8];
      bfrag ql_ = *(const bfrag*)&Ql[(w*16+m16)*AST + s*32 + q*8];
#pragma unroll
      for(int nt=0;nt<4;nt++){
        bfrag kh_ = *(const bfrag*)&Kh[(nt*16+m16)*AST + s*32 + q*8];
        bfrag kl_ = *(const bfrag*)&Kl[(nt*16+m16)*AST + s*32 + q*8];
        sacc[nt] = __builtin_amdgcn_mfma_f32_16x16x32_bf16(qh_, kh_, sacc[nt],0,0,0);
        sacc[nt] = __builtin_amdgcn_mfma_f32_16x16x32_bf16(qh_, kl_, sacc[nt],0,0,0);
        sacc[nt] = __builtin_amdgcn_mfma_f32_16x16x32_bf16(ql_, kh_, sacc[nt],0,0,0);
      }
    }

    // ---- mask + online softmax (C layout: row=q*4+r, col=nt*16+m16) ----
    const bool needlo = (kt == qt+4);   // causal edge
    const bool needhi = (kt == qt);     // window-left edge
#pragma unroll
    for(int r=0;r<4;r++){
      int qp = qt*64 + w*16 + q*4 + r;
      float sv[4];
      float tm = -3.0e38f;
#pragma unroll
      for(int nt=0;nt<4;nt++){
        float scv = sacc[nt][r];
        if(needlo || needhi){
          int kj = kt*64 + nt*16 + m16;
          int diff = qp + WNN - kj;
          bool ok = (!needlo || diff >= 0) && (!needhi || diff <= WNN);
          scv = ok ? scv : -3.0e38f;
        }
        sv[nt] = scv;
        tm = fmaxf(tm, scv);
      }
#pragma unroll
      for(int off=1; off<16; off<<=1) tm = fmaxf(tm, __shfl_xor(tm, off, 64));
      float mn = fmaxf(mrow[r], tm);
      float alpha = __expf(mrow[r]-mn);
      float rs = 0.f;
#pragma unroll
      for(int nt=0;nt<4;nt++){
        float pp = __expf(sv[nt]-mn);
        rs += pp;
        Ps[w*16*AST + (q*4+r)*AST + nt*16 + m16] = f2bf(pp);
      }
#pragma unroll
      for(int off=1; off<16; off<<=1) rs += __shfl_xor(rs, off, 64);
      lrow[r] = lrow[r]*alpha + rs;
      mrow[r] = mn;
#pragma unroll
      for(int nt=0;nt<4;nt++) oacc[nt][r] *= alpha;
    }

    // ---- O += P V (P from wave-private LDS; 2-term on V) ----
#pragma unroll
    for(int s=0;s<2;s++){
      bfrag pa = *(const bfrag*)&Ps[w*16*AST + m16*AST + s*32 + q*8];
#pragma unroll
      for(int nt=0;nt<4;nt++){
        bfrag vh_ = *(const bfrag*)&Vh[(nt*16+m16)*AST + s*32 + q*8];
        bfrag vl_ = *(const bfrag*)&Vl[(nt*16+m16)*AST + s*32 + q*8];
        oacc[nt] = __builtin_amdgcn_mfma_f32_16x16x32_bf16(pa, vh_, oacc[nt],0,0,0);
        oacc[nt] = __builtin_amdgcn_mfma_f32_16x16x32_bf16(pa, vl_, oacc[nt],0,0,0);
      }
    }
    __syncthreads();
  }

  // ---- epilogue: normalize, store (C layout) ----
#pragma unroll
  for(int r=0;r<4;r++){
    float invl = 1.f/lrow[r];
    const size_t rowbase = ((size_t)(b*SS + s0 + w*16 + q*4 + r))*DD + h*HDIM;
#pragma unroll
    for(int nt=0;nt<4;nt++)
      O[rowbase + nt*16 + m16] = oacc[nt][r]*invl;
  }
}

__global__ __launch_bounds__(256) void comb_k(const float* __restrict__ of,
    const float* __restrict__ ob, const float* __restrict__ z,
    const float* __restrict__ skip, float* __restrict__ out)
{
  int idx = blockIdx.x*256 + threadIdx.x;
  int r = idx >> 8;
  out[idx] = z[r]*(of[idx]+ob[idx]) + skip[idx];
}

// ---------------------------------------------------------------------------
struct Params {
  const float *ln_gamma,*ln_beta,*proj_w,*proj_b,*fconv_w,*fconv_b,*bconv_w,*bconv_b,
    *rn0_t,*rn0_c,*ly_w,*ly_b,*lx_w,*lx_b,*lo_w,*lo_b,*c1d_w,*c1d_b,*a_param,
    *ig_w,*ig_b,*ag_w,*ag_b,*mlp0_up_w,*mlp0_up_b,*mlp0_dn_w,*mlp0_dn_b,
    *rn1_t,*rn1_c,*q_w,*k_w,*v_w,*o_w,*o_b,*mlp1_up_w,*mlp1_up_b,*mlp1_dn_w,*mlp1_dn_b;
};

struct WSplit {
  unsigned short *proj_h,*proj_l,*fconv_h,*fconv_l,*bconv_h,*bconv_l,
    *ly_h,*ly_l,*lx_h,*lx_l,*lo_h,*lo_l,*q_h,*q_l,*o_h,*o_l,
    *k_h,*k_l,*v_h,*v_l,
    *up0a_h,*up0a_l,*up0b_h,*up0b_l,*up1a_h,*up1a_l,*up1b_h,*up1b_l,
    *dn0_h,*dn0_l,*dn1_h,*dn1_l;
};

static void run_block(const Params& p, const WSplit& w,
                      float* XB, float* N, float* Y, float* XR,
                      float* CV, float* ACT, float* KB, float* VB,
                      float* CSA, float* CSB, float* OUT, hipStream_t stream)
{
  dim3 blk(256);
  dim3 g2(2,128,1), g64(1,128,1), gbd(1,128,4), gdual(12,128,1);

  // ---- residual block 0: recurrent ----
  rms_k<<<RR/4, blk, 0, stream>>>(XB, p.rn0_t, N);
  gemm_mfma<128,3,0><<<g2,blk,0,stream>>>(N,nullptr,w.ly_h,w.ly_l,nullptr,nullptr,
      p.ly_b,nullptr,nullptr,Y, DD,DD,DD);
  gemm_mfma<128,1,0><<<g2,blk,0,stream>>>(N,nullptr,w.lx_h,w.lx_l,nullptr,nullptr,
      p.lx_b,nullptr,nullptr,XR, DD,DD,DD);
  conv_k<<<RR*DD/256, blk, 0, stream>>>(XR, p.c1d_w, p.c1d_b, CV);
  gemm_k<64,1><<<gbd,blk,0,stream>>>(CV,p.ig_w,p.ig_b,N,
      RR,HDIM,HDIM, DD,HDIM,DD, HDIM, HDIM*HDIM, HDIM, HDIM);
  gemm_k<64,1><<<gbd,blk,0,stream>>>(CV,p.ag_w,p.ag_b,XR,
      RR,HDIM,HDIM, DD,HDIM,DD, HDIM, HDIM*HDIM, HDIM, HDIM);
  gate_k<<<RR*DD/256, blk, 0, stream>>>(CV, N, XR, p.a_param);
  scan1_k<<<BB*NCH*DD/256, blk,0,stream>>>(N, XR, CSA, CSB);
  scan2_k<<<BB*DD/256, blk,0,stream>>>(CSA, CSB);
  scan3_k<<<BB*NCH*DD/256, blk,0,stream>>>(N, XR, CSB);
  gemm_mfma<128,13,0><<<g2,blk,0,stream>>>(XR, Y, w.lo_h,w.lo_l,nullptr,nullptr,
      p.lo_b,nullptr,XB,CV, DD,DD,DD);
  rms_k<<<RR/4,blk,0,stream>>>(CV, p.rn0_c, N);
  gemm_mfma<64,1,1><<<gdual,blk,0,stream>>>(N,nullptr, w.up0a_h,w.up0a_l, w.up0b_h,w.up0b_l,
      p.mlp0_up_b, p.mlp0_up_b+EE, nullptr, ACT, DD,DD,EE);
  gemm_mfma<128,9,0><<<g2,blk,0,stream>>>(ACT,nullptr, w.dn0_h,w.dn0_l,nullptr,nullptr,
      p.mlp0_dn_b,nullptr,CV,XB, EE,EE,DD);

  // ---- residual block 1: local attention ----
  rms_k<<<RR/4,blk,0,stream>>>(XB, p.rn1_t, N);
  gemm_mfma<128,0,0><<<g2,blk,0,stream>>>(N,nullptr,w.q_h,w.q_l,nullptr,nullptr,
      nullptr,nullptr,nullptr,Y, DD,DD,DD);
  gemm_mfma<64,0,0><<<g64,blk,0,stream>>>(N,nullptr,w.k_h,w.k_l,nullptr,nullptr,
      nullptr,nullptr,nullptr,KB, DD,DD,HDIM);
  gemm_mfma<64,0,0><<<g64,blk,0,stream>>>(N,nullptr,w.v_h,w.v_l,nullptr,nullptr,
      nullptr,nullptr,nullptr,VB, DD,DD,HDIM);
  rope_q_k<<<RR*HH*16/256, blk,0,stream>>>(Y);
  rope_k_k<<<RR*16/256, blk,0,stream>>>(KB);
  attn_k<<<dim3(64,4,4),blk,0,stream>>>(Y, KB, VB, XR);
  gemm_mfma<128,9,0><<<g2,blk,0,stream>>>(XR,nullptr,w.o_h,w.o_l,nullptr,nullptr,
      p.o_b,nullptr,XB,CV, DD,DD,DD);
  rms_k<<<RR/4,blk,0,stream>>>(CV, p.rn1_c, N);
  gemm_mfma<64,1,1><<<gdual,blk,0,stream>>>(N,nullptr, w.up1a_h,w.up1a_l, w.up1b_h,w.up1b_l,
      p.mlp1_up_b, p.mlp1_up_b+EE, nullptr, ACT, DD,DD,EE);
  gemm_mfma<128,9,0><<<g2,blk,0,stream>>>(ACT,nullptr, w.dn1_h,w.dn1_l,nullptr,nullptr,
      p.mlp1_dn_b,nullptr,CV,OUT, EE,EE,DD);
}

extern "C" void kernel_launch(void* const* d_in, const int* in_sizes, int n_in,
                              void* d_out, int out_size, void* d_ws, size_t ws_size,
                              hipStream_t stream)
{
  (void)in_sizes; (void)n_in; (void)out_size; (void)ws_size;
  const float* skip = (const float*)d_in[0];
  Params p;
  p.ln_gamma  =(const float*)d_in[1];  p.ln_beta  =(const float*)d_in[2];
  p.proj_w    =(const float*)d_in[3];  p.proj_b   =(const float*)d_in[4];
  p.fconv_w   =(const float*)d_in[5];  p.fconv_b  =(const float*)d_in[6];
  p.bconv_w   =(const float*)d_in[7];  p.bconv_b  =(const float*)d_in[8];
  p.rn0_t     =(const float*)d_in[9];  p.rn0_c    =(const float*)d_in[10];
  p.ly_w      =(const float*)d_in[11]; p.ly_b     =(const float*)d_in[12];
  p.lx_w      =(const float*)d_in[13]; p.lx_b     =(const float*)d_in[14];
  p.lo_w      =(const float*)d_in[15]; p.lo_b     =(const float*)d_in[16];
  p.c1d_w     =(const float*)d_in[17]; p.c1d_b    =(const float*)d_in[18];
  p.a_param   =(const float*)d_in[19];
  p.ig_w      =(const float*)d_in[20]; p.ig_b     =(const float*)d_in[21];
  p.ag_w      =(const float*)d_in[22]; p.ag_b     =(const float*)d_in[23];
  p.mlp0_up_w =(const float*)d_in[24]; p.mlp0_up_b=(const float*)d_in[25];
  p.mlp0_dn_w =(const float*)d_in[26]; p.mlp0_dn_b=(const float*)d_in[27];
  p.rn1_t     =(const float*)d_in[28]; p.rn1_c    =(const float*)d_in[29];
  p.q_w       =(const float*)d_in[30]; p.k_w      =(const float*)d_in[31];
  p.v_w       =(const float*)d_in[32]; p.o_w      =(const float*)d_in[33];
  p.o_b       =(const float*)d_in[34];
  p.mlp1_up_w =(const float*)d_in[35]; p.mlp1_up_b=(const float*)d_in[36];
  p.mlp1_dn_w =(const float*)d_in[37]; p.mlp1_dn_b=(const float*)d_in[38];

  float* ws = (float*)d_ws;
  const size_t RD = (size_t)RR*DD;
  size_t off = 0;
  float* Z   = ws + off; off += 16384;
  float* X0  = ws + off; off += RD;
  float* XB  = ws + off; off += RD;
  float* N   = ws + off; off += RD;
  float* Y   = ws + off; off += RD;
  float* XR  = ws + off; off += RD;
  float* CV  = ws + off; off += RD;
  float* OF  = ws + off; off += RD;
  float* OB  = ws + off; off += RD;
  float* ACT = ws + off; off += (size_t)RR*EE;
  float* KB  = ws + off; off += (size_t)RR*HDIM;
  float* VB  = ws + off; off += (size_t)RR*HDIM;
  float* CSA = ws + off; off += (size_t)BB*NCH*DD;
  float* CSB = ws + off; off += (size_t)BB*NCH*DD;
  off = (off + 3) & ~(size_t)3;

  unsigned short* sp = (unsigned short*)(ws + off);
  WSplit w;
  auto alloc_s = [&](size_t n){ unsigned short* r = sp; sp += n; return r; };
  const size_t SDD = (size_t)DD*DD, SKV = (size_t)DD*HDIM, SUP = (size_t)DD*EE;
  w.proj_h=alloc_s(SDD);  w.proj_l=alloc_s(SDD);
  w.fconv_h=alloc_s(SDD); w.fconv_l=alloc_s(SDD);
  w.bconv_h=alloc_s(SDD); w.bconv_l=alloc_s(SDD);
  w.ly_h=alloc_s(SDD);    w.ly_l=alloc_s(SDD);
  w.lx_h=alloc_s(SDD);    w.lx_l=alloc_s(SDD);
  w.lo_h=alloc_s(SDD);    w.lo_l=alloc_s(SDD);
  w.q_h=alloc_s(SDD);     w.q_l=alloc_s(SDD);
  w.o_h=alloc_s(SDD);     w.o_l=alloc_s(SDD);
  w.k_h=alloc_s(SKV);     w.k_l=alloc_s(SKV);
  w.v_h=alloc_s(SKV);     w.v_l=alloc_s(SKV);
  w.up0a_h=alloc_s(SUP);  w.up0a_l=alloc_s(SUP);
  w.up0b_h=alloc_s(SUP);  w.up0b_l=alloc_s(SUP);
  w.up1a_h=alloc_s(SUP);  w.up1a_l=alloc_s(SUP);
  w.up1b_h=alloc_s(SUP);  w.up1b_l=alloc_s(SUP);
  w.dn0_h=alloc_s(SUP);   w.dn0_l=alloc_s(SUP);
  w.dn1_h=alloc_s(SUP);   w.dn1_l=alloc_s(SUP);

  dim3 blk(256);
  dim3 g2(2,128,1);

  {
    TS8 ga;
    ga.t[0] = {p.proj_w,  w.proj_h,  w.proj_l,  DD, DD};
    ga.t[1] = {p.fconv_w, w.fconv_h, w.fconv_l, DD, DD};
    ga.t[2] = {p.bconv_w, w.bconv_h, w.bconv_l, DD, DD};
    ga.t[3] = {p.ly_w,    w.ly_h,    w.ly_l,    DD, DD};
    ga.t[4] = {p.lx_w,    w.lx_h,    w.lx_l,    DD, DD};
    ga.t[5] = {p.lo_w,    w.lo_h,    w.lo_l,    DD, DD};
    ga.t[6] = {p.q_w,     w.q_h,     w.q_l,     DD, DD};
    ga.t[7] = {p.o_w,     w.o_h,     w.o_l,     DD, DD};
    tsplit8_k<<<dim3(DD*DD/256, 8), blk, 0, stream>>>(ga);
    TS8 gb;
    gb.t[0] = {p.k_w,              w.k_h,    w.k_l,    DD, HDIM};
    gb.t[1] = {p.v_w,              w.v_h,    w.v_l,    DD, HDIM};
    gb.t[2] = {p.mlp0_up_w,        w.up0a_h, w.up0a_l, DD, EE};
    gb.t[3] = {p.mlp0_up_w+(size_t)DD*EE, w.up0b_h, w.up0b_l, DD, EE};
    gb.t[4] = {p.mlp1_up_w,        w.up1a_h, w.up1a_l, DD, EE};
    gb.t[5] = {p.mlp1_up_w+(size_t)DD*EE, w.up1b_h, w.up1b_l, DD, EE};
    gb.t[6] = {p.mlp0_dn_w,        w.dn0_h,  w.dn0_l,  EE, DD};
    gb.t[7] = {p.mlp1_dn_w,        w.dn1_h,  w.dn1_l,  EE, DD};
    tsplit8_k<<<dim3(DD*EE/256, 8), blk, 0, stream>>>(gb);
  }

  ln_z_k<<<RR/4, blk, 0, stream>>>(skip, p.ln_gamma, p.ln_beta, N, Z);
  gemm_mfma<128,1,0><<<g2,blk,0,stream>>>(N,nullptr,w.proj_h,w.proj_l,nullptr,nullptr,
      p.proj_b,nullptr,nullptr,X0, DD,DD,DD);

  gemm_mfma<128,1,0><<<g2,blk,0,stream>>>(X0,nullptr,w.fconv_h,w.fconv_l,nullptr,nullptr,
      p.fconv_b,nullptr,nullptr,XB, DD,DD,DD);
  run_block(p, w, XB, N, Y, XR, CV, ACT, KB, VB, CSA, CSB, OF, stream);

  gemm_mfma<128,1,0><<<g2,blk,0,stream>>>(X0,nullptr,w.bconv_h,w.bconv_l,nullptr,nullptr,
      p.bconv_b,nullptr,nullptr,XB, DD,DD,DD);
  run_block(p, w, XB, N, Y, XR, CV, ACT, KB, VB, CSA, CSB, OB, stream);

  comb_k<<<RR*DD/256, blk, 0, stream>>>(OF, OB, Z, skip, (float*)d_out);
}

// Round 5
// 1227.076 us; speedup vs baseline: 1.9254x; 1.1707x over previous
//
#include <hip/hip_runtime.h>
#include <math.h>
#include <stddef.h>

// ---------------------------------------------------------------------------
// BiDiGemma forward. Round 5: R4 dataflow (pre-split bf16 activation planes,
// fused RoPE/V^T epilogues, register-Q flash attention) with staging fixed:
//   - all LDS copies are 8-short float4 chunks covering full rows
//   - ST=40 shorts (80 B): 16B-aligned rows, 2-way-max bank aliasing (free)
//   - correct workspace sizes for KP planes and V^T
//   - block-0 MLP always uses mlp0 weights, block-1 always mlp1
// ---------------------------------------------------------------------------

#define BB   4
#define SS   4096
#define DD   256
#define HH   4
#define HDIM 64
#define EE   768
#define RR   (BB*SS)
#define WNN  256
#define CH   64
#define NCH  (SS/CH)

typedef __attribute__((ext_vector_type(8))) short bfrag;
typedef __attribute__((ext_vector_type(4))) float f4acc;

__device__ __forceinline__ float geluf(float x){
  return 0.5f*x*(1.0f + erff(x*0.70710678118654752f));
}
__device__ __forceinline__ float sigm(float x){ return 1.0f/(1.0f+expf(-x)); }

__device__ __forceinline__ unsigned short f2bf(float x){
  unsigned u = __float_as_uint(x);
  return (unsigned short)((u + 0x7FFFu + ((u>>16)&1u)) >> 16);
}
__device__ __forceinline__ float bf2f(unsigned short h){
  return __uint_as_float(((unsigned)h) << 16);
}
__device__ __forceinline__ void split2(float v, unsigned short* h, unsigned short* l){
  unsigned short hb = f2bf(v);
  *h = hb; *l = f2bf(v - bf2f(hb));
}

__device__ __forceinline__ float wredSum(float v){
#pragma unroll
  for(int o=32;o>0;o>>=1) v += __shfl_xor(v,o,64);
  return v;
}

// ---------------------------------------------------------------------------
// LayerNorm(skip) -> hi/lo planes ; z = sigmoid(mean(silu(skip)))
// ---------------------------------------------------------------------------
__global__ __launch_bounds__(256) void ln_z_k(const float* __restrict__ skip,
    const float* __restrict__ g, const float* __restrict__ b,
    unsigned short* __restrict__ oh, unsigned short* __restrict__ ol,
    float* __restrict__ z)
{
  int row  = blockIdx.x*4 + (threadIdx.x>>6);
  int lane = threadIdx.x & 63;
  float4 v = ((const float4*)(skip + (size_t)row*DD))[lane];
  float s  = v.x+v.y+v.z+v.w;
  float sq = v.x*v.x+v.y*v.y+v.z*v.z+v.w*v.w;
  float si = v.x*sigm(v.x)+v.y*sigm(v.y)+v.z*sigm(v.z)+v.w*sigm(v.w);
  s = wredSum(s); sq = wredSum(sq); si = wredSum(si);
  float mean = s*(1.0f/DD);
  float var  = sq*(1.0f/DD) - mean*mean;
  float inv  = rsqrtf(var + 1e-5f);
  float4 gv = ((const float4*)g)[lane];
  float4 bv = ((const float4*)b)[lane];
  float o0 = (v.x-mean)*inv*gv.x + bv.x;
  float o1 = (v.y-mean)*inv*gv.y + bv.y;
  float o2 = (v.z-mean)*inv*gv.z + bv.z;
  float o3 = (v.w-mean)*inv*gv.w + bv.w;
  ushort4 hi, lo;
  split2(o0,&hi.x,&lo.x); split2(o1,&hi.y,&lo.y);
  split2(o2,&hi.z,&lo.z); split2(o3,&hi.w,&lo.w);
  ((ushort4*)(oh + (size_t)row*DD))[lane] = hi;
  ((ushort4*)(ol + (size_t)row*DD))[lane] = lo;
  if(lane==0) z[row] = sigm(si*(1.0f/DD));
}

// ---------------------------------------------------------------------------
// RMSNorm -> hi/lo planes
// ---------------------------------------------------------------------------
__global__ __launch_bounds__(256) void rms_k(const float* __restrict__ x,
    const float* __restrict__ t,
    unsigned short* __restrict__ oh, unsigned short* __restrict__ ol)
{
  int row  = blockIdx.x*4 + (threadIdx.x>>6);
  int lane = threadIdx.x & 63;
  float4 v = ((const float4*)(x + (size_t)row*DD))[lane];
  float sq = v.x*v.x+v.y*v.y+v.z*v.z+v.w*v.w;
  sq = wredSum(sq);
  float inv = rsqrtf(sq*(1.0f/DD) + 1e-6f);
  float4 tv = ((const float4*)t)[lane];
  float o0 = v.x*inv*(1.0f+tv.x);
  float o1 = v.y*inv*(1.0f+tv.y);
  float o2 = v.z*inv*(1.0f+tv.z);
  float o3 = v.w*inv*(1.0f+tv.w);
  ushort4 hi, lo;
  split2(o0,&hi.x,&lo.x); split2(o1,&hi.y,&lo.y);
  split2(o2,&hi.z,&lo.z); split2(o3,&hi.w,&lo.w);
  ((ushort4*)(oh + (size_t)row*DD))[lane] = hi;
  ((ushort4*)(ol + (size_t)row*DD))[lane] = lo;
}

// ---------------------------------------------------------------------------
// Weight transpose + split
// ---------------------------------------------------------------------------
struct TS  { const float* s; unsigned short* h; unsigned short* l; int K; int N; };
struct TS8 { TS t[8]; };

__global__ __launch_bounds__(256) void tsplit8_k(TS8 g){
  TS tt = g.t[blockIdx.y];
  int idx = blockIdx.x*256 + threadIdx.x;
  int tot = tt.K*tt.N;
  if(idx >= tot) return;
  int k = idx / tt.N;
  int n = idx - k*tt.N;
  float x = tt.s[idx];
  unsigned short hb = f2bf(x);
  unsigned short lb = f2bf(x - bf2f(hb));
  tt.h[(size_t)n*tt.K + k] = hb;
  tt.l[(size_t)n*tt.K + k] = lb;
}

// ---------------------------------------------------------------------------
// Split-bf16 MFMA GEMM, pre-split A planes (pure copy staging).
// MODE bits: 1=bias0, 2=gelu, 8=+Res(fp32).
// DUAL: C = gelu(A@B0+b0)*(A@B1+b1).
// OUT: 0=fp32 C; 1=hi/lo planes; 2=RoPE-q planes (BN=128, *0.125);
//      3=RoPE-k planes (BN=64); 4=V^T bf16 (BN=64, Ch = Vt [b][64][SS]).
// ST=40 shorts (80 B): rows 16B-aligned; 20-dw stride -> 2-way aliasing max.
// ---------------------------------------------------------------------------
template<int BN, int MODE, int DUAL, int OUT>
__global__ __launch_bounds__(256) void gemm_mfma(
    const unsigned short* __restrict__ Ah_g, const unsigned short* __restrict__ Al_g,
    const unsigned short* __restrict__ B0h, const unsigned short* __restrict__ B0l,
    const unsigned short* __restrict__ B1h, const unsigned short* __restrict__ B1l,
    const float* __restrict__ bias0, const float* __restrict__ bias1,
    const float* __restrict__ Res, float* __restrict__ C,
    unsigned short* __restrict__ Ch, unsigned short* __restrict__ Cl,
    int K, int lda, int ldc)
{
  constexpr int NT = BN/32;
  constexpr int ST = 40;
  __shared__ unsigned short Ash[128*ST], Asl[128*ST];
  __shared__ unsigned short Bsh[BN*ST],  Bsl[BN*ST];
  __shared__ unsigned short B2h[DUAL?BN*ST:8], B2l[DUAL?BN*ST:8];

  const int tid  = threadIdx.x;
  const int lane = tid & 63, wave = tid >> 6;
  const int wm = wave >> 1, wn = wave & 1;
  const int bm = blockIdx.y*128, bn = blockIdx.x*BN;
  const int m16 = lane & 15, q = lane >> 4;

  f4acc acc[4][NT];
  f4acc acc2[DUAL?4:1][DUAL?NT:1];
#pragma unroll
  for(int i=0;i<4;i++)
#pragma unroll
    for(int j=0;j<NT;j++){
      acc[i][j] = (f4acc)0.f;
      if constexpr(DUAL) acc2[i][j] = (f4acc)0.f;
    }

  const int arow = tid >> 1, ahalf = tid & 1;

  for(int k0 = 0; k0 < K; k0 += 32){
    // ---- A stage: 2 x float4 (8 shorts each) per plane per thread ----
#pragma unroll
    for(int c=0;c<2;c++){
      *(float4*)&Ash[arow*ST + ahalf*16 + c*8] =
        *(const float4*)(Ah_g + (size_t)(bm+arow)*lda + k0 + ahalf*16 + c*8);
      *(float4*)&Asl[arow*ST + ahalf*16 + c*8] =
        *(const float4*)(Al_g + (size_t)(bm+arow)*lda + k0 + ahalf*16 + c*8);
    }
    // ---- B stage ----
    if constexpr(BN==128){
#pragma unroll
      for(int c=0;c<2;c++){
        *(float4*)&Bsh[arow*ST + ahalf*16 + c*8] =
          *(const float4*)(B0h + (size_t)(bn+arow)*K + k0 + ahalf*16 + c*8);
        *(float4*)&Bsl[arow*ST + ahalf*16 + c*8] =
          *(const float4*)(B0l + (size_t)(bn+arow)*K + k0 + ahalf*16 + c*8);
      }
    } else if constexpr(!DUAL){
      int plane = tid >> 7, t2 = tid & 127;
      int row = t2 >> 1, half = t2 & 1;
      const unsigned short* src = plane ? B0l : B0h;
      unsigned short* dst = plane ? Bsl : Bsh;
#pragma unroll
      for(int c=0;c<2;c++)
        *(float4*)&dst[row*ST + half*16 + c*8] =
          *(const float4*)(src + (size_t)(bn+row)*K + k0 + half*16 + c*8);
    } else {
      int plane = tid >> 6, row = tid & 63;
      const unsigned short* src = (plane==0)?B0h:(plane==1)?B0l:(plane==2)?B1h:B1l;
      unsigned short* dst = (plane==0)?Bsh:(plane==1)?Bsl:(plane==2)?B2h:B2l;
#pragma unroll
      for(int c=0;c<4;c++)
        *(float4*)&dst[row*ST + c*8] =
          *(const float4*)(src + (size_t)(bn+row)*K + k0 + c*8);
    }
    __syncthreads();

    bfrag ah[4], al[4], b0hf[NT], b0lf[NT];
    bfrag b1hf[DUAL?NT:1], b1lf[DUAL?NT:1];
#pragma unroll
    for(int mi=0;mi<4;mi++){
      int row = wm*64 + mi*16 + m16;
      ah[mi] = *(const bfrag*)&Ash[row*ST + q*8];
      al[mi] = *(const bfrag*)&Asl[row*ST + q*8];
    }
#pragma unroll
    for(int ni=0;ni<NT;ni++){
      int n = wn*(BN/2) + ni*16 + m16;
      b0hf[ni] = *(const bfrag*)&Bsh[n*ST + q*8];
      b0lf[ni] = *(const bfrag*)&Bsl[n*ST + q*8];
      if constexpr(DUAL){
        b1hf[ni] = *(const bfrag*)&B2h[n*ST + q*8];
        b1lf[ni] = *(const bfrag*)&B2l[n*ST + q*8];
      }
    }
#pragma unroll
    for(int mi=0;mi<4;mi++)
#pragma unroll
      for(int ni=0;ni<NT;ni++){
        acc[mi][ni] = __builtin_amdgcn_mfma_f32_16x16x32_bf16(ah[mi], b0hf[ni], acc[mi][ni],0,0,0);
        acc[mi][ni] = __builtin_amdgcn_mfma_f32_16x16x32_bf16(ah[mi], b0lf[ni], acc[mi][ni],0,0,0);
        acc[mi][ni] = __builtin_amdgcn_mfma_f32_16x16x32_bf16(al[mi], b0hf[ni], acc[mi][ni],0,0,0);
        if constexpr(DUAL){
          acc2[mi][ni] = __builtin_amdgcn_mfma_f32_16x16x32_bf16(ah[mi], b1hf[ni], acc2[mi][ni],0,0,0);
          acc2[mi][ni] = __builtin_amdgcn_mfma_f32_16x16x32_bf16(ah[mi], b1lf[ni], acc2[mi][ni],0,0,0);
          acc2[mi][ni] = __builtin_amdgcn_mfma_f32_16x16x32_bf16(al[mi], b1hf[ni], acc2[mi][ni],0,0,0);
        }
      }
    __syncthreads();
  }

  // ---- epilogue (C/D layout: col = lane&15, row = q*4 + r) ----
  if constexpr(OUT==0 || OUT==1){
#pragma unroll
    for(int ni=0;ni<NT;ni++){
      const int col = bn + wn*(BN/2) + ni*16 + m16;
      float bv0 = (MODE&1) ? bias0[col] : 0.f;
      float bv1 = DUAL ? bias1[col] : 0.f;
#pragma unroll
      for(int mi=0;mi<4;mi++){
#pragma unroll
        for(int r=0;r<4;r++){
          const int row = bm + wm*64 + mi*16 + q*4 + r;
          float v = acc[mi][ni][r] + bv0;
          if constexpr(DUAL){
            float v2 = acc2[mi][ni][r] + bv1;
            v = geluf(v) * v2;
          } else if(MODE&2){
            v = geluf(v);
          }
          if(MODE&8) v += Res[(size_t)row*ldc + col];
          if constexpr(OUT==0){
            C[(size_t)row*ldc + col] = v;
          } else {
            unsigned short hb = f2bf(v);
            Ch[(size_t)row*ldc + col] = hb;
            Cl[(size_t)row*ldc + col] = f2bf(v - bf2f(hb));
          }
        }
      }
    }
  } else if constexpr(OUT==2){
    // RoPE-q: BN=128, each wave covers one 64-wide head.
    const int hb = bn + wn*64;
    const float p = (float)m16;
    const float invf = __expf(-p * 0.575646273248511f);
#pragma unroll
    for(int mi=0;mi<4;mi++){
#pragma unroll
      for(int r=0;r<4;r++){
        const int row = bm + wm*64 + mi*16 + q*4 + r;
        const int s = row & (SS-1);
        float t = (float)s * invf;
        float sn, cs; __sincosf(t, &sn, &cs);
        float x1 = acc[mi][0][r], x2 = acc[mi][1][r];
        float v0 = (x1*cs - x2*sn)*0.125f;
        float v1 = (x2*cs + x1*sn)*0.125f;
        float v2 = acc[mi][2][r]*0.125f;
        float v3 = acc[mi][3][r]*0.125f;
        size_t base = (size_t)row*ldc + hb;
        unsigned short hh;
        hh=f2bf(v0); Ch[base+m16]=hh;    Cl[base+m16]   =f2bf(v0-bf2f(hh));
        hh=f2bf(v1); Ch[base+16+m16]=hh; Cl[base+16+m16]=f2bf(v1-bf2f(hh));
        hh=f2bf(v2); Ch[base+32+m16]=hh; Cl[base+32+m16]=f2bf(v2-bf2f(hh));
        hh=f2bf(v3); Ch[base+48+m16]=hh; Cl[base+48+m16]=f2bf(v3-bf2f(hh));
      }
    }
  } else if constexpr(OUT==3){
    // RoPE-k: BN=64. wn=0: rotate (cols 0..31); wn=1: copy (cols 32..63).
    const float p = (float)m16;
    const float invf = __expf(-p * 0.575646273248511f);
#pragma unroll
    for(int mi=0;mi<4;mi++){
#pragma unroll
      for(int r=0;r<4;r++){
        const int row = bm + wm*64 + mi*16 + q*4 + r;
        const int s = row & (SS-1);
        float v0, v1;
        if(wn==0){
          float t = (float)s * invf;
          float sn, cs; __sincosf(t, &sn, &cs);
          float x1 = acc[mi][0][r], x2 = acc[mi][1][r];
          v0 = x1*cs - x2*sn;
          v1 = x2*cs + x1*sn;
        } else {
          v0 = acc[mi][0][r]; v1 = acc[mi][1][r];
        }
        size_t base = (size_t)row*ldc + wn*32;
        unsigned short hh;
        hh=f2bf(v0); Ch[base+m16]=hh;    Cl[base+m16]   =f2bf(v0-bf2f(hh));
        hh=f2bf(v1); Ch[base+16+m16]=hh; Cl[base+16+m16]=f2bf(v1-bf2f(hh));
      }
    }
  } else if constexpr(OUT==4){
    // V^T bf16: Ch = Vt [b][64][SS]; ushort4 over 4 consecutive s.
#pragma unroll
    for(int ni=0;ni<NT;ni++){
      const int col = wn*32 + ni*16 + m16;
#pragma unroll
      for(int mi=0;mi<4;mi++){
        const int rowb = bm + wm*64 + mi*16 + q*4;
        const int b = rowb >> 12, sl = rowb & (SS-1);
        ushort4 hv;
        hv.x = f2bf(acc[mi][ni][0]); hv.y = f2bf(acc[mi][ni][1]);
        hv.z = f2bf(acc[mi][ni][2]); hv.w = f2bf(acc[mi][ni][3]);
        *(ushort4*)(Ch + ((size_t)(b*64 + col))*SS + sl) = hv;
      }
    }
  }
}

// fp32 GEMM for block-diagonal gate linears.
template<int BN, int MODE>
__global__ __launch_bounds__(256) void gemm_k(
    const float* __restrict__ A,
    const float* __restrict__ B0,
    const float* __restrict__ bias0,
    float* __restrict__ C,
    int M, int N, int K, int lda, int ldb, int ldc,
    int batA, int batB, int batC, int batBias)
{
  constexpr int BK = 16;
  constexpr int TN = BN/16;
  constexpr int NH = BN/64;
  __shared__ float Ask[BK][132];
  __shared__ float Bs [BK][BN+4];

  const int bz = blockIdx.z;
  const float* Ab  = A  + (size_t)bz*batA;
  const float* Bb  = B0 + (size_t)bz*batB;
  float* Cb = C + (size_t)bz*batC;

  const int bm = blockIdx.y*128, bn = blockIdx.x*BN;
  const int tid = threadIdx.x;
  const int tx = tid & 15, ty = tid >> 4;
  const int ar = tid >> 1, ac = (tid & 1)*8;
  const int br = tid >> 4;

  float acc[8][TN];
#pragma unroll
  for(int i=0;i<8;i++)
#pragma unroll
    for(int j=0;j<TN;j++) acc[i][j]=0.f;

  for(int k0=0;k0<K;k0+=BK){
#pragma unroll
    for(int hf=0;hf<2;hf++){
      float4 av = *(const float4*)(Ab + (size_t)(bm+ar)*lda + (k0+ac+hf*4));
      Ask[ac+hf*4+0][ar]=av.x; Ask[ac+hf*4+1][ar]=av.y;
      Ask[ac+hf*4+2][ar]=av.z; Ask[ac+hf*4+3][ar]=av.w;
    }
    {
      const int bc = (tid&15)*4;
      *(float4*)&Bs[br][bc] = *(const float4*)(Bb + (size_t)(k0+br)*ldb + (bn+bc));
    }
    __syncthreads();
#pragma unroll
    for(int k=0;k<BK;k++){
      float a[8];
      *(float4*)&a[0] = *(const float4*)&Ask[k][ty*8];
      *(float4*)&a[4] = *(const float4*)&Ask[k][ty*8+4];
      float bv[TN];
#pragma unroll
      for(int hh=0;hh<NH;hh++)
        *(float4*)&bv[hh*4] = *(const float4*)&Bs[k][hh*64 + tx*4];
#pragma unroll
      for(int i=0;i<8;i++)
#pragma unroll
        for(int j=0;j<TN;j++)
          acc[i][j] = fmaf(a[i], bv[j], acc[i][j]);
    }
    __syncthreads();
  }

#pragma unroll
  for(int i=0;i<8;i++){
    const int row = bm + ty*8 + i;
#pragma unroll
    for(int hh=0;hh<NH;hh++){
      const int col = bn + hh*64 + tx*4;
      float v0=acc[i][hh*4+0], v1=acc[i][hh*4+1], v2=acc[i][hh*4+2], v3=acc[i][hh*4+3];
      if(MODE&1){
        float4 bbv = *(const float4*)(bias0 + (size_t)bz*batBias + col);
        v0+=bbv.x; v1+=bbv.y; v2+=bbv.z; v3+=bbv.w;
      }
      float4 ov; ov.x=v0; ov.y=v1; ov.z=v2; ov.w=v3;
      *(float4*)(Cb + (size_t)row*ldc + col) = ov;
    }
  }
}

__global__ __launch_bounds__(256) void conv_k(const float* __restrict__ x,
    const float* __restrict__ w, const float* __restrict__ b, float* __restrict__ out)
{
  int idx = blockIdx.x*256 + threadIdx.x;
  int d = idx & (DD-1);
  int r = idx >> 8;
  int s = r & (SS-1);
  float acc = b[d];
#pragma unroll
  for(int i=0;i<4;i++){
    int t = s - 3 + i;
    if(t >= 0) acc += w[i*DD + d] * x[(size_t)(r-3+i)*DD + d];
  }
  out[idx] = acc;
}

__global__ __launch_bounds__(256) void gate_k(const float* __restrict__ x,
    float* __restrict__ ig, float* __restrict__ ag, const float* __restrict__ ap)
{
  int idx = blockIdx.x*256 + threadIdx.x;
  int d = idx & (DD-1);
  int r = idx >> 8;
  int s = r & (SS-1);
  float gx = sigm(ig[idx]);
  float ga = sigm(ag[idx]);
  float a_ = ap[d];
  float sp = (a_ > 20.f) ? a_ : log1pf(expf(a_));
  float la = -8.f * ga * sp;
  float a  = expf(la);
  float mult = (s==0) ? 1.f : sqrtf(fmaxf(-expm1f(2.f*la), 0.f));
  float bt = x[idx] * gx * mult;
  ig[idx] = a;
  ag[idx] = bt;
}

__global__ __launch_bounds__(256) void scan1_k(const float* __restrict__ A,
    const float* __restrict__ Bv, float* __restrict__ csa, float* __restrict__ csb)
{
  int idx = blockIdx.x*256 + threadIdx.x;
  int d = idx & (DD-1);
  int c = (idx >> 8) & (NCH-1);
  int b = idx >> 14;
  size_t base = ((size_t)b*SS + (size_t)c*CH)*DD + d;
  float Aa = 1.f, Bb_ = 0.f;
  for(int t=0;t<CH;t++){
    float a  = A [base + (size_t)t*DD];
    float bb = Bv[base + (size_t)t*DD];
    Aa  = a*Aa;
    Bb_ = a*Bb_ + bb;
  }
  csa[idx] = Aa; csb[idx] = Bb_;
}

__global__ __launch_bounds__(256) void scan2_k(const float* __restrict__ csa,
    float* __restrict__ csb)
{
  int idx = blockIdx.x*256 + threadIdx.x;
  int d = idx & (DD-1);
  int b = idx >> 8;
  float h = 0.f;
  for(int c=0;c<NCH;c++){
    size_t i = ((size_t)b*NCH + c)*DD + d;
    float Aa = csa[i], Bb_ = csb[i];
    csb[i] = h;
    h = Aa*h + Bb_;
  }
}

// scan3: finish recurrence, multiply by gelu branch y, write hi/lo planes.
__global__ __launch_bounds__(256) void scan3_k(const float* __restrict__ A,
    const float* __restrict__ Bv, const float* __restrict__ csb,
    const float* __restrict__ Y,
    unsigned short* __restrict__ Hh, unsigned short* __restrict__ Hl)
{
  int idx = blockIdx.x*256 + threadIdx.x;
  int d = idx & (DD-1);
  int c = (idx >> 8) & (NCH-1);
  int b = idx >> 14;
  size_t base = ((size_t)b*SS + (size_t)c*CH)*DD + d;
  float h = csb[idx];
  for(int t=0;t<CH;t++){
    float a  = A [base + (size_t)t*DD];
    float bb = Bv[base + (size_t)t*DD];
    h = a*h + bb;
    float v = h * Y[base + (size_t)t*DD];
    unsigned short hb = f2bf(v);
    Hh[base + (size_t)t*DD] = hb;
    Hl[base + (size_t)t*DD] = f2bf(v - bf2f(hb));
  }
}

// ---------------------------------------------------------------------------
// MFMA flash attention: Q frags in registers (pre-split planes), K hi/lo +
// V^T bf16 staged via full-row 8-short chunks. LDS 36.9 KB -> 4 blocks/CU.
// ---------------------------------------------------------------------------
#define AST 72
__global__ __launch_bounds__(256) void attn_k(
    const unsigned short* __restrict__ Qh, const unsigned short* __restrict__ Ql,
    const unsigned short* __restrict__ Kh, const unsigned short* __restrict__ Kl,
    const unsigned short* __restrict__ Vt,
    unsigned short* __restrict__ Oh, unsigned short* __restrict__ Ol)
{
  __shared__ unsigned short Ksh[64*AST], Ksl[64*AST], Vsh[64*AST];
  __shared__ unsigned short Ps[4*16*AST];

  const int qt = blockIdx.x & 3, n = blockIdx.x >> 2;
  const int h = blockIdx.y, b = blockIdx.z;
  const int tid = threadIdx.x;
  const int lane = tid & 63, w = tid >> 6;
  const int m16 = lane & 15, q = lane >> 4;
  const int s0 = n*WNN + qt*64;

  // Q fragments from global (A-layout: row=m16, k=q*8 + s*32)
  const size_t qro = ((size_t)(b*SS + s0 + w*16 + m16))*DD + h*HDIM + q*8;
  bfrag qh0 = *(const bfrag*)(Qh + qro);
  bfrag qh1 = *(const bfrag*)(Qh + qro + 32);
  bfrag ql0 = *(const bfrag*)(Ql + qro);
  bfrag ql1 = *(const bfrag*)(Ql + qro + 32);

  float mrow[4], lrow[4];
  f4acc oacc[4];
#pragma unroll
  for(int i=0;i<4;i++){ mrow[i]=-3.0e38f; lrow[i]=0.f; oacc[i]=(f4acc)0.f; }

  const int ktlo = (n==0) ? 4 : qt;
  const int kthi = qt + 4;
  const int sr = tid >> 2, sc = tid & 3;   // 64 rows x 4 threads

  for(int kt=ktlo; kt<=kthi; kt++){
    const int kbase = (n-1)*WNN + kt*64;
    // stage K hi/lo rows + V^T rows: 2 chunks of 8 shorts per plane per thread
#pragma unroll
    for(int cc=0; cc<2; cc++){
      int g = sc + cc*4;   // 0..7
      *(float4*)&Ksh[sr*AST + g*8] =
        *(const float4*)(Kh + (size_t)(b*SS + kbase + sr)*HDIM + g*8);
      *(float4*)&Ksl[sr*AST + g*8] =
        *(const float4*)(Kl + (size_t)(b*SS + kbase + sr)*HDIM + g*8);
      *(float4*)&Vsh[sr*AST + g*8] =
        *(const float4*)(Vt + ((size_t)(b*64 + sr))*SS + kbase + g*8);
    }
    __syncthreads();

    // S = Q K^T (3-term)
    f4acc sacc[4];
#pragma unroll
    for(int nt=0;nt<4;nt++) sacc[nt] = (f4acc)0.f;
#pragma unroll
    for(int nt=0;nt<4;nt++){
      const int kr = (nt*16+m16)*AST;
      bfrag kh0 = *(const bfrag*)&Ksh[kr + q*8];
      bfrag kh1 = *(const bfrag*)&Ksh[kr + 32 + q*8];
      bfrag kl0 = *(const bfrag*)&Ksl[kr + q*8];
      bfrag kl1 = *(const bfrag*)&Ksl[kr + 32 + q*8];
      sacc[nt] = __builtin_amdgcn_mfma_f32_16x16x32_bf16(qh0, kh0, sacc[nt],0,0,0);
      sacc[nt] = __builtin_amdgcn_mfma_f32_16x16x32_bf16(qh0, kl0, sacc[nt],0,0,0);
      sacc[nt] = __builtin_amdgcn_mfma_f32_16x16x32_bf16(ql0, kh0, sacc[nt],0,0,0);
      sacc[nt] = __builtin_amdgcn_mfma_f32_16x16x32_bf16(qh1, kh1, sacc[nt],0,0,0);
      sacc[nt] = __builtin_amdgcn_mfma_f32_16x16x32_bf16(qh1, kl1, sacc[nt],0,0,0);
      sacc[nt] = __builtin_amdgcn_mfma_f32_16x16x32_bf16(ql1, kh1, sacc[nt],0,0,0);
    }

    // mask (edges only) + online softmax; write P (bf16) to wave-private LDS
    const bool needlo = (kt == qt+4);
    const bool needhi = (kt == qt);
#pragma unroll
    for(int r=0;r<4;r++){
      int qp = qt*64 + w*16 + q*4 + r;
      float sv[4];
      float tm = -3.0e38f;
#pragma unroll
      for(int nt=0;nt<4;nt++){
        float scv = sacc[nt][r];
        if(needlo || needhi){
          int kj = kt*64 + nt*16 + m16;
          int diff = qp + WNN - kj;
          bool ok = (!needlo || diff >= 0) && (!needhi || diff <= WNN);
          scv = ok ? scv : -3.0e38f;
        }
        sv[nt] = scv;
        tm = fmaxf(tm, scv);
      }
#pragma unroll
      for(int off=1; off<16; off<<=1) tm = fmaxf(tm, __shfl_xor(tm, off, 64));
      float mn = fmaxf(mrow[r], tm);
      float alpha = __expf(mrow[r]-mn);
      float rs = 0.f;
#pragma unroll
      for(int nt=0;nt<4;nt++){
        float pp = __expf(sv[nt]-mn);
        rs += pp;
        Ps[w*16*AST + (q*4+r)*AST + nt*16 + m16] = f2bf(pp);
      }
#pragma unroll
      for(int off=1; off<16; off<<=1) rs += __shfl_xor(rs, off, 64);
      lrow[r] = lrow[r]*alpha + rs;
      mrow[r] = mn;
#pragma unroll
      for(int nt=0;nt<4;nt++) oacc[nt][r] *= alpha;
    }

    // O += P V (V hi only)
#pragma unroll
    for(int s=0;s<2;s++){
      bfrag pa = *(const bfrag*)&Ps[w*16*AST + m16*AST + s*32 + q*8];
#pragma unroll
      for(int nt=0;nt<4;nt++){
        bfrag vh_ = *(const bfrag*)&Vsh[(nt*16+m16)*AST + s*32 + q*8];
        oacc[nt] = __builtin_amdgcn_mfma_f32_16x16x32_bf16(pa, vh_, oacc[nt],0,0,0);
      }
    }
    __syncthreads();
  }

  // epilogue: normalize, write O hi/lo planes (C layout)
#pragma unroll
  for(int r=0;r<4;r++){
    float invl = 1.f/lrow[r];
    const size_t rowbase = ((size_t)(b*SS + s0 + w*16 + q*4 + r))*DD + h*HDIM;
#pragma unroll
    for(int nt=0;nt<4;nt++){
      float v = oacc[nt][r]*invl;
      unsigned short hb = f2bf(v);
      Oh[rowbase + nt*16 + m16] = hb;
      Ol[rowbase + nt*16 + m16] = f2bf(v - bf2f(hb));
    }
  }
}

__global__ __launch_bounds__(256) void comb_k(const float* __restrict__ of,
    const float* __restrict__ ob, const float* __restrict__ z,
    const float* __restrict__ skip, float* __restrict__ out)
{
  int idx = blockIdx.x*256 + threadIdx.x;
  int r = idx >> 8;
  out[idx] = z[r]*(of[idx]+ob[idx]) + skip[idx];
}

// ---------------------------------------------------------------------------
struct Params {
  const float *ln_gamma,*ln_beta,*proj_w,*proj_b,*fconv_w,*fconv_b,*bconv_w,*bconv_b,
    *rn0_t,*rn0_c,*ly_w,*ly_b,*lx_w,*lx_b,*lo_w,*lo_b,*c1d_w,*c1d_b,*a_param,
    *ig_w,*ig_b,*ag_w,*ag_b,*mlp0_up_w,*mlp0_up_b,*mlp0_dn_w,*mlp0_dn_b,
    *rn1_t,*rn1_c,*q_w,*k_w,*v_w,*o_w,*o_b,*mlp1_up_w,*mlp1_up_b,*mlp1_dn_w,*mlp1_dn_b;
};

struct WSplit {
  unsigned short *proj_h,*proj_l,*fconv_h,*fconv_l,*bconv_h,*bconv_l,
    *ly_h,*ly_l,*lx_h,*lx_l,*lo_h,*lo_l,*q_h,*q_l,*o_h,*o_l,
    *k_h,*k_l,*v_h,*v_l,
    *up0a_h,*up0a_l,*up0b_h,*up0b_l,*up1a_h,*up1a_l,*up1b_h,*up1b_l,
    *dn0_h,*dn0_l,*dn1_h,*dn1_l;
};

struct Bufs {
  float *Z,*XB,*Y,*XR,*CV,*OF,*OB,*CSA,*CSB;
  unsigned short *NPh,*NPl,*X0h,*X0l,*P1h,*P1l,*P2h,*P2l,*KPh,*KPl,*Vt,*ACTh,*ACTl;
};

#define USN ((unsigned short*)nullptr)

static void run_block(const Params& p, const WSplit& w, const Bufs& bf,
                      float* OUT, hipStream_t stream)
{
  dim3 blk(256);
  dim3 g2(2,128,1), g64(1,128,1), gbd(1,128,4), gdual(12,128,1);
  float* Abuf = OUT;   // fp32 scratch for gate 'a' (safe: OUT written last)

  // ---- residual block 0: recurrent (mlp0 weights) ----
  rms_k<<<RR/4, blk, 0, stream>>>(bf.XB, p.rn0_t, bf.NPh, bf.NPl);
  gemm_mfma<128,3,0,0><<<g2,blk,0,stream>>>(bf.NPh,bf.NPl, w.ly_h,w.ly_l, USN,USN,
      p.ly_b,nullptr,nullptr, bf.Y, USN,USN, DD,DD,DD);
  gemm_mfma<128,1,0,0><<<g2,blk,0,stream>>>(bf.NPh,bf.NPl, w.lx_h,w.lx_l, USN,USN,
      p.lx_b,nullptr,nullptr, bf.XR, USN,USN, DD,DD,DD);
  conv_k<<<RR*DD/256, blk, 0, stream>>>(bf.XR, p.c1d_w, p.c1d_b, bf.CV);
  gemm_k<64,1><<<gbd,blk,0,stream>>>(bf.CV,p.ig_w,p.ig_b,Abuf,
      RR,HDIM,HDIM, DD,HDIM,DD, HDIM, HDIM*HDIM, HDIM, HDIM);
  gemm_k<64,1><<<gbd,blk,0,stream>>>(bf.CV,p.ag_w,p.ag_b,bf.XR,
      RR,HDIM,HDIM, DD,HDIM,DD, HDIM, HDIM*HDIM, HDIM, HDIM);
  gate_k<<<RR*DD/256, blk, 0, stream>>>(bf.CV, Abuf, bf.XR, p.a_param);
  scan1_k<<<BB*NCH*DD/256, blk,0,stream>>>(Abuf, bf.XR, bf.CSA, bf.CSB);
  scan2_k<<<BB*DD/256, blk,0,stream>>>(bf.CSA, bf.CSB);
  scan3_k<<<BB*NCH*DD/256, blk,0,stream>>>(Abuf, bf.XR, bf.CSB, bf.Y, bf.P1h, bf.P1l);
  gemm_mfma<128,9,0,0><<<g2,blk,0,stream>>>(bf.P1h,bf.P1l, w.lo_h,w.lo_l, USN,USN,
      p.lo_b,nullptr, bf.XB, bf.CV, USN,USN, DD,DD,DD);
  rms_k<<<RR/4,blk,0,stream>>>(bf.CV, p.rn0_c, bf.NPh, bf.NPl);
  gemm_mfma<64,1,1,1><<<gdual,blk,0,stream>>>(bf.NPh,bf.NPl, w.up0a_h,w.up0a_l,
      w.up0b_h,w.up0b_l, p.mlp0_up_b, p.mlp0_up_b+EE, nullptr, nullptr,
      bf.ACTh, bf.ACTl, DD,DD,EE);
  gemm_mfma<128,9,0,0><<<g2,blk,0,stream>>>(bf.ACTh,bf.ACTl, w.dn0_h,w.dn0_l, USN,USN,
      p.mlp0_dn_b,nullptr, bf.CV, bf.XB, USN,USN, EE,EE,DD);

  // ---- residual block 1: local attention (mlp1 weights) ----
  rms_k<<<RR/4,blk,0,stream>>>(bf.XB, p.rn1_t, bf.NPh, bf.NPl);
  gemm_mfma<128,0,0,2><<<g2,blk,0,stream>>>(bf.NPh,bf.NPl, w.q_h,w.q_l, USN,USN,
      nullptr,nullptr,nullptr, nullptr, bf.P1h, bf.P1l, DD,DD,DD);
  gemm_mfma<64,0,0,3><<<g64,blk,0,stream>>>(bf.NPh,bf.NPl, w.k_h,w.k_l, USN,USN,
      nullptr,nullptr,nullptr, nullptr, bf.KPh, bf.KPl, DD,DD,HDIM);
  gemm_mfma<64,0,0,4><<<g64,blk,0,stream>>>(bf.NPh,bf.NPl, w.v_h,w.v_l, USN,USN,
      nullptr,nullptr,nullptr, nullptr, bf.Vt, USN, DD,DD,HDIM);
  attn_k<<<dim3(64,4,4),blk,0,stream>>>(bf.P1h, bf.P1l, bf.KPh, bf.KPl, bf.Vt,
      bf.P2h, bf.P2l);
  gemm_mfma<128,9,0,0><<<g2,blk,0,stream>>>(bf.P2h,bf.P2l, w.o_h,w.o_l, USN,USN,
      p.o_b,nullptr, bf.XB, bf.CV, USN,USN, DD,DD,DD);
  rms_k<<<RR/4,blk,0,stream>>>(bf.CV, p.rn1_c, bf.NPh, bf.NPl);
  gemm_mfma<64,1,1,1><<<gdual,blk,0,stream>>>(bf.NPh,bf.NPl, w.up1a_h,w.up1a_l,
      w.up1b_h,w.up1b_l, p.mlp1_up_b, p.mlp1_up_b+EE, nullptr, nullptr,
      bf.ACTh, bf.ACTl, DD,DD,EE);
  gemm_mfma<128,9,0,0><<<g2,blk,0,stream>>>(bf.ACTh,bf.ACTl, w.dn1_h,w.dn1_l, USN,USN,
      p.mlp1_dn_b,nullptr, bf.CV, OUT, USN,USN, EE,EE,DD);
}

extern "C" void kernel_launch(void* const* d_in, const int* in_sizes, int n_in,
                              void* d_out, int out_size, void* d_ws, size_t ws_size,
                              hipStream_t stream)
{
  (void)in_sizes; (void)n_in; (void)out_size; (void)ws_size;
  const float* skip = (const float*)d_in[0];
  Params p;
  p.ln_gamma  =(const float*)d_in[1];  p.ln_beta  =(const float*)d_in[2];
  p.proj_w    =(const float*)d_in[3];  p.proj_b   =(const float*)d_in[4];
  p.fconv_w   =(const float*)d_in[5];  p.fconv_b  =(const float*)d_in[6];
  p.bconv_w   =(const float*)d_in[7];  p.bconv_b  =(const float*)d_in[8];
  p.rn0_t     =(const float*)d_in[9];  p.rn0_c    =(const float*)d_in[10];
  p.ly_w      =(const float*)d_in[11]; p.ly_b     =(const float*)d_in[12];
  p.lx_w      =(const float*)d_in[13]; p.lx_b     =(const float*)d_in[14];
  p.lo_w      =(const float*)d_in[15]; p.lo_b     =(const float*)d_in[16];
  p.c1d_w     =(const float*)d_in[17]; p.c1d_b    =(const float*)d_in[18];
  p.a_param   =(const float*)d_in[19];
  p.ig_w      =(const float*)d_in[20]; p.ig_b     =(const float*)d_in[21];
  p.ag_w      =(const float*)d_in[22]; p.ag_b     =(const float*)d_in[23];
  p.mlp0_up_w =(const float*)d_in[24]; p.mlp0_up_b=(const float*)d_in[25];
  p.mlp0_dn_w =(const float*)d_in[26]; p.mlp0_dn_b=(const float*)d_in[27];
  p.rn1_t     =(const float*)d_in[28]; p.rn1_c    =(const float*)d_in[29];
  p.q_w       =(const float*)d_in[30]; p.k_w      =(const float*)d_in[31];
  p.v_w       =(const float*)d_in[32]; p.o_w      =(const float*)d_in[33];
  p.o_b       =(const float*)d_in[34];
  p.mlp1_up_w =(const float*)d_in[35]; p.mlp1_up_b=(const float*)d_in[36];
  p.mlp1_dn_w =(const float*)d_in[37]; p.mlp1_dn_b=(const float*)d_in[38];

  float* ws = (float*)d_ws;
  const size_t RD = (size_t)RR*DD;      // 4.19M floats
  size_t off = 0;
  Bufs bf;
  bf.Z   = ws + off; off += 16384;
  bf.XB  = ws + off; off += RD;
  bf.Y   = ws + off; off += RD;         // ACT planes alias [Y, XR, P1]
  bf.XR  = ws + off; off += RD;
  float* P1f = ws + off; off += RD;
  bf.CV  = ws + off; off += RD;
  bf.OF  = ws + off; off += RD;
  bf.OB  = ws + off; off += RD;
  bf.CSA = ws + off; off += (size_t)BB*NCH*DD;
  bf.CSB = ws + off; off += (size_t)BB*NCH*DD;
  float* NPf = ws + off; off += RD;
  float* X0f = ws + off; off += RD;
  float* P2f = ws + off; off += RD;
  float* KPf = ws + off; off += (size_t)RR*HDIM;     // 2 planes of RR*64 shorts
  float* Vtf = ws + off; off += (size_t)RR*HDIM/2;   // 1 plane  of RR*64 shorts

  bf.NPh = (unsigned short*)NPf;        bf.NPl = bf.NPh + RD;
  bf.X0h = (unsigned short*)X0f;        bf.X0l = bf.X0h + RD;
  bf.P1h = (unsigned short*)P1f;        bf.P1l = bf.P1h + RD;
  bf.P2h = (unsigned short*)P2f;        bf.P2l = bf.P2h + RD;
  bf.KPh = (unsigned short*)KPf;        bf.KPl = bf.KPh + (size_t)RR*HDIM;
  bf.Vt  = (unsigned short*)Vtf;
  bf.ACTh = (unsigned short*)bf.Y;      bf.ACTl = bf.ACTh + (size_t)RR*EE;

  unsigned short* sp = (unsigned short*)(ws + off);
  WSplit w;
  auto alloc_s = [&](size_t n){ unsigned short* r = sp; sp += n; return r; };
  const size_t SDD = (size_t)DD*DD, SKV = (size_t)DD*HDIM, SUP = (size_t)DD*EE;
  w.proj_h=alloc_s(SDD);  w.proj_l=alloc_s(SDD);
  w.fconv_h=alloc_s(SDD); w.fconv_l=alloc_s(SDD);
  w.bconv_h=alloc_s(SDD); w.bconv_l=alloc_s(SDD);
  w.ly_h=alloc_s(SDD);    w.ly_l=alloc_s(SDD);
  w.lx_h=alloc_s(SDD);    w.lx_l=alloc_s(SDD);
  w.lo_h=alloc_s(SDD);    w.lo_l=alloc_s(SDD);
  w.q_h=alloc_s(SDD);     w.q_l=alloc_s(SDD);
  w.o_h=alloc_s(SDD);     w.o_l=alloc_s(SDD);
  w.k_h=alloc_s(SKV);     w.k_l=alloc_s(SKV);
  w.v_h=alloc_s(SKV);     w.v_l=alloc_s(SKV);
  w.up0a_h=alloc_s(SUP);  w.up0a_l=alloc_s(SUP);
  w.up0b_h=alloc_s(SUP);  w.up0b_l=alloc_s(SUP);
  w.up1a_h=alloc_s(SUP);  w.up1a_l=alloc_s(SUP);
  w.up1b_h=alloc_s(SUP);  w.up1b_l=alloc_s(SUP);
  w.dn0_h=alloc_s(SUP);   w.dn0_l=alloc_s(SUP);
  w.dn1_h=alloc_s(SUP);   w.dn1_l=alloc_s(SUP);

  dim3 blk(256);
  dim3 g2(2,128,1);

  {
    TS8 ga;
    ga.t[0] = {p.proj_w,  w.proj_h,  w.proj_l,  DD, DD};
    ga.t[1] = {p.fconv_w, w.fconv_h, w.fconv_l, DD, DD};
    ga.t[2] = {p.bconv_w, w.bconv_h, w.bconv_l, DD, DD};
    ga.t[3] = {p.ly_w,    w.ly_h,    w.ly_l,    DD, DD};
    ga.t[4] = {p.lx_w,    w.lx_h,    w.lx_l,    DD, DD};
    ga.t[5] = {p.lo_w,    w.lo_h,    w.lo_l,    DD, DD};
    ga.t[6] = {p.q_w,     w.q_h,     w.q_l,     DD, DD};
    ga.t[7] = {p.o_w,     w.o_h,     w.o_l,     DD, DD};
    tsplit8_k<<<dim3(DD*DD/256, 8), blk, 0, stream>>>(ga);
    TS8 gb;
    gb.t[0] = {p.k_w,              w.k_h,    w.k_l,    DD, HDIM};
    gb.t[1] = {p.v_w,              w.v_h,    w.v_l,    DD, HDIM};
    gb.t[2] = {p.mlp0_up_w,        w.up0a_h, w.up0a_l, DD, EE};
    gb.t[3] = {p.mlp0_up_w+(size_t)DD*EE, w.up0b_h, w.up0b_l, DD, EE};
    gb.t[4] = {p.mlp1_up_w,        w.up1a_h, w.up1a_l, DD, EE};
    gb.t[5] = {p.mlp1_up_w+(size_t)DD*EE, w.up1b_h, w.up1b_l, DD, EE};
    gb.t[6] = {p.mlp0_dn_w,        w.dn0_h,  w.dn0_l,  EE, DD};
    gb.t[7] = {p.mlp1_dn_w,        w.dn1_h,  w.dn1_l,  EE, DD};
    tsplit8_k<<<dim3(DD*EE/256, 8), blk, 0, stream>>>(gb);
  }

  ln_z_k<<<RR/4, blk, 0, stream>>>(skip, p.ln_gamma, p.ln_beta, bf.NPh, bf.NPl, bf.Z);
  gemm_mfma<128,1,0,1><<<g2,blk,0,stream>>>(bf.NPh,bf.NPl, w.proj_h,w.proj_l, USN,USN,
      p.proj_b,nullptr,nullptr, nullptr, bf.X0h, bf.X0l, DD,DD,DD);

  gemm_mfma<128,1,0,0><<<g2,blk,0,stream>>>(bf.X0h,bf.X0l, w.fconv_h,w.fconv_l, USN,USN,
      p.fconv_b,nullptr,nullptr, bf.XB, USN,USN, DD,DD,DD);
  run_block(p, w, bf, bf.OF, stream);

  gemm_mfma<128,1,0,0><<<g2,blk,0,stream>>>(bf.X0h,bf.X0l, w.bconv_h,w.bconv_l, USN,USN,
      p.bconv_b,nullptr,nullptr, bf.XB, USN,USN, DD,DD,DD);
  run_block(p, w, bf, bf.OB, stream);

  comb_k<<<RR*DD/256, blk, 0, stream>>>(bf.OF, bf.OB, bf.Z, skip, (float*)d_out);
}

// Round 7
// 1064.558 us; speedup vs baseline: 2.2193x; 1.1527x over previous
//
#include <hip/hip_runtime.h>
#include <math.h>
#include <stddef.h>

// ---------------------------------------------------------------------------
// BiDiGemma forward. Round 7: R6 merged-branch plan (M=32768 GEMMs, 2-term
// MLP split, hoisted addressing) with a liveness-packed workspace (~192 MB;
// R6's 272 MB overran d_ws and crashed). Y is bf16-hi only (scan3 converts).
// ---------------------------------------------------------------------------

#define BB   4
#define SS   4096
#define DD   256
#define HH   4
#define HDIM 64
#define EE   768
#define RR   (BB*SS)        // rows per branch
#define RR2  (2*RR)         // merged rows
#define WNN  256
#define CH   64
#define NCH  (SS/CH)

typedef __attribute__((ext_vector_type(8))) short bfrag;
typedef __attribute__((ext_vector_type(4))) float f4acc;

__device__ __forceinline__ float geluf(float x){
  return 0.5f*x*(1.0f + erff(x*0.70710678118654752f));
}
__device__ __forceinline__ float sigm(float x){ return 1.0f/(1.0f+expf(-x)); }

__device__ __forceinline__ unsigned short f2bf(float x){
  unsigned u = __float_as_uint(x);
  return (unsigned short)((u + 0x7FFFu + ((u>>16)&1u)) >> 16);
}
__device__ __forceinline__ float bf2f(unsigned short h){
  return __uint_as_float(((unsigned)h) << 16);
}
__device__ __forceinline__ void split2(float v, unsigned short* h, unsigned short* l){
  unsigned short hb = f2bf(v);
  *h = hb; *l = f2bf(v - bf2f(hb));
}

__device__ __forceinline__ float wredSum(float v){
#pragma unroll
  for(int o=32;o>0;o>>=1) v += __shfl_xor(v,o,64);
  return v;
}

// ---------------------------------------------------------------------------
// LayerNorm(skip) -> hi/lo planes ; z = sigmoid(mean(silu(skip)))
// ---------------------------------------------------------------------------
__global__ __launch_bounds__(256) void ln_z_k(const float* __restrict__ skip,
    const float* __restrict__ g, const float* __restrict__ b,
    unsigned short* __restrict__ oh, unsigned short* __restrict__ ol,
    float* __restrict__ z)
{
  int row  = blockIdx.x*4 + (threadIdx.x>>6);
  int lane = threadIdx.x & 63;
  float4 v = ((const float4*)(skip + (size_t)row*DD))[lane];
  float s  = v.x+v.y+v.z+v.w;
  float sq = v.x*v.x+v.y*v.y+v.z*v.z+v.w*v.w;
  float si = v.x*sigm(v.x)+v.y*sigm(v.y)+v.z*sigm(v.z)+v.w*sigm(v.w);
  s = wredSum(s); sq = wredSum(sq); si = wredSum(si);
  float mean = s*(1.0f/DD);
  float var  = sq*(1.0f/DD) - mean*mean;
  float inv  = rsqrtf(var + 1e-5f);
  float4 gv = ((const float4*)g)[lane];
  float4 bv = ((const float4*)b)[lane];
  float o0 = (v.x-mean)*inv*gv.x + bv.x;
  float o1 = (v.y-mean)*inv*gv.y + bv.y;
  float o2 = (v.z-mean)*inv*gv.z + bv.z;
  float o3 = (v.w-mean)*inv*gv.w + bv.w;
  ushort4 hi, lo;
  split2(o0,&hi.x,&lo.x); split2(o1,&hi.y,&lo.y);
  split2(o2,&hi.z,&lo.z); split2(o3,&hi.w,&lo.w);
  ((ushort4*)(oh + (size_t)row*DD))[lane] = hi;
  ((ushort4*)(ol + (size_t)row*DD))[lane] = lo;
  if(lane==0) z[row] = sigm(si*(1.0f/DD));
}

// ---------------------------------------------------------------------------
// RMSNorm -> hi/lo planes
// ---------------------------------------------------------------------------
__global__ __launch_bounds__(256) void rms_k(const float* __restrict__ x,
    const float* __restrict__ t,
    unsigned short* __restrict__ oh, unsigned short* __restrict__ ol)
{
  int row  = blockIdx.x*4 + (threadIdx.x>>6);
  int lane = threadIdx.x & 63;
  float4 v = ((const float4*)(x + (size_t)row*DD))[lane];
  float sq = v.x*v.x+v.y*v.y+v.z*v.z+v.w*v.w;
  sq = wredSum(sq);
  float inv = rsqrtf(sq*(1.0f/DD) + 1e-6f);
  float4 tv = ((const float4*)t)[lane];
  float o0 = v.x*inv*(1.0f+tv.x);
  float o1 = v.y*inv*(1.0f+tv.y);
  float o2 = v.z*inv*(1.0f+tv.z);
  float o3 = v.w*inv*(1.0f+tv.w);
  ushort4 hi, lo;
  split2(o0,&hi.x,&lo.x); split2(o1,&hi.y,&lo.y);
  split2(o2,&hi.z,&lo.z); split2(o3,&hi.w,&lo.w);
  ((ushort4*)(oh + (size_t)row*DD))[lane] = hi;
  ((ushort4*)(ol + (size_t)row*DD))[lane] = lo;
}

// ---------------------------------------------------------------------------
// Weight transpose + split
// ---------------------------------------------------------------------------
struct TS  { const float* s; unsigned short* h; unsigned short* l; int K; int N; };
struct TS8 { TS t[8]; };

__global__ __launch_bounds__(256) void tsplit8_k(TS8 g){
  TS tt = g.t[blockIdx.y];
  int idx = blockIdx.x*256 + threadIdx.x;
  int tot = tt.K*tt.N;
  if(idx >= tot) return;
  int k = idx / tt.N;
  int n = idx - k*tt.N;
  float x = tt.s[idx];
  unsigned short hb = f2bf(x);
  unsigned short lb = f2bf(x - bf2f(hb));
  tt.h[(size_t)n*tt.K + k] = hb;
  tt.l[(size_t)n*tt.K + k] = lb;
}

// ---------------------------------------------------------------------------
// Split-bf16 MFMA GEMM, pre-split A planes (pure copy staging).
// MODE bits: 1=bias0, 2=gelu, 8=+Res(fp32).
// DUAL: C = gelu(A@B0+b0)*(A@B1+b1).
// OUT: 0=fp32; 1=hi/lo planes; 2=RoPE-q planes (BN=128, *0.125);
//      3=RoPE-k planes (BN=64); 4=V^T bf16; 5=hi plane only.
// TERMS: 3 = AhBh+AhBl+AlBh ; 2 = AhBh+AhBl (A-lo ignored, Al_g unused).
// ST=40 shorts (80 B): rows 16B-aligned; 2-way-max bank aliasing (free).
// ---------------------------------------------------------------------------
template<int BN, int MODE, int DUAL, int OUT, int TERMS>
__global__ __launch_bounds__(256) void gemm_mfma(
    const unsigned short* __restrict__ Ah_g, const unsigned short* __restrict__ Al_g,
    const unsigned short* __restrict__ B0h, const unsigned short* __restrict__ B0l,
    const unsigned short* __restrict__ B1h, const unsigned short* __restrict__ B1l,
    const float* __restrict__ bias0, const float* __restrict__ bias1,
    const float* __restrict__ Res, float* __restrict__ C,
    unsigned short* __restrict__ Ch, unsigned short* __restrict__ Cl,
    int K, int lda, int ldc)
{
  constexpr int NT = BN/32;
  constexpr int ST = 40;
  __shared__ unsigned short Ash[128*ST];
  __shared__ unsigned short Asl[TERMS==3 ? 128*ST : 8];
  __shared__ unsigned short Bsh[BN*ST],  Bsl[BN*ST];
  __shared__ unsigned short B2h[DUAL?BN*ST:8], B2l[DUAL?BN*ST:8];

  const int tid  = threadIdx.x;
  const int lane = tid & 63, wave = tid >> 6;
  const int wm = wave >> 1, wn = wave & 1;
  const int bm = blockIdx.y*128, bn = blockIdx.x*BN;
  const int m16 = lane & 15, q = lane >> 4;

  f4acc acc[4][NT];
  f4acc acc2[DUAL?4:1][DUAL?NT:1];
#pragma unroll
  for(int i=0;i<4;i++)
#pragma unroll
    for(int j=0;j<NT;j++){
      acc[i][j] = (f4acc)0.f;
      if constexpr(DUAL) acc2[i][j] = (f4acc)0.f;
    }

  const int arow = tid >> 1, ahalf = tid & 1;

  const unsigned short* pAh = Ah_g + (size_t)(bm+arow)*lda + ahalf*16;
  const unsigned short* pAl = (TERMS==3) ? (Al_g + (size_t)(bm+arow)*lda + ahalf*16)
                                         : (const unsigned short*)nullptr;
  const unsigned short* pB0 = nullptr;
  const unsigned short* pB1 = nullptr;
  int bdst0 = 0, bdst1 = 0;
  if constexpr(BN==128){
    pB0 = B0h + (size_t)(bn+arow)*K + ahalf*16;
    pB1 = B0l + (size_t)(bn+arow)*K + ahalf*16;
    bdst0 = arow*ST + ahalf*16;
  } else if constexpr(!DUAL){
    int plane = tid >> 7, t2 = tid & 127;
    int row = t2 >> 1, half = t2 & 1;
    pB0 = (plane ? B0l : B0h) + (size_t)(bn+row)*K + half*16;
    bdst0 = row*ST + half*16;
    bdst1 = plane;
  } else {
    int plane = tid >> 6, row = tid & 63;
    pB0 = ((plane==0)?B0h:(plane==1)?B0l:(plane==2)?B1h:B1l) + (size_t)(bn+row)*K;
    bdst0 = row*ST;
    bdst1 = plane;
  }

  for(int k0 = 0; k0 < K; k0 += 32){
#pragma unroll
    for(int c=0;c<2;c++){
      *(float4*)&Ash[arow*ST + ahalf*16 + c*8] = *(const float4*)(pAh + k0 + c*8);
      if constexpr(TERMS==3)
        *(float4*)&Asl[arow*ST + ahalf*16 + c*8] = *(const float4*)(pAl + k0 + c*8);
    }
    if constexpr(BN==128){
#pragma unroll
      for(int c=0;c<2;c++){
        *(float4*)&Bsh[bdst0 + c*8] = *(const float4*)(pB0 + k0 + c*8);
        *(float4*)&Bsl[bdst0 + c*8] = *(const float4*)(pB1 + k0 + c*8);
      }
    } else if constexpr(!DUAL){
      unsigned short* dst = bdst1 ? Bsl : Bsh;
#pragma unroll
      for(int c=0;c<2;c++)
        *(float4*)&dst[bdst0 + c*8] = *(const float4*)(pB0 + k0 + c*8);
    } else {
      unsigned short* dst = (bdst1==0)?Bsh:(bdst1==1)?Bsl:(bdst1==2)?B2h:B2l;
#pragma unroll
      for(int c=0;c<4;c++)
        *(float4*)&dst[bdst0 + c*8] = *(const float4*)(pB0 + k0 + c*8);
    }
    __syncthreads();

    bfrag ah[4], al[TERMS==3?4:1], b0hf[NT], b0lf[NT];
    bfrag b1hf[DUAL?NT:1], b1lf[DUAL?NT:1];
#pragma unroll
    for(int mi=0;mi<4;mi++){
      int row = wm*64 + mi*16 + m16;
      ah[mi] = *(const bfrag*)&Ash[row*ST + q*8];
      if constexpr(TERMS==3) al[mi] = *(const bfrag*)&Asl[row*ST + q*8];
    }
#pragma unroll
    for(int ni=0;ni<NT;ni++){
      int n = wn*(BN/2) + ni*16 + m16;
      b0hf[ni] = *(const bfrag*)&Bsh[n*ST + q*8];
      b0lf[ni] = *(const bfrag*)&Bsl[n*ST + q*8];
      if constexpr(DUAL){
        b1hf[ni] = *(const bfrag*)&B2h[n*ST + q*8];
        b1lf[ni] = *(const bfrag*)&B2l[n*ST + q*8];
      }
    }
#pragma unroll
    for(int mi=0;mi<4;mi++)
#pragma unroll
      for(int ni=0;ni<NT;ni++){
        acc[mi][ni] = __builtin_amdgcn_mfma_f32_16x16x32_bf16(ah[mi], b0hf[ni], acc[mi][ni],0,0,0);
        acc[mi][ni] = __builtin_amdgcn_mfma_f32_16x16x32_bf16(ah[mi], b0lf[ni], acc[mi][ni],0,0,0);
        if constexpr(TERMS==3)
          acc[mi][ni] = __builtin_amdgcn_mfma_f32_16x16x32_bf16(al[mi], b0hf[ni], acc[mi][ni],0,0,0);
        if constexpr(DUAL){
          acc2[mi][ni] = __builtin_amdgcn_mfma_f32_16x16x32_bf16(ah[mi], b1hf[ni], acc2[mi][ni],0,0,0);
          acc2[mi][ni] = __builtin_amdgcn_mfma_f32_16x16x32_bf16(ah[mi], b1lf[ni], acc2[mi][ni],0,0,0);
          if constexpr(TERMS==3)
            acc2[mi][ni] = __builtin_amdgcn_mfma_f32_16x16x32_bf16(al[mi], b1hf[ni], acc2[mi][ni],0,0,0);
        }
      }
    __syncthreads();
  }

  // ---- epilogue (C/D layout: col = lane&15, row = q*4 + r) ----
  if constexpr(OUT==0 || OUT==1 || OUT==5){
#pragma unroll
    for(int ni=0;ni<NT;ni++){
      const int col = bn + wn*(BN/2) + ni*16 + m16;
      float bv0 = (MODE&1) ? bias0[col] : 0.f;
      float bv1 = DUAL ? bias1[col] : 0.f;
#pragma unroll
      for(int mi=0;mi<4;mi++){
#pragma unroll
        for(int r=0;r<4;r++){
          const int row = bm + wm*64 + mi*16 + q*4 + r;
          float v = acc[mi][ni][r] + bv0;
          if constexpr(DUAL){
            float v2 = acc2[mi][ni][r] + bv1;
            v = geluf(v) * v2;
          } else if(MODE&2){
            v = geluf(v);
          }
          if(MODE&8) v += Res[(size_t)row*ldc + col];
          if constexpr(OUT==0){
            C[(size_t)row*ldc + col] = v;
          } else if constexpr(OUT==1){
            unsigned short hb = f2bf(v);
            Ch[(size_t)row*ldc + col] = hb;
            Cl[(size_t)row*ldc + col] = f2bf(v - bf2f(hb));
          } else {
            Ch[(size_t)row*ldc + col] = f2bf(v);
          }
        }
      }
    }
  } else if constexpr(OUT==2){
    const int hb = bn + wn*64;
    const float p = (float)m16;
    const float invf = __expf(-p * 0.575646273248511f);
#pragma unroll
    for(int mi=0;mi<4;mi++){
#pragma unroll
      for(int r=0;r<4;r++){
        const int row = bm + wm*64 + mi*16 + q*4 + r;
        const int s = row & (SS-1);
        float t = (float)s * invf;
        float sn, cs; __sincosf(t, &sn, &cs);
        float x1 = acc[mi][0][r], x2 = acc[mi][1][r];
        float v0 = (x1*cs - x2*sn)*0.125f;
        float v1 = (x2*cs + x1*sn)*0.125f;
        float v2 = acc[mi][2][r]*0.125f;
        float v3 = acc[mi][3][r]*0.125f;
        size_t base = (size_t)row*ldc + hb;
        unsigned short hh;
        hh=f2bf(v0); Ch[base+m16]=hh;    Cl[base+m16]   =f2bf(v0-bf2f(hh));
        hh=f2bf(v1); Ch[base+16+m16]=hh; Cl[base+16+m16]=f2bf(v1-bf2f(hh));
        hh=f2bf(v2); Ch[base+32+m16]=hh; Cl[base+32+m16]=f2bf(v2-bf2f(hh));
        hh=f2bf(v3); Ch[base+48+m16]=hh; Cl[base+48+m16]=f2bf(v3-bf2f(hh));
      }
    }
  } else if constexpr(OUT==3){
    const float p = (float)m16;
    const float invf = __expf(-p * 0.575646273248511f);
#pragma unroll
    for(int mi=0;mi<4;mi++){
#pragma unroll
      for(int r=0;r<4;r++){
        const int row = bm + wm*64 + mi*16 + q*4 + r;
        const int s = row & (SS-1);
        float v0, v1;
        if(wn==0){
          float t = (float)s * invf;
          float sn, cs; __sincosf(t, &sn, &cs);
          float x1 = acc[mi][0][r], x2 = acc[mi][1][r];
          v0 = x1*cs - x2*sn;
          v1 = x2*cs + x1*sn;
        } else {
          v0 = acc[mi][0][r]; v1 = acc[mi][1][r];
        }
        size_t base = (size_t)row*ldc + wn*32;
        unsigned short hh;
        hh=f2bf(v0); Ch[base+m16]=hh;    Cl[base+m16]   =f2bf(v0-bf2f(hh));
        hh=f2bf(v1); Ch[base+16+m16]=hh; Cl[base+16+m16]=f2bf(v1-bf2f(hh));
      }
    }
  } else if constexpr(OUT==4){
#pragma unroll
    for(int ni=0;ni<NT;ni++){
      const int col = wn*32 + ni*16 + m16;
#pragma unroll
      for(int mi=0;mi<4;mi++){
        const int rowb = bm + wm*64 + mi*16 + q*4;
        const int b = rowb >> 12, sl = rowb & (SS-1);
        ushort4 hv;
        hv.x = f2bf(acc[mi][ni][0]); hv.y = f2bf(acc[mi][ni][1]);
        hv.z = f2bf(acc[mi][ni][2]); hv.w = f2bf(acc[mi][ni][3]);
        *(ushort4*)(Ch + ((size_t)(b*64 + col))*SS + sl) = hv;
      }
    }
  }
}

// fp32 GEMM for block-diagonal gate linears.
template<int BN, int MODE>
__global__ __launch_bounds__(256) void gemm_k(
    const float* __restrict__ A,
    const float* __restrict__ B0,
    const float* __restrict__ bias0,
    float* __restrict__ C,
    int M, int N, int K, int lda, int ldb, int ldc,
    int batA, int batB, int batC, int batBias)
{
  constexpr int BK = 16;
  constexpr int TN = BN/16;
  constexpr int NH = BN/64;
  __shared__ float Ask[BK][132];
  __shared__ float Bs [BK][BN+4];

  const int bz = blockIdx.z;
  const float* Ab  = A  + (size_t)bz*batA;
  const float* Bb  = B0 + (size_t)bz*batB;
  float* Cb = C + (size_t)bz*batC;

  const int bm = blockIdx.y*128, bn = blockIdx.x*BN;
  const int tid = threadIdx.x;
  const int tx = tid & 15, ty = tid >> 4;
  const int ar = tid >> 1, ac = (tid & 1)*8;
  const int br = tid >> 4;

  float acc[8][TN];
#pragma unroll
  for(int i=0;i<8;i++)
#pragma unroll
    for(int j=0;j<TN;j++) acc[i][j]=0.f;

  for(int k0=0;k0<K;k0+=BK){
#pragma unroll
    for(int hf=0;hf<2;hf++){
      float4 av = *(const float4*)(Ab + (size_t)(bm+ar)*lda + (k0+ac+hf*4));
      Ask[ac+hf*4+0][ar]=av.x; Ask[ac+hf*4+1][ar]=av.y;
      Ask[ac+hf*4+2][ar]=av.z; Ask[ac+hf*4+3][ar]=av.w;
    }
    {
      const int bc = (tid&15)*4;
      *(float4*)&Bs[br][bc] = *(const float4*)(Bb + (size_t)(k0+br)*ldb + (bn+bc));
    }
    __syncthreads();
#pragma unroll
    for(int k=0;k<BK;k++){
      float a[8];
      *(float4*)&a[0] = *(const float4*)&Ask[k][ty*8];
      *(float4*)&a[4] = *(const float4*)&Ask[k][ty*8+4];
      float bv[TN];
#pragma unroll
      for(int hh=0;hh<NH;hh++)
        *(float4*)&bv[hh*4] = *(const float4*)&Bs[k][hh*64 + tx*4];
#pragma unroll
      for(int i=0;i<8;i++)
#pragma unroll
        for(int j=0;j<TN;j++)
          acc[i][j] = fmaf(a[i], bv[j], acc[i][j]);
    }
    __syncthreads();
  }

#pragma unroll
  for(int i=0;i<8;i++){
    const int row = bm + ty*8 + i;
#pragma unroll
    for(int hh=0;hh<NH;hh++){
      const int col = bn + hh*64 + tx*4;
      float v0=acc[i][hh*4+0], v1=acc[i][hh*4+1], v2=acc[i][hh*4+2], v3=acc[i][hh*4+3];
      if(MODE&1){
        float4 bbv = *(const float4*)(bias0 + (size_t)bz*batBias + col);
        v0+=bbv.x; v1+=bbv.y; v2+=bbv.z; v3+=bbv.w;
      }
      float4 ov; ov.x=v0; ov.y=v1; ov.z=v2; ov.w=v3;
      *(float4*)(Cb + (size_t)row*ldc + col) = ov;
    }
  }
}

__global__ __launch_bounds__(256) void conv_k(const float* __restrict__ x,
    const float* __restrict__ w, const float* __restrict__ b, float* __restrict__ out)
{
  int idx = blockIdx.x*256 + threadIdx.x;
  int d = idx & (DD-1);
  int r = idx >> 8;
  int s = r & (SS-1);
  float acc = b[d];
#pragma unroll
  for(int i=0;i<4;i++){
    int t = s - 3 + i;
    if(t >= 0) acc += w[i*DD + d] * x[(size_t)(r-3+i)*DD + d];
  }
  out[idx] = acc;
}

__global__ __launch_bounds__(256) void gate_k(const float* __restrict__ x,
    float* __restrict__ ig, float* __restrict__ ag, const float* __restrict__ ap)
{
  int idx = blockIdx.x*256 + threadIdx.x;
  int d = idx & (DD-1);
  int r = idx >> 8;
  int s = r & (SS-1);
  float gx = sigm(ig[idx]);
  float ga = sigm(ag[idx]);
  float a_ = ap[d];
  float sp = (a_ > 20.f) ? a_ : log1pf(expf(a_));
  float la = -8.f * ga * sp;
  float a  = expf(la);
  float mult = (s==0) ? 1.f : sqrtf(fmaxf(-expm1f(2.f*la), 0.f));
  float bt = x[idx] * gx * mult;
  ig[idx] = a;
  ag[idx] = bt;
}

__global__ __launch_bounds__(256) void scan1_k(const float* __restrict__ A,
    const float* __restrict__ Bv, float* __restrict__ csa, float* __restrict__ csb)
{
  int idx = blockIdx.x*256 + threadIdx.x;   // < 8*NCH*DD
  int d = idx & (DD-1);
  int c = (idx >> 8) & (NCH-1);
  int b = idx >> 14;                        // 0..7
  size_t base = ((size_t)b*SS + (size_t)c*CH)*DD + d;
  float Aa = 1.f, Bb_ = 0.f;
  for(int t=0;t<CH;t++){
    float a  = A [base + (size_t)t*DD];
    float bb = Bv[base + (size_t)t*DD];
    Aa  = a*Aa;
    Bb_ = a*Bb_ + bb;
  }
  csa[idx] = Aa; csb[idx] = Bb_;
}

__global__ __launch_bounds__(256) void scan2_k(const float* __restrict__ csa,
    float* __restrict__ csb)
{
  int idx = blockIdx.x*256 + threadIdx.x;   // < 8*DD
  int d = idx & (DD-1);
  int b = idx >> 8;
  float h = 0.f;
  for(int c=0;c<NCH;c++){
    size_t i = ((size_t)b*NCH + c)*DD + d;
    float Aa = csa[i], Bb_ = csb[i];
    csb[i] = h;
    h = Aa*h + Bb_;
  }
}

// scan3: finish recurrence, multiply by gelu branch y (bf16 hi), write planes.
__global__ __launch_bounds__(256) void scan3_k(const float* __restrict__ A,
    const float* __restrict__ Bv, const float* __restrict__ csb,
    const unsigned short* __restrict__ Yh,
    unsigned short* __restrict__ Hh, unsigned short* __restrict__ Hl)
{
  int idx = blockIdx.x*256 + threadIdx.x;
  int d = idx & (DD-1);
  int c = (idx >> 8) & (NCH-1);
  int b = idx >> 14;
  size_t base = ((size_t)b*SS + (size_t)c*CH)*DD + d;
  float h = csb[idx];
  for(int t=0;t<CH;t++){
    float a  = A [base + (size_t)t*DD];
    float bb = Bv[base + (size_t)t*DD];
    h = a*h + bb;
    float v = h * bf2f(Yh[base + (size_t)t*DD]);
    unsigned short hb = f2bf(v);
    Hh[base + (size_t)t*DD] = hb;
    Hl[base + (size_t)t*DD] = f2bf(v - bf2f(hb));
  }
}

// ---------------------------------------------------------------------------
// MFMA flash attention (unchanged from R5/R6; grid z covers 8 sequences).
// ---------------------------------------------------------------------------
#define AST 72
__global__ __launch_bounds__(256) void attn_k(
    const unsigned short* __restrict__ Qh, const unsigned short* __restrict__ Ql,
    const unsigned short* __restrict__ Kh, const unsigned short* __restrict__ Kl,
    const unsigned short* __restrict__ Vt,
    unsigned short* __restrict__ Oh, unsigned short* __restrict__ Ol)
{
  __shared__ unsigned short Ksh[64*AST], Ksl[64*AST], Vsh[64*AST];
  __shared__ unsigned short Ps[4*16*AST];

  const int qt = blockIdx.x & 3, n = blockIdx.x >> 2;
  const int h = blockIdx.y, b = blockIdx.z;
  const int tid = threadIdx.x;
  const int lane = tid & 63, w = tid >> 6;
  const int m16 = lane & 15, q = lane >> 4;
  const int s0 = n*WNN + qt*64;

  const size_t qro = ((size_t)(b*SS + s0 + w*16 + m16))*DD + h*HDIM + q*8;
  bfrag qh0 = *(const bfrag*)(Qh + qro);
  bfrag qh1 = *(const bfrag*)(Qh + qro + 32);
  bfrag ql0 = *(const bfrag*)(Ql + qro);
  bfrag ql1 = *(const bfrag*)(Ql + qro + 32);

  float mrow[4], lrow[4];
  f4acc oacc[4];
#pragma unroll
  for(int i=0;i<4;i++){ mrow[i]=-3.0e38f; lrow[i]=0.f; oacc[i]=(f4acc)0.f; }

  const int ktlo = (n==0) ? 4 : qt;
  const int kthi = qt + 4;
  const int sr = tid >> 2, sc = tid & 3;

  for(int kt=ktlo; kt<=kthi; kt++){
    const int kbase = (n-1)*WNN + kt*64;
#pragma unroll
    for(int cc=0; cc<2; cc++){
      int g = sc + cc*4;
      *(float4*)&Ksh[sr*AST + g*8] =
        *(const float4*)(Kh + (size_t)(b*SS + kbase + sr)*HDIM + g*8);
      *(float4*)&Ksl[sr*AST + g*8] =
        *(const float4*)(Kl + (size_t)(b*SS + kbase + sr)*HDIM + g*8);
      *(float4*)&Vsh[sr*AST + g*8] =
        *(const float4*)(Vt + ((size_t)(b*64 + sr))*SS + kbase + g*8);
    }
    __syncthreads();

    f4acc sacc[4];
#pragma unroll
    for(int nt=0;nt<4;nt++) sacc[nt] = (f4acc)0.f;
#pragma unroll
    for(int nt=0;nt<4;nt++){
      const int kr = (nt*16+m16)*AST;
      bfrag kh0 = *(const bfrag*)&Ksh[kr + q*8];
      bfrag kh1 = *(const bfrag*)&Ksh[kr + 32 + q*8];
      bfrag kl0 = *(const bfrag*)&Ksl[kr + q*8];
      bfrag kl1 = *(const bfrag*)&Ksl[kr + 32 + q*8];
      sacc[nt] = __builtin_amdgcn_mfma_f32_16x16x32_bf16(qh0, kh0, sacc[nt],0,0,0);
      sacc[nt] = __builtin_amdgcn_mfma_f32_16x16x32_bf16(qh0, kl0, sacc[nt],0,0,0);
      sacc[nt] = __builtin_amdgcn_mfma_f32_16x16x32_bf16(ql0, kh0, sacc[nt],0,0,0);
      sacc[nt] = __builtin_amdgcn_mfma_f32_16x16x32_bf16(qh1, kh1, sacc[nt],0,0,0);
      sacc[nt] = __builtin_amdgcn_mfma_f32_16x16x32_bf16(qh1, kl1, sacc[nt],0,0,0);
      sacc[nt] = __builtin_amdgcn_mfma_f32_16x16x32_bf16(ql1, kh1, sacc[nt],0,0,0);
    }

    const bool needlo = (kt == qt+4);
    const bool needhi = (kt == qt);
#pragma unroll
    for(int r=0;r<4;r++){
      int qp = qt*64 + w*16 + q*4 + r;
      float sv[4];
      float tm = -3.0e38f;
#pragma unroll
      for(int nt=0;nt<4;nt++){
        float scv = sacc[nt][r];
        if(needlo || needhi){
          int kj = kt*64 + nt*16 + m16;
          int diff = qp + WNN - kj;
          bool ok = (!needlo || diff >= 0) && (!needhi || diff <= WNN);
          scv = ok ? scv : -3.0e38f;
        }
        sv[nt] = scv;
        tm = fmaxf(tm, scv);
      }
#pragma unroll
      for(int off=1; off<16; off<<=1) tm = fmaxf(tm, __shfl_xor(tm, off, 64));
      float mn = fmaxf(mrow[r], tm);
      float alpha = __expf(mrow[r]-mn);
      float rs = 0.f;
#pragma unroll
      for(int nt=0;nt<4;nt++){
        float pp = __expf(sv[nt]-mn);
        rs += pp;
        Ps[w*16*AST + (q*4+r)*AST + nt*16 + m16] = f2bf(pp);
      }
#pragma unroll
      for(int off=1; off<16; off<<=1) rs += __shfl_xor(rs, off, 64);
      lrow[r] = lrow[r]*alpha + rs;
      mrow[r] = mn;
#pragma unroll
      for(int nt=0;nt<4;nt++) oacc[nt][r] *= alpha;
    }

#pragma unroll
    for(int s=0;s<2;s++){
      bfrag pa = *(const bfrag*)&Ps[w*16*AST + m16*AST + s*32 + q*8];
#pragma unroll
      for(int nt=0;nt<4;nt++){
        bfrag vh_ = *(const bfrag*)&Vsh[(nt*16+m16)*AST + s*32 + q*8];
        oacc[nt] = __builtin_amdgcn_mfma_f32_16x16x32_bf16(pa, vh_, oacc[nt],0,0,0);
      }
    }
    __syncthreads();
  }

#pragma unroll
  for(int r=0;r<4;r++){
    float invl = 1.f/lrow[r];
    const size_t rowbase = ((size_t)(b*SS + s0 + w*16 + q*4 + r))*DD + h*HDIM;
#pragma unroll
    for(int nt=0;nt<4;nt++){
      float v = oacc[nt][r]*invl;
      unsigned short hb = f2bf(v);
      Oh[rowbase + nt*16 + m16] = hb;
      Ol[rowbase + nt*16 + m16] = f2bf(v - bf2f(hb));
    }
  }
}

__global__ __launch_bounds__(256) void comb_k(const float* __restrict__ of,
    const float* __restrict__ ob, const float* __restrict__ z,
    const float* __restrict__ skip, float* __restrict__ out)
{
  int idx = blockIdx.x*256 + threadIdx.x;
  int r = idx >> 8;
  out[idx] = z[r]*(of[idx]+ob[idx]) + skip[idx];
}

// ---------------------------------------------------------------------------
struct Params {
  const float *ln_gamma,*ln_beta,*proj_w,*proj_b,*fconv_w,*fconv_b,*bconv_w,*bconv_b,
    *rn0_t,*rn0_c,*ly_w,*ly_b,*lx_w,*lx_b,*lo_w,*lo_b,*c1d_w,*c1d_b,*a_param,
    *ig_w,*ig_b,*ag_w,*ag_b,*mlp0_up_w,*mlp0_up_b,*mlp0_dn_w,*mlp0_dn_b,
    *rn1_t,*rn1_c,*q_w,*k_w,*v_w,*o_w,*o_b,*mlp1_up_w,*mlp1_up_b,*mlp1_dn_w,*mlp1_dn_b;
};

struct WSplit {
  unsigned short *proj_h,*proj_l,*fconv_h,*fconv_l,*bconv_h,*bconv_l,
    *ly_h,*ly_l,*lx_h,*lx_l,*lo_h,*lo_l,*q_h,*q_l,*o_h,*o_l,
    *k_h,*k_l,*v_h,*v_l,
    *up0a_h,*up0a_l,*up0b_h,*up0b_l,*up1a_h,*up1a_l,*up1b_h,*up1b_l,
    *dn0_h,*dn0_l,*dn1_h,*dn1_l;
};

#define USN ((unsigned short*)nullptr)

extern "C" void kernel_launch(void* const* d_in, const int* in_sizes, int n_in,
                              void* d_out, int out_size, void* d_ws, size_t ws_size,
                              hipStream_t stream)
{
  (void)in_sizes; (void)n_in; (void)out_size; (void)ws_size;
  const float* skip = (const float*)d_in[0];
  Params p;
  p.ln_gamma  =(const float*)d_in[1];  p.ln_beta  =(const float*)d_in[2];
  p.proj_w    =(const float*)d_in[3];  p.proj_b   =(const float*)d_in[4];
  p.fconv_w   =(const float*)d_in[5];  p.fconv_b  =(const float*)d_in[6];
  p.bconv_w   =(const float*)d_in[7];  p.bconv_b  =(const float*)d_in[8];
  p.rn0_t     =(const float*)d_in[9];  p.rn0_c    =(const float*)d_in[10];
  p.ly_w      =(const float*)d_in[11]; p.ly_b     =(const float*)d_in[12];
  p.lx_w      =(const float*)d_in[13]; p.lx_b     =(const float*)d_in[14];
  p.lo_w      =(const float*)d_in[15]; p.lo_b     =(const float*)d_in[16];
  p.c1d_w     =(const float*)d_in[17]; p.c1d_b    =(const float*)d_in[18];
  p.a_param   =(const float*)d_in[19];
  p.ig_w      =(const float*)d_in[20]; p.ig_b     =(const float*)d_in[21];
  p.ag_w      =(const float*)d_in[22]; p.ag_b     =(const float*)d_in[23];
  p.mlp0_up_w =(const float*)d_in[24]; p.mlp0_up_b=(const float*)d_in[25];
  p.mlp0_dn_w =(const float*)d_in[26]; p.mlp0_dn_b=(const float*)d_in[27];
  p.rn1_t     =(const float*)d_in[28]; p.rn1_c    =(const float*)d_in[29];
  p.q_w       =(const float*)d_in[30]; p.k_w      =(const float*)d_in[31];
  p.v_w       =(const float*)d_in[32]; p.o_w      =(const float*)d_in[33];
  p.o_b       =(const float*)d_in[34];
  p.mlp1_up_w =(const float*)d_in[35]; p.mlp1_up_b=(const float*)d_in[36];
  p.mlp1_dn_w =(const float*)d_in[37]; p.mlp1_dn_b=(const float*)d_in[38];

  float* ws = (float*)d_ws;
  const size_t RD  = (size_t)RR*DD;    // 4.19M floats
  const size_t PD2 = (size_t)RR2*DD;   // shorts per merged plane
  size_t off = 0;
  float* Z   = ws + off; off += 16384;
  float* XB2 = ws + off; off += 2*RD;  // residual stream; dn1 output (comb input)
  float* CV2 = ws + off; off += 2*RD;  // post-mixer residual; CSA/CSB alias
  float* W1  = ws + off; off += 2*RD;  // X0 planes | XR2 fp32 | Q planes; ACT[0:2RD)
  float* W2  = ws + off; off += 2*RD;  // gate-a fp32 | P2 planes; ACT[2RD:3RD)
  float* W3  = ws + off; off += RD;    // Y hi plane | KP planes + Vt
  float* W4  = ws + off; off += 2*RD;  // NP planes <-> scan3 h*y planes
  // liveness-packed total: 11*RD + Z  (~186 MB) + ~7 MB weights

  float* CSA = CV2;                    // dead window [gate_k, lo-gemm]
  float* CSB = CV2 + 8*NCH*DD;

  unsigned short* NPh = (unsigned short*)W4;  unsigned short* NPl = NPh + PD2;
  unsigned short* HYh = NPh;                  unsigned short* HYl = NPl;   // scan3 out
  unsigned short* X0h = (unsigned short*)W1;  unsigned short* X0l = X0h + (size_t)RR*DD;
  float* XR2 = W1;
  unsigned short* Qph = (unsigned short*)W1;  unsigned short* Qpl = Qph + PD2;
  float* Abuf = W2;
  unsigned short* P2h = (unsigned short*)W2;  unsigned short* P2l = P2h + PD2;
  unsigned short* Yh  = (unsigned short*)W3;
  unsigned short* KPh = (unsigned short*)W3;  unsigned short* KPl = KPh + (size_t)RR2*HDIM;
  unsigned short* Vt  = KPl + (size_t)RR2*HDIM;
  unsigned short* ACTh = (unsigned short*)W1; // spans W1 + first half of W2 (contiguous)
  float* OUT2 = XB2;                          // dn1 writes here (XB2 dead by then)

  unsigned short* sp = (unsigned short*)(ws + off);
  WSplit w;
  auto alloc_s = [&](size_t n){ unsigned short* r = sp; sp += n; return r; };
  const size_t SDD = (size_t)DD*DD, SKV = (size_t)DD*HDIM, SUP = (size_t)DD*EE;
  w.proj_h=alloc_s(SDD);  w.proj_l=alloc_s(SDD);
  w.fconv_h=alloc_s(SDD); w.fconv_l=alloc_s(SDD);
  w.bconv_h=alloc_s(SDD); w.bconv_l=alloc_s(SDD);
  w.ly_h=alloc_s(SDD);    w.ly_l=alloc_s(SDD);
  w.lx_h=alloc_s(SDD);    w.lx_l=alloc_s(SDD);
  w.lo_h=alloc_s(SDD);    w.lo_l=alloc_s(SDD);
  w.q_h=alloc_s(SDD);     w.q_l=alloc_s(SDD);
  w.o_h=alloc_s(SDD);     w.o_l=alloc_s(SDD);
  w.k_h=alloc_s(SKV);     w.k_l=alloc_s(SKV);
  w.v_h=alloc_s(SKV);     w.v_l=alloc_s(SKV);
  w.up0a_h=alloc_s(SUP);  w.up0a_l=alloc_s(SUP);
  w.up0b_h=alloc_s(SUP);  w.up0b_l=alloc_s(SUP);
  w.up1a_h=alloc_s(SUP);  w.up1a_l=alloc_s(SUP);
  w.up1b_h=alloc_s(SUP);  w.up1b_l=alloc_s(SUP);
  w.dn0_h=alloc_s(SUP);   w.dn0_l=alloc_s(SUP);
  w.dn1_h=alloc_s(SUP);   w.dn1_l=alloc_s(SUP);

  dim3 blk(256);
  dim3 g2(2,128,1);                    // prologue: M=16384
  dim3 g2m(2,256,1), g64m(1,256,1), gbd(1,256,4), gdual(12,256,1);

  // ---- weight conversion ----
  {
    TS8 ga;
    ga.t[0] = {p.proj_w,  w.proj_h,  w.proj_l,  DD, DD};
    ga.t[1] = {p.fconv_w, w.fconv_h, w.fconv_l, DD, DD};
    ga.t[2] = {p.bconv_w, w.bconv_h, w.bconv_l, DD, DD};
    ga.t[3] = {p.ly_w,    w.ly_h,    w.ly_l,    DD, DD};
    ga.t[4] = {p.lx_w,    w.lx_h,    w.lx_l,    DD, DD};
    ga.t[5] = {p.lo_w,    w.lo_h,    w.lo_l,    DD, DD};
    ga.t[6] = {p.q_w,     w.q_h,     w.q_l,     DD, DD};
    ga.t[7] = {p.o_w,     w.o_h,     w.o_l,     DD, DD};
    tsplit8_k<<<dim3(DD*DD/256, 8), blk, 0, stream>>>(ga);
    TS8 gb;
    gb.t[0] = {p.k_w,              w.k_h,    w.k_l,    DD, HDIM};
    gb.t[1] = {p.v_w,              w.v_h,    w.v_l,    DD, HDIM};
    gb.t[2] = {p.mlp0_up_w,        w.up0a_h, w.up0a_l, DD, EE};
    gb.t[3] = {p.mlp0_up_w+(size_t)DD*EE, w.up0b_h, w.up0b_l, DD, EE};
    gb.t[4] = {p.mlp1_up_w,        w.up1a_h, w.up1a_l, DD, EE};
    gb.t[5] = {p.mlp1_up_w+(size_t)DD*EE, w.up1b_h, w.up1b_l, DD, EE};
    gb.t[6] = {p.mlp0_dn_w,        w.dn0_h,  w.dn0_l,  EE, DD};
    gb.t[7] = {p.mlp1_dn_w,        w.dn1_h,  w.dn1_l,  EE, DD};
    tsplit8_k<<<dim3(DD*EE/256, 8), blk, 0, stream>>>(gb);
  }

  // ---- prologue: LN, proj, fconv/bconv into XB2 halves ----
  ln_z_k<<<RR/4, blk, 0, stream>>>(skip, p.ln_gamma, p.ln_beta, NPh, NPl, Z);
  gemm_mfma<128,1,0,1,3><<<g2,blk,0,stream>>>(NPh,NPl, w.proj_h,w.proj_l, USN,USN,
      p.proj_b,nullptr,nullptr, nullptr, X0h, X0l, DD,DD,DD);
  gemm_mfma<128,1,0,0,3><<<g2,blk,0,stream>>>(X0h,X0l, w.fconv_h,w.fconv_l, USN,USN,
      p.fconv_b,nullptr,nullptr, XB2, USN,USN, DD,DD,DD);
  gemm_mfma<128,1,0,0,3><<<g2,blk,0,stream>>>(X0h,X0l, w.bconv_h,w.bconv_l, USN,USN,
      p.bconv_b,nullptr,nullptr, XB2 + RD, USN,USN, DD,DD,DD);

  // ---- residual block 0: recurrent (merged, M=32768) ----
  rms_k<<<RR2/4, blk, 0, stream>>>(XB2, p.rn0_t, NPh, NPl);
  gemm_mfma<128,3,0,5,3><<<g2m,blk,0,stream>>>(NPh,NPl, w.ly_h,w.ly_l, USN,USN,
      p.ly_b,nullptr,nullptr, nullptr, Yh, USN, DD,DD,DD);
  gemm_mfma<128,1,0,0,3><<<g2m,blk,0,stream>>>(NPh,NPl, w.lx_h,w.lx_l, USN,USN,
      p.lx_b,nullptr,nullptr, XR2, USN,USN, DD,DD,DD);
  conv_k<<<(size_t)RR2*DD/256, blk, 0, stream>>>(XR2, p.c1d_w, p.c1d_b, CV2);
  gemm_k<64,1><<<gbd,blk,0,stream>>>(CV2,p.ig_w,p.ig_b,Abuf,
      RR2,HDIM,HDIM, DD,HDIM,DD, HDIM, HDIM*HDIM, HDIM, HDIM);
  gemm_k<64,1><<<gbd,blk,0,stream>>>(CV2,p.ag_w,p.ag_b,XR2,
      RR2,HDIM,HDIM, DD,HDIM,DD, HDIM, HDIM*HDIM, HDIM, HDIM);
  gate_k<<<(size_t)RR2*DD/256, blk, 0, stream>>>(CV2, Abuf, XR2, p.a_param);
  scan1_k<<<8*NCH*DD/256, blk,0,stream>>>(Abuf, XR2, CSA, CSB);
  scan2_k<<<8*DD/256, blk,0,stream>>>(CSA, CSB);
  scan3_k<<<8*NCH*DD/256, blk,0,stream>>>(Abuf, XR2, CSB, Yh, HYh, HYl);
  gemm_mfma<128,9,0,0,3><<<g2m,blk,0,stream>>>(HYh,HYl, w.lo_h,w.lo_l, USN,USN,
      p.lo_b,nullptr, XB2, CV2, USN,USN, DD,DD,DD);
  rms_k<<<RR2/4,blk,0,stream>>>(CV2, p.rn0_c, NPh, NPl);
  gemm_mfma<64,1,1,5,2><<<gdual,blk,0,stream>>>(NPh,USN, w.up0a_h,w.up0a_l,
      w.up0b_h,w.up0b_l, p.mlp0_up_b, p.mlp0_up_b+EE, nullptr, nullptr,
      ACTh, USN, DD,DD,EE);
  gemm_mfma<128,9,0,0,2><<<g2m,blk,0,stream>>>(ACTh,USN, w.dn0_h,w.dn0_l, USN,USN,
      p.mlp0_dn_b,nullptr, CV2, XB2, USN,USN, EE,EE,DD);

  // ---- residual block 1: local attention (merged) ----
  rms_k<<<RR2/4,blk,0,stream>>>(XB2, p.rn1_t, NPh, NPl);
  gemm_mfma<128,0,0,2,3><<<g2m,blk,0,stream>>>(NPh,NPl, w.q_h,w.q_l, USN,USN,
      nullptr,nullptr,nullptr, nullptr, Qph, Qpl, DD,DD,DD);
  gemm_mfma<64,0,0,3,3><<<g64m,blk,0,stream>>>(NPh,NPl, w.k_h,w.k_l, USN,USN,
      nullptr,nullptr,nullptr, nullptr, KPh, KPl, DD,DD,HDIM);
  gemm_mfma<64,0,0,4,3><<<g64m,blk,0,stream>>>(NPh,NPl, w.v_h,w.v_l, USN,USN,
      nullptr,nullptr,nullptr, nullptr, Vt, USN, DD,DD,HDIM);
  attn_k<<<dim3(64,4,8),blk,0,stream>>>(Qph, Qpl, KPh, KPl, Vt, P2h, P2l);
  gemm_mfma<128,9,0,0,3><<<g2m,blk,0,stream>>>(P2h,P2l, w.o_h,w.o_l, USN,USN,
      p.o_b,nullptr, XB2, CV2, USN,USN, DD,DD,DD);
  rms_k<<<RR2/4,blk,0,stream>>>(CV2, p.rn1_c, NPh, NPl);
  gemm_mfma<64,1,1,5,2><<<gdual,blk,0,stream>>>(NPh,USN, w.up1a_h,w.up1a_l,
      w.up1b_h,w.up1b_l, p.mlp1_up_b, p.mlp1_up_b+EE, nullptr, nullptr,
      ACTh, USN, DD,DD,EE);
  gemm_mfma<128,9,0,0,2><<<g2m,blk,0,stream>>>(ACTh,USN, w.dn1_h,w.dn1_l, USN,USN,
      p.mlp1_dn_b,nullptr, CV2, OUT2, USN,USN, EE,EE,DD);

  // ---- combine ----
  comb_k<<<RR*DD/256, blk, 0, stream>>>(OUT2, OUT2 + RD, Z, skip, (float*)d_out);
}

// Round 8
// 997.027 us; speedup vs baseline: 2.3696x; 1.0677x over previous
//
#include <hip/hip_runtime.h>
#include <math.h>
#include <stddef.h>

// ---------------------------------------------------------------------------
// BiDiGemma forward. Round 8: R7 + (1) coalesced staging lane-maps (4 lanes
// cover one row's 64B slab -> every 64B line fully consumed per instruction;
// was 16B-of-512B-stride = 4x transactions), (2) tanh fast-gelu in epilogues.
// ---------------------------------------------------------------------------

#define BB   4
#define SS   4096
#define DD   256
#define HH   4
#define HDIM 64
#define EE   768
#define RR   (BB*SS)        // rows per branch
#define RR2  (2*RR)         // merged rows
#define WNN  256
#define CH   64
#define NCH  (SS/CH)

typedef __attribute__((ext_vector_type(8))) short bfrag;
typedef __attribute__((ext_vector_type(4))) float f4acc;

__device__ __forceinline__ float geluf(float x){
  // tanh-form gelu: ~1e-3 max abs dev from erf-gelu; __expf is HW v_exp_f32
  float u = 1.5957691216f*(x + 0.044715f*x*x*x);   // 2*0.7978845608
  float e = __expf(u);
  float t = 1.f - 2.f/(e+1.f);
  return 0.5f*x*(1.f+t);
}
__device__ __forceinline__ float sigm(float x){ return 1.0f/(1.0f+expf(-x)); }

__device__ __forceinline__ unsigned short f2bf(float x){
  unsigned u = __float_as_uint(x);
  return (unsigned short)((u + 0x7FFFu + ((u>>16)&1u)) >> 16);
}
__device__ __forceinline__ float bf2f(unsigned short h){
  return __uint_as_float(((unsigned)h) << 16);
}
__device__ __forceinline__ void split2(float v, unsigned short* h, unsigned short* l){
  unsigned short hb = f2bf(v);
  *h = hb; *l = f2bf(v - bf2f(hb));
}

__device__ __forceinline__ float wredSum(float v){
#pragma unroll
  for(int o=32;o>0;o>>=1) v += __shfl_xor(v,o,64);
  return v;
}

// ---------------------------------------------------------------------------
// LayerNorm(skip) -> hi/lo planes ; z = sigmoid(mean(silu(skip)))
// ---------------------------------------------------------------------------
__global__ __launch_bounds__(256) void ln_z_k(const float* __restrict__ skip,
    const float* __restrict__ g, const float* __restrict__ b,
    unsigned short* __restrict__ oh, unsigned short* __restrict__ ol,
    float* __restrict__ z)
{
  int row  = blockIdx.x*4 + (threadIdx.x>>6);
  int lane = threadIdx.x & 63;
  float4 v = ((const float4*)(skip + (size_t)row*DD))[lane];
  float s  = v.x+v.y+v.z+v.w;
  float sq = v.x*v.x+v.y*v.y+v.z*v.z+v.w*v.w;
  float si = v.x*sigm(v.x)+v.y*sigm(v.y)+v.z*sigm(v.z)+v.w*sigm(v.w);
  s = wredSum(s); sq = wredSum(sq); si = wredSum(si);
  float mean = s*(1.0f/DD);
  float var  = sq*(1.0f/DD) - mean*mean;
  float inv  = rsqrtf(var + 1e-5f);
  float4 gv = ((const float4*)g)[lane];
  float4 bv = ((const float4*)b)[lane];
  float o0 = (v.x-mean)*inv*gv.x + bv.x;
  float o1 = (v.y-mean)*inv*gv.y + bv.y;
  float o2 = (v.z-mean)*inv*gv.z + bv.z;
  float o3 = (v.w-mean)*inv*gv.w + bv.w;
  ushort4 hi, lo;
  split2(o0,&hi.x,&lo.x); split2(o1,&hi.y,&lo.y);
  split2(o2,&hi.z,&lo.z); split2(o3,&hi.w,&lo.w);
  ((ushort4*)(oh + (size_t)row*DD))[lane] = hi;
  ((ushort4*)(ol + (size_t)row*DD))[lane] = lo;
  if(lane==0) z[row] = sigm(si*(1.0f/DD));
}

// ---------------------------------------------------------------------------
// RMSNorm -> hi/lo planes
// ---------------------------------------------------------------------------
__global__ __launch_bounds__(256) void rms_k(const float* __restrict__ x,
    const float* __restrict__ t,
    unsigned short* __restrict__ oh, unsigned short* __restrict__ ol)
{
  int row  = blockIdx.x*4 + (threadIdx.x>>6);
  int lane = threadIdx.x & 63;
  float4 v = ((const float4*)(x + (size_t)row*DD))[lane];
  float sq = v.x*v.x+v.y*v.y+v.z*v.z+v.w*v.w;
  sq = wredSum(sq);
  float inv = rsqrtf(sq*(1.0f/DD) + 1e-6f);
  float4 tv = ((const float4*)t)[lane];
  float o0 = v.x*inv*(1.0f+tv.x);
  float o1 = v.y*inv*(1.0f+tv.y);
  float o2 = v.z*inv*(1.0f+tv.z);
  float o3 = v.w*inv*(1.0f+tv.w);
  ushort4 hi, lo;
  split2(o0,&hi.x,&lo.x); split2(o1,&hi.y,&lo.y);
  split2(o2,&hi.z,&lo.z); split2(o3,&hi.w,&lo.w);
  ((ushort4*)(oh + (size_t)row*DD))[lane] = hi;
  ((ushort4*)(ol + (size_t)row*DD))[lane] = lo;
}

// ---------------------------------------------------------------------------
// Weight transpose + split
// ---------------------------------------------------------------------------
struct TS  { const float* s; unsigned short* h; unsigned short* l; int K; int N; };
struct TS8 { TS t[8]; };

__global__ __launch_bounds__(256) void tsplit8_k(TS8 g){
  TS tt = g.t[blockIdx.y];
  int idx = blockIdx.x*256 + threadIdx.x;
  int tot = tt.K*tt.N;
  if(idx >= tot) return;
  int k = idx / tt.N;
  int n = idx - k*tt.N;
  float x = tt.s[idx];
  unsigned short hb = f2bf(x);
  unsigned short lb = f2bf(x - bf2f(hb));
  tt.h[(size_t)n*tt.K + k] = hb;
  tt.l[(size_t)n*tt.K + k] = lb;
}

// ---------------------------------------------------------------------------
// Split-bf16 MFMA GEMM, pre-split A planes, coalesced copy staging.
// MODE bits: 1=bias0, 2=gelu, 8=+Res(fp32).
// DUAL: C = gelu(A@B0+b0)*(A@B1+b1).
// OUT: 0=fp32; 1=hi/lo planes; 2=RoPE-q planes (BN=128, *0.125);
//      3=RoPE-k planes (BN=64); 4=V^T bf16; 5=hi plane only.
// TERMS: 3 = AhBh+AhBl+AlBh ; 2 = AhBh+AhBl (A-lo ignored, Al_g unused).
// ST=40 shorts (80 B): rows 16B-aligned; 2-way-max bank aliasing (free).
// Staging: 4 lanes per row cover the row's 4x16B chunks (full 64B lines).
// ---------------------------------------------------------------------------
template<int BN, int MODE, int DUAL, int OUT, int TERMS>
__global__ __launch_bounds__(256) void gemm_mfma(
    const unsigned short* __restrict__ Ah_g, const unsigned short* __restrict__ Al_g,
    const unsigned short* __restrict__ B0h, const unsigned short* __restrict__ B0l,
    const unsigned short* __restrict__ B1h, const unsigned short* __restrict__ B1l,
    const float* __restrict__ bias0, const float* __restrict__ bias1,
    const float* __restrict__ Res, float* __restrict__ C,
    unsigned short* __restrict__ Ch, unsigned short* __restrict__ Cl,
    int K, int lda, int ldc)
{
  constexpr int NT = BN/32;
  constexpr int ST = 40;
  __shared__ unsigned short Ash[128*ST];
  __shared__ unsigned short Asl[TERMS==3 ? 128*ST : 8];
  __shared__ unsigned short Bsh[BN*ST],  Bsl[BN*ST];
  __shared__ unsigned short B2h[DUAL?BN*ST:8], B2l[DUAL?BN*ST:8];

  const int tid  = threadIdx.x;
  const int lane = tid & 63, wave = tid >> 6;
  const int wm = wave >> 1, wn = wave & 1;
  const int bm = blockIdx.y*128, bn = blockIdx.x*BN;
  const int m16 = lane & 15, q = lane >> 4;

  f4acc acc[4][NT];
  f4acc acc2[DUAL?4:1][DUAL?NT:1];
#pragma unroll
  for(int i=0;i<4;i++)
#pragma unroll
    for(int j=0;j<NT;j++){
      acc[i][j] = (f4acc)0.f;
      if constexpr(DUAL) acc2[i][j] = (f4acc)0.f;
    }

  // staging map: 4 lanes per row; r0 in [0,64), chunk c0 in [0,4)
  const int r0 = tid >> 2, c0 = tid & 3;
  const int coff = c0*8;                       // shorts
  const int d0 = r0*ST + coff, d1 = (r0+64)*ST + coff;

  const unsigned short* pAh0 = Ah_g + (size_t)(bm+r0)*lda + coff;
  const unsigned short* pAh1 = pAh0 + (size_t)64*lda;
  const unsigned short* pAl0 = (TERMS==3) ? (Al_g + (size_t)(bm+r0)*lda + coff)
                                          : (const unsigned short*)nullptr;
  const unsigned short* pAl1 = (TERMS==3) ? (pAl0 + (size_t)64*lda)
                                          : (const unsigned short*)nullptr;
  const unsigned short *pB0h0=nullptr,*pB0h1=nullptr,*pB0l0=nullptr,*pB0l1=nullptr;
  const unsigned short *pBa=nullptr,*pBb=nullptr,*pBc=nullptr,*pBd=nullptr;
  if constexpr(BN==128){
    pB0h0 = B0h + (size_t)(bn+r0)*K + coff;  pB0h1 = pB0h0 + (size_t)64*K;
    pB0l0 = B0l + (size_t)(bn+r0)*K + coff;  pB0l1 = pB0l0 + (size_t)64*K;
  } else {
    pBa = B0h + (size_t)(bn+r0)*K + coff;
    pBb = B0l + (size_t)(bn+r0)*K + coff;
    if constexpr(DUAL){
      pBc = B1h + (size_t)(bn+r0)*K + coff;
      pBd = B1l + (size_t)(bn+r0)*K + coff;
    }
  }

  for(int k0 = 0; k0 < K; k0 += 32){
    // ---- A stage ----
    *(float4*)&Ash[d0] = *(const float4*)(pAh0 + k0);
    *(float4*)&Ash[d1] = *(const float4*)(pAh1 + k0);
    if constexpr(TERMS==3){
      *(float4*)&Asl[d0] = *(const float4*)(pAl0 + k0);
      *(float4*)&Asl[d1] = *(const float4*)(pAl1 + k0);
    }
    // ---- B stage ----
    if constexpr(BN==128){
      *(float4*)&Bsh[d0] = *(const float4*)(pB0h0 + k0);
      *(float4*)&Bsh[d1] = *(const float4*)(pB0h1 + k0);
      *(float4*)&Bsl[d0] = *(const float4*)(pB0l0 + k0);
      *(float4*)&Bsl[d1] = *(const float4*)(pB0l1 + k0);
    } else {
      *(float4*)&Bsh[d0] = *(const float4*)(pBa + k0);
      *(float4*)&Bsl[d0] = *(const float4*)(pBb + k0);
      if constexpr(DUAL){
        *(float4*)&B2h[d0] = *(const float4*)(pBc + k0);
        *(float4*)&B2l[d0] = *(const float4*)(pBd + k0);
      }
    }
    __syncthreads();

    bfrag ah[4], al[TERMS==3?4:1], b0hf[NT], b0lf[NT];
    bfrag b1hf[DUAL?NT:1], b1lf[DUAL?NT:1];
#pragma unroll
    for(int mi=0;mi<4;mi++){
      int row = wm*64 + mi*16 + m16;
      ah[mi] = *(const bfrag*)&Ash[row*ST + q*8];
      if constexpr(TERMS==3) al[mi] = *(const bfrag*)&Asl[row*ST + q*8];
    }
#pragma unroll
    for(int ni=0;ni<NT;ni++){
      int n = wn*(BN/2) + ni*16 + m16;
      b0hf[ni] = *(const bfrag*)&Bsh[n*ST + q*8];
      b0lf[ni] = *(const bfrag*)&Bsl[n*ST + q*8];
      if constexpr(DUAL){
        b1hf[ni] = *(const bfrag*)&B2h[n*ST + q*8];
        b1lf[ni] = *(const bfrag*)&B2l[n*ST + q*8];
      }
    }
#pragma unroll
    for(int mi=0;mi<4;mi++)
#pragma unroll
      for(int ni=0;ni<NT;ni++){
        acc[mi][ni] = __builtin_amdgcn_mfma_f32_16x16x32_bf16(ah[mi], b0hf[ni], acc[mi][ni],0,0,0);
        acc[mi][ni] = __builtin_amdgcn_mfma_f32_16x16x32_bf16(ah[mi], b0lf[ni], acc[mi][ni],0,0,0);
        if constexpr(TERMS==3)
          acc[mi][ni] = __builtin_amdgcn_mfma_f32_16x16x32_bf16(al[mi], b0hf[ni], acc[mi][ni],0,0,0);
        if constexpr(DUAL){
          acc2[mi][ni] = __builtin_amdgcn_mfma_f32_16x16x32_bf16(ah[mi], b1hf[ni], acc2[mi][ni],0,0,0);
          acc2[mi][ni] = __builtin_amdgcn_mfma_f32_16x16x32_bf16(ah[mi], b1lf[ni], acc2[mi][ni],0,0,0);
          if constexpr(TERMS==3)
            acc2[mi][ni] = __builtin_amdgcn_mfma_f32_16x16x32_bf16(al[mi], b1hf[ni], acc2[mi][ni],0,0,0);
        }
      }
    __syncthreads();
  }

  // ---- epilogue (C/D layout: col = lane&15, row = q*4 + r) ----
  if constexpr(OUT==0 || OUT==1 || OUT==5){
#pragma unroll
    for(int ni=0;ni<NT;ni++){
      const int col = bn + wn*(BN/2) + ni*16 + m16;
      float bv0 = (MODE&1) ? bias0[col] : 0.f;
      float bv1 = DUAL ? bias1[col] : 0.f;
#pragma unroll
      for(int mi=0;mi<4;mi++){
#pragma unroll
        for(int r=0;r<4;r++){
          const int row = bm + wm*64 + mi*16 + q*4 + r;
          float v = acc[mi][ni][r] + bv0;
          if constexpr(DUAL){
            float v2 = acc2[mi][ni][r] + bv1;
            v = geluf(v) * v2;
          } else if(MODE&2){
            v = geluf(v);
          }
          if(MODE&8) v += Res[(size_t)row*ldc + col];
          if constexpr(OUT==0){
            C[(size_t)row*ldc + col] = v;
          } else if constexpr(OUT==1){
            unsigned short hb = f2bf(v);
            Ch[(size_t)row*ldc + col] = hb;
            Cl[(size_t)row*ldc + col] = f2bf(v - bf2f(hb));
          } else {
            Ch[(size_t)row*ldc + col] = f2bf(v);
          }
        }
      }
    }
  } else if constexpr(OUT==2){
    const int hb = bn + wn*64;
    const float p = (float)m16;
    const float invf = __expf(-p * 0.575646273248511f);
#pragma unroll
    for(int mi=0;mi<4;mi++){
#pragma unroll
      for(int r=0;r<4;r++){
        const int row = bm + wm*64 + mi*16 + q*4 + r;
        const int s = row & (SS-1);
        float t = (float)s * invf;
        float sn, cs; __sincosf(t, &sn, &cs);
        float x1 = acc[mi][0][r], x2 = acc[mi][1][r];
        float v0 = (x1*cs - x2*sn)*0.125f;
        float v1 = (x2*cs + x1*sn)*0.125f;
        float v2 = acc[mi][2][r]*0.125f;
        float v3 = acc[mi][3][r]*0.125f;
        size_t base = (size_t)row*ldc + hb;
        unsigned short hh;
        hh=f2bf(v0); Ch[base+m16]=hh;    Cl[base+m16]   =f2bf(v0-bf2f(hh));
        hh=f2bf(v1); Ch[base+16+m16]=hh; Cl[base+16+m16]=f2bf(v1-bf2f(hh));
        hh=f2bf(v2); Ch[base+32+m16]=hh; Cl[base+32+m16]=f2bf(v2-bf2f(hh));
        hh=f2bf(v3); Ch[base+48+m16]=hh; Cl[base+48+m16]=f2bf(v3-bf2f(hh));
      }
    }
  } else if constexpr(OUT==3){
    const float p = (float)m16;
    const float invf = __expf(-p * 0.575646273248511f);
#pragma unroll
    for(int mi=0;mi<4;mi++){
#pragma unroll
      for(int r=0;r<4;r++){
        const int row = bm + wm*64 + mi*16 + q*4 + r;
        const int s = row & (SS-1);
        float v0, v1;
        if(wn==0){
          float t = (float)s * invf;
          float sn, cs; __sincosf(t, &sn, &cs);
          float x1 = acc[mi][0][r], x2 = acc[mi][1][r];
          v0 = x1*cs - x2*sn;
          v1 = x2*cs + x1*sn;
        } else {
          v0 = acc[mi][0][r]; v1 = acc[mi][1][r];
        }
        size_t base = (size_t)row*ldc + wn*32;
        unsigned short hh;
        hh=f2bf(v0); Ch[base+m16]=hh;    Cl[base+m16]   =f2bf(v0-bf2f(hh));
        hh=f2bf(v1); Ch[base+16+m16]=hh; Cl[base+16+m16]=f2bf(v1-bf2f(hh));
      }
    }
  } else if constexpr(OUT==4){
#pragma unroll
    for(int ni=0;ni<NT;ni++){
      const int col = wn*32 + ni*16 + m16;
#pragma unroll
      for(int mi=0;mi<4;mi++){
        const int rowb = bm + wm*64 + mi*16 + q*4;
        const int b = rowb >> 12, sl = rowb & (SS-1);
        ushort4 hv;
        hv.x = f2bf(acc[mi][ni][0]); hv.y = f2bf(acc[mi][ni][1]);
        hv.z = f2bf(acc[mi][ni][2]); hv.w = f2bf(acc[mi][ni][3]);
        *(ushort4*)(Ch + ((size_t)(b*64 + col))*SS + sl) = hv;
      }
    }
  }
}

// fp32 GEMM for block-diagonal gate linears (A-staging coalesced: 4 lanes/row).
template<int BN, int MODE>
__global__ __launch_bounds__(256) void gemm_k(
    const float* __restrict__ A,
    const float* __restrict__ B0,
    const float* __restrict__ bias0,
    float* __restrict__ C,
    int M, int N, int K, int lda, int ldb, int ldc,
    int batA, int batB, int batC, int batBias)
{
  constexpr int BK = 16;
  constexpr int TN = BN/16;
  constexpr int NH = BN/64;
  __shared__ float Ask[BK][132];
  __shared__ float Bs [BK][BN+4];

  const int bz = blockIdx.z;
  const float* Ab  = A  + (size_t)bz*batA;
  const float* Bb  = B0 + (size_t)bz*batB;
  float* Cb = C + (size_t)bz*batC;

  const int bm = blockIdx.y*128, bn = blockIdx.x*BN;
  const int tid = threadIdx.x;
  const int tx = tid & 15, ty = tid >> 4;
  const int r0 = tid >> 2, c0 = (tid & 3)*4;
  const int br = tid >> 4;

  float acc[8][TN];
#pragma unroll
  for(int i=0;i<8;i++)
#pragma unroll
    for(int j=0;j<TN;j++) acc[i][j]=0.f;

  for(int k0=0;k0<K;k0+=BK){
#pragma unroll
    for(int hf=0;hf<2;hf++){
      float4 av = *(const float4*)(Ab + (size_t)(bm+r0+hf*64)*lda + (k0+c0));
      Ask[c0+0][r0+hf*64]=av.x; Ask[c0+1][r0+hf*64]=av.y;
      Ask[c0+2][r0+hf*64]=av.z; Ask[c0+3][r0+hf*64]=av.w;
    }
    {
      const int bc = (tid&15)*4;
      *(float4*)&Bs[br][bc] = *(const float4*)(Bb + (size_t)(k0+br)*ldb + (bn+bc));
    }
    __syncthreads();
#pragma unroll
    for(int k=0;k<BK;k++){
      float a[8];
      *(float4*)&a[0] = *(const float4*)&Ask[k][ty*8];
      *(float4*)&a[4] = *(const float4*)&Ask[k][ty*8+4];
      float bv[TN];
#pragma unroll
      for(int hh=0;hh<NH;hh++)
        *(float4*)&bv[hh*4] = *(const float4*)&Bs[k][hh*64 + tx*4];
#pragma unroll
      for(int i=0;i<8;i++)
#pragma unroll
        for(int j=0;j<TN;j++)
          acc[i][j] = fmaf(a[i], bv[j], acc[i][j]);
    }
    __syncthreads();
  }

#pragma unroll
  for(int i=0;i<8;i++){
    const int row = bm + ty*8 + i;
#pragma unroll
    for(int hh=0;hh<NH;hh++){
      const int col = bn + hh*64 + tx*4;
      float v0=acc[i][hh*4+0], v1=acc[i][hh*4+1], v2=acc[i][hh*4+2], v3=acc[i][hh*4+3];
      if(MODE&1){
        float4 bbv = *(const float4*)(bias0 + (size_t)bz*batBias + col);
        v0+=bbv.x; v1+=bbv.y; v2+=bbv.z; v3+=bbv.w;
      }
      float4 ov; ov.x=v0; ov.y=v1; ov.z=v2; ov.w=v3;
      *(float4*)(Cb + (size_t)row*ldc + col) = ov;
    }
  }
}

__global__ __launch_bounds__(256) void conv_k(const float* __restrict__ x,
    const float* __restrict__ w, const float* __restrict__ b, float* __restrict__ out)
{
  int idx = blockIdx.x*256 + threadIdx.x;
  int d = idx & (DD-1);
  int r = idx >> 8;
  int s = r & (SS-1);
  float acc = b[d];
#pragma unroll
  for(int i=0;i<4;i++){
    int t = s - 3 + i;
    if(t >= 0) acc += w[i*DD + d] * x[(size_t)(r-3+i)*DD + d];
  }
  out[idx] = acc;
}

__global__ __launch_bounds__(256) void gate_k(const float* __restrict__ x,
    float* __restrict__ ig, float* __restrict__ ag, const float* __restrict__ ap)
{
  int idx = blockIdx.x*256 + threadIdx.x;
  int d = idx & (DD-1);
  int r = idx >> 8;
  int s = r & (SS-1);
  float gx = sigm(ig[idx]);
  float ga = sigm(ag[idx]);
  float a_ = ap[d];
  float sp = (a_ > 20.f) ? a_ : log1pf(expf(a_));
  float la = -8.f * ga * sp;
  float a  = expf(la);
  float mult = (s==0) ? 1.f : sqrtf(fmaxf(-expm1f(2.f*la), 0.f));
  float bt = x[idx] * gx * mult;
  ig[idx] = a;
  ag[idx] = bt;
}

__global__ __launch_bounds__(256) void scan1_k(const float* __restrict__ A,
    const float* __restrict__ Bv, float* __restrict__ csa, float* __restrict__ csb)
{
  int idx = blockIdx.x*256 + threadIdx.x;   // < 8*NCH*DD
  int d = idx & (DD-1);
  int c = (idx >> 8) & (NCH-1);
  int b = idx >> 14;                        // 0..7
  size_t base = ((size_t)b*SS + (size_t)c*CH)*DD + d;
  float Aa = 1.f, Bb_ = 0.f;
  for(int t=0;t<CH;t++){
    float a  = A [base + (size_t)t*DD];
    float bb = Bv[base + (size_t)t*DD];
    Aa  = a*Aa;
    Bb_ = a*Bb_ + bb;
  }
  csa[idx] = Aa; csb[idx] = Bb_;
}

__global__ __launch_bounds__(256) void scan2_k(const float* __restrict__ csa,
    float* __restrict__ csb)
{
  int idx = blockIdx.x*256 + threadIdx.x;   // < 8*DD
  int d = idx & (DD-1);
  int b = idx >> 8;
  float h = 0.f;
  for(int c=0;c<NCH;c++){
    size_t i = ((size_t)b*NCH + c)*DD + d;
    float Aa = csa[i], Bb_ = csb[i];
    csb[i] = h;
    h = Aa*h + Bb_;
  }
}

// scan3: finish recurrence, multiply by gelu branch y (bf16 hi), write planes.
__global__ __launch_bounds__(256) void scan3_k(const float* __restrict__ A,
    const float* __restrict__ Bv, const float* __restrict__ csb,
    const unsigned short* __restrict__ Yh,
    unsigned short* __restrict__ Hh, unsigned short* __restrict__ Hl)
{
  int idx = blockIdx.x*256 + threadIdx.x;
  int d = idx & (DD-1);
  int c = (idx >> 8) & (NCH-1);
  int b = idx >> 14;
  size_t base = ((size_t)b*SS + (size_t)c*CH)*DD + d;
  float h = csb[idx];
  for(int t=0;t<CH;t++){
    float a  = A [base + (size_t)t*DD];
    float bb = Bv[base + (size_t)t*DD];
    h = a*h + bb;
    float v = h * bf2f(Yh[base + (size_t)t*DD]);
    unsigned short hb = f2bf(v);
    Hh[base + (size_t)t*DD] = hb;
    Hl[base + (size_t)t*DD] = f2bf(v - bf2f(hb));
  }
}

// ---------------------------------------------------------------------------
// MFMA flash attention (unchanged from R7).
// ---------------------------------------------------------------------------
#define AST 72
__global__ __launch_bounds__(256) void attn_k(
    const unsigned short* __restrict__ Qh, const unsigned short* __restrict__ Ql,
    const unsigned short* __restrict__ Kh, const unsigned short* __restrict__ Kl,
    const unsigned short* __restrict__ Vt,
    unsigned short* __restrict__ Oh, unsigned short* __restrict__ Ol)
{
  __shared__ unsigned short Ksh[64*AST], Ksl[64*AST], Vsh[64*AST];
  __shared__ unsigned short Ps[4*16*AST];

  const int qt = blockIdx.x & 3, n = blockIdx.x >> 2;
  const int h = blockIdx.y, b = blockIdx.z;
  const int tid = threadIdx.x;
  const int lane = tid & 63, w = tid >> 6;
  const int m16 = lane & 15, q = lane >> 4;
  const int s0 = n*WNN + qt*64;

  const size_t qro = ((size_t)(b*SS + s0 + w*16 + m16))*DD + h*HDIM + q*8;
  bfrag qh0 = *(const bfrag*)(Qh + qro);
  bfrag qh1 = *(const bfrag*)(Qh + qro + 32);
  bfrag ql0 = *(const bfrag*)(Ql + qro);
  bfrag ql1 = *(const bfrag*)(Ql + qro + 32);

  float mrow[4], lrow[4];
  f4acc oacc[4];
#pragma unroll
  for(int i=0;i<4;i++){ mrow[i]=-3.0e38f; lrow[i]=0.f; oacc[i]=(f4acc)0.f; }

  const int ktlo = (n==0) ? 4 : qt;
  const int kthi = qt + 4;
  const int sr = tid >> 2, sc = tid & 3;

  for(int kt=ktlo; kt<=kthi; kt++){
    const int kbase = (n-1)*WNN + kt*64;
#pragma unroll
    for(int cc=0; cc<2; cc++){
      int g = sc + cc*4;
      *(float4*)&Ksh[sr*AST + g*8] =
        *(const float4*)(Kh + (size_t)(b*SS + kbase + sr)*HDIM + g*8);
      *(float4*)&Ksl[sr*AST + g*8] =
        *(const float4*)(Kl + (size_t)(b*SS + kbase + sr)*HDIM + g*8);
      *(float4*)&Vsh[sr*AST + g*8] =
        *(const float4*)(Vt + ((size_t)(b*64 + sr))*SS + kbase + g*8);
    }
    __syncthreads();

    f4acc sacc[4];
#pragma unroll
    for(int nt=0;nt<4;nt++) sacc[nt] = (f4acc)0.f;
#pragma unroll
    for(int nt=0;nt<4;nt++){
      const int kr = (nt*16+m16)*AST;
      bfrag kh0 = *(const bfrag*)&Ksh[kr + q*8];
      bfrag kh1 = *(const bfrag*)&Ksh[kr + 32 + q*8];
      bfrag kl0 = *(const bfrag*)&Ksl[kr + q*8];
      bfrag kl1 = *(const bfrag*)&Ksl[kr + 32 + q*8];
      sacc[nt] = __builtin_amdgcn_mfma_f32_16x16x32_bf16(qh0, kh0, sacc[nt],0,0,0);
      sacc[nt] = __builtin_amdgcn_mfma_f32_16x16x32_bf16(qh0, kl0, sacc[nt],0,0,0);
      sacc[nt] = __builtin_amdgcn_mfma_f32_16x16x32_bf16(ql0, kh0, sacc[nt],0,0,0);
      sacc[nt] = __builtin_amdgcn_mfma_f32_16x16x32_bf16(qh1, kh1, sacc[nt],0,0,0);
      sacc[nt] = __builtin_amdgcn_mfma_f32_16x16x32_bf16(qh1, kl1, sacc[nt],0,0,0);
      sacc[nt] = __builtin_amdgcn_mfma_f32_16x16x32_bf16(ql1, kh1, sacc[nt],0,0,0);
    }

    const bool needlo = (kt == qt+4);
    const bool needhi = (kt == qt);
#pragma unroll
    for(int r=0;r<4;r++){
      int qp = qt*64 + w*16 + q*4 + r;
      float sv[4];
      float tm = -3.0e38f;
#pragma unroll
      for(int nt=0;nt<4;nt++){
        float scv = sacc[nt][r];
        if(needlo || needhi){
          int kj = kt*64 + nt*16 + m16;
          int diff = qp + WNN - kj;
          bool ok = (!needlo || diff >= 0) && (!needhi || diff <= WNN);
          scv = ok ? scv : -3.0e38f;
        }
        sv[nt] = scv;
        tm = fmaxf(tm, scv);
      }
#pragma unroll
      for(int off=1; off<16; off<<=1) tm = fmaxf(tm, __shfl_xor(tm, off, 64));
      float mn = fmaxf(mrow[r], tm);
      float alpha = __expf(mrow[r]-mn);
      float rs = 0.f;
#pragma unroll
      for(int nt=0;nt<4;nt++){
        float pp = __expf(sv[nt]-mn);
        rs += pp;
        Ps[w*16*AST + (q*4+r)*AST + nt*16 + m16] = f2bf(pp);
      }
#pragma unroll
      for(int off=1; off<16; off<<=1) rs += __shfl_xor(rs, off, 64);
      lrow[r] = lrow[r]*alpha + rs;
      mrow[r] = mn;
#pragma unroll
      for(int nt=0;nt<4;nt++) oacc[nt][r] *= alpha;
    }

#pragma unroll
    for(int s=0;s<2;s++){
      bfrag pa = *(const bfrag*)&Ps[w*16*AST + m16*AST + s*32 + q*8];
#pragma unroll
      for(int nt=0;nt<4;nt++){
        bfrag vh_ = *(const bfrag*)&Vsh[(nt*16+m16)*AST + s*32 + q*8];
        oacc[nt] = __builtin_amdgcn_mfma_f32_16x16x32_bf16(pa, vh_, oacc[nt],0,0,0);
      }
    }
    __syncthreads();
  }

#pragma unroll
  for(int r=0;r<4;r++){
    float invl = 1.f/lrow[r];
    const size_t rowbase = ((size_t)(b*SS + s0 + w*16 + q*4 + r))*DD + h*HDIM;
#pragma unroll
    for(int nt=0;nt<4;nt++){
      float v = oacc[nt][r]*invl;
      unsigned short hb = f2bf(v);
      Oh[rowbase + nt*16 + m16] = hb;
      Ol[rowbase + nt*16 + m16] = f2bf(v - bf2f(hb));
    }
  }
}

__global__ __launch_bounds__(256) void comb_k(const float* __restrict__ of,
    const float* __restrict__ ob, const float* __restrict__ z,
    const float* __restrict__ skip, float* __restrict__ out)
{
  int idx = blockIdx.x*256 + threadIdx.x;
  int r = idx >> 8;
  out[idx] = z[r]*(of[idx]+ob[idx]) + skip[idx];
}

// ---------------------------------------------------------------------------
struct Params {
  const float *ln_gamma,*ln_beta,*proj_w,*proj_b,*fconv_w,*fconv_b,*bconv_w,*bconv_b,
    *rn0_t,*rn0_c,*ly_w,*ly_b,*lx_w,*lx_b,*lo_w,*lo_b,*c1d_w,*c1d_b,*a_param,
    *ig_w,*ig_b,*ag_w,*ag_b,*mlp0_up_w,*mlp0_up_b,*mlp0_dn_w,*mlp0_dn_b,
    *rn1_t,*rn1_c,*q_w,*k_w,*v_w,*o_w,*o_b,*mlp1_up_w,*mlp1_up_b,*mlp1_dn_w,*mlp1_dn_b;
};

struct WSplit {
  unsigned short *proj_h,*proj_l,*fconv_h,*fconv_l,*bconv_h,*bconv_l,
    *ly_h,*ly_l,*lx_h,*lx_l,*lo_h,*lo_l,*q_h,*q_l,*o_h,*o_l,
    *k_h,*k_l,*v_h,*v_l,
    *up0a_h,*up0a_l,*up0b_h,*up0b_l,*up1a_h,*up1a_l,*up1b_h,*up1b_l,
    *dn0_h,*dn0_l,*dn1_h,*dn1_l;
};

#define USN ((unsigned short*)nullptr)

extern "C" void kernel_launch(void* const* d_in, const int* in_sizes, int n_in,
                              void* d_out, int out_size, void* d_ws, size_t ws_size,
                              hipStream_t stream)
{
  (void)in_sizes; (void)n_in; (void)out_size; (void)ws_size;
  const float* skip = (const float*)d_in[0];
  Params p;
  p.ln_gamma  =(const float*)d_in[1];  p.ln_beta  =(const float*)d_in[2];
  p.proj_w    =(const float*)d_in[3];  p.proj_b   =(const float*)d_in[4];
  p.fconv_w   =(const float*)d_in[5];  p.fconv_b  =(const float*)d_in[6];
  p.bconv_w   =(const float*)d_in[7];  p.bconv_b  =(const float*)d_in[8];
  p.rn0_t     =(const float*)d_in[9];  p.rn0_c    =(const float*)d_in[10];
  p.ly_w      =(const float*)d_in[11]; p.ly_b     =(const float*)d_in[12];
  p.lx_w      =(const float*)d_in[13]; p.lx_b     =(const float*)d_in[14];
  p.lo_w      =(const float*)d_in[15]; p.lo_b     =(const float*)d_in[16];
  p.c1d_w     =(const float*)d_in[17]; p.c1d_b    =(const float*)d_in[18];
  p.a_param   =(const float*)d_in[19];
  p.ig_w      =(const float*)d_in[20]; p.ig_b     =(const float*)d_in[21];
  p.ag_w      =(const float*)d_in[22]; p.ag_b     =(const float*)d_in[23];
  p.mlp0_up_w =(const float*)d_in[24]; p.mlp0_up_b=(const float*)d_in[25];
  p.mlp0_dn_w =(const float*)d_in[26]; p.mlp0_dn_b=(const float*)d_in[27];
  p.rn1_t     =(const float*)d_in[28]; p.rn1_c    =(const float*)d_in[29];
  p.q_w       =(const float*)d_in[30]; p.k_w      =(const float*)d_in[31];
  p.v_w       =(const float*)d_in[32]; p.o_w      =(const float*)d_in[33];
  p.o_b       =(const float*)d_in[34];
  p.mlp1_up_w =(const float*)d_in[35]; p.mlp1_up_b=(const float*)d_in[36];
  p.mlp1_dn_w =(const float*)d_in[37]; p.mlp1_dn_b=(const float*)d_in[38];

  float* ws = (float*)d_ws;
  const size_t RD  = (size_t)RR*DD;    // 4.19M floats
  const size_t PD2 = (size_t)RR2*DD;   // shorts per merged plane
  size_t off = 0;
  float* Z   = ws + off; off += 16384;
  float* XB2 = ws + off; off += 2*RD;  // residual stream; dn1 output (comb input)
  float* CV2 = ws + off; off += 2*RD;  // post-mixer residual; CSA/CSB alias
  float* W1  = ws + off; off += 2*RD;  // X0 planes | XR2 fp32 | Q planes; ACT[0:2RD)
  float* W2  = ws + off; off += 2*RD;  // gate-a fp32 | P2 planes; ACT[2RD:3RD)
  float* W3  = ws + off; off += RD;    // Y hi plane | KP planes + Vt
  float* W4  = ws + off; off += 2*RD;  // NP planes <-> scan3 h*y planes
  // liveness-packed total: 11*RD + Z  (~186 MB) + ~7 MB weights

  float* CSA = CV2;                    // dead window [gate_k, lo-gemm]
  float* CSB = CV2 + 8*NCH*DD;

  unsigned short* NPh = (unsigned short*)W4;  unsigned short* NPl = NPh + PD2;
  unsigned short* HYh = NPh;                  unsigned short* HYl = NPl;   // scan3 out
  unsigned short* X0h = (unsigned short*)W1;  unsigned short* X0l = X0h + (size_t)RR*DD;
  float* XR2 = W1;
  unsigned short* Qph = (unsigned short*)W1;  unsigned short* Qpl = Qph + PD2;
  float* Abuf = W2;
  unsigned short* P2h = (unsigned short*)W2;  unsigned short* P2l = P2h + PD2;
  unsigned short* Yh  = (unsigned short*)W3;
  unsigned short* KPh = (unsigned short*)W3;  unsigned short* KPl = KPh + (size_t)RR2*HDIM;
  unsigned short* Vt  = KPl + (size_t)RR2*HDIM;
  unsigned short* ACTh = (unsigned short*)W1; // spans W1 + first half of W2 (contiguous)
  float* OUT2 = XB2;                          // dn1 writes here (XB2 dead by then)

  unsigned short* sp = (unsigned short*)(ws + off);
  WSplit w;
  auto alloc_s = [&](size_t n){ unsigned short* r = sp; sp += n; return r; };
  const size_t SDD = (size_t)DD*DD, SKV = (size_t)DD*HDIM, SUP = (size_t)DD*EE;
  w.proj_h=alloc_s(SDD);  w.proj_l=alloc_s(SDD);
  w.fconv_h=alloc_s(SDD); w.fconv_l=alloc_s(SDD);
  w.bconv_h=alloc_s(SDD); w.bconv_l=alloc_s(SDD);
  w.ly_h=alloc_s(SDD);    w.ly_l=alloc_s(SDD);
  w.lx_h=alloc_s(SDD);    w.lx_l=alloc_s(SDD);
  w.lo_h=alloc_s(SDD);    w.lo_l=alloc_s(SDD);
  w.q_h=alloc_s(SDD);     w.q_l=alloc_s(SDD);
  w.o_h=alloc_s(SDD);     w.o_l=alloc_s(SDD);
  w.k_h=alloc_s(SKV);     w.k_l=alloc_s(SKV);
  w.v_h=alloc_s(SKV);     w.v_l=alloc_s(SKV);
  w.up0a_h=alloc_s(SUP);  w.up0a_l=alloc_s(SUP);
  w.up0b_h=alloc_s(SUP);  w.up0b_l=alloc_s(SUP);
  w.up1a_h=alloc_s(SUP);  w.up1a_l=alloc_s(SUP);
  w.up1b_h=alloc_s(SUP);  w.up1b_l=alloc_s(SUP);
  w.dn0_h=alloc_s(SUP);   w.dn0_l=alloc_s(SUP);
  w.dn1_h=alloc_s(SUP);   w.dn1_l=alloc_s(SUP);

  dim3 blk(256);
  dim3 g2(2,128,1);                    // prologue: M=16384
  dim3 g2m(2,256,1), g64m(1,256,1), gbd(1,256,4), gdual(12,256,1);

  // ---- weight conversion ----
  {
    TS8 ga;
    ga.t[0] = {p.proj_w,  w.proj_h,  w.proj_l,  DD, DD};
    ga.t[1] = {p.fconv_w, w.fconv_h, w.fconv_l, DD, DD};
    ga.t[2] = {p.bconv_w, w.bconv_h, w.bconv_l, DD, DD};
    ga.t[3] = {p.ly_w,    w.ly_h,    w.ly_l,    DD, DD};
    ga.t[4] = {p.lx_w,    w.lx_h,    w.lx_l,    DD, DD};
    ga.t[5] = {p.lo_w,    w.lo_h,    w.lo_l,    DD, DD};
    ga.t[6] = {p.q_w,     w.q_h,     w.q_l,     DD, DD};
    ga.t[7] = {p.o_w,     w.o_h,     w.o_l,     DD, DD};
    tsplit8_k<<<dim3(DD*DD/256, 8), blk, 0, stream>>>(ga);
    TS8 gb;
    gb.t[0] = {p.k_w,              w.k_h,    w.k_l,    DD, HDIM};
    gb.t[1] = {p.v_w,              w.v_h,    w.v_l,    DD, HDIM};
    gb.t[2] = {p.mlp0_up_w,        w.up0a_h, w.up0a_l, DD, EE};
    gb.t[3] = {p.mlp0_up_w+(size_t)DD*EE, w.up0b_h, w.up0b_l, DD, EE};
    gb.t[4] = {p.mlp1_up_w,        w.up1a_h, w.up1a_l, DD, EE};
    gb.t[5] = {p.mlp1_up_w+(size_t)DD*EE, w.up1b_h, w.up1b_l, DD, EE};
    gb.t[6] = {p.mlp0_dn_w,        w.dn0_h,  w.dn0_l,  EE, DD};
    gb.t[7] = {p.mlp1_dn_w,        w.dn1_h,  w.dn1_l,  EE, DD};
    tsplit8_k<<<dim3(DD*EE/256, 8), blk, 0, stream>>>(gb);
  }

  // ---- prologue: LN, proj, fconv/bconv into XB2 halves ----
  ln_z_k<<<RR/4, blk, 0, stream>>>(skip, p.ln_gamma, p.ln_beta, NPh, NPl, Z);
  gemm_mfma<128,1,0,1,3><<<g2,blk,0,stream>>>(NPh,NPl, w.proj_h,w.proj_l, USN,USN,
      p.proj_b,nullptr,nullptr, nullptr, X0h, X0l, DD,DD,DD);
  gemm_mfma<128,1,0,0,3><<<g2,blk,0,stream>>>(X0h,X0l, w.fconv_h,w.fconv_l, USN,USN,
      p.fconv_b,nullptr,nullptr, XB2, USN,USN, DD,DD,DD);
  gemm_mfma<128,1,0,0,3><<<g2,blk,0,stream>>>(X0h,X0l, w.bconv_h,w.bconv_l, USN,USN,
      p.bconv_b,nullptr,nullptr, XB2 + RD, USN,USN, DD,DD,DD);

  // ---- residual block 0: recurrent (merged, M=32768) ----
  rms_k<<<RR2/4, blk, 0, stream>>>(XB2, p.rn0_t, NPh, NPl);
  gemm_mfma<128,3,0,5,3><<<g2m,blk,0,stream>>>(NPh,NPl, w.ly_h,w.ly_l, USN,USN,
      p.ly_b,nullptr,nullptr, nullptr, Yh, USN, DD,DD,DD);
  gemm_mfma<128,1,0,0,3><<<g2m,blk,0,stream>>>(NPh,NPl, w.lx_h,w.lx_l, USN,USN,
      p.lx_b,nullptr,nullptr, XR2, USN,USN, DD,DD,DD);
  conv_k<<<(size_t)RR2*DD/256, blk, 0, stream>>>(XR2, p.c1d_w, p.c1d_b, CV2);
  gemm_k<64,1><<<gbd,blk,0,stream>>>(CV2,p.ig_w,p.ig_b,Abuf,
      RR2,HDIM,HDIM, DD,HDIM,DD, HDIM, HDIM*HDIM, HDIM, HDIM);
  gemm_k<64,1><<<gbd,blk,0,stream>>>(CV2,p.ag_w,p.ag_b,XR2,
      RR2,HDIM,HDIM, DD,HDIM,DD, HDIM, HDIM*HDIM, HDIM, HDIM);
  gate_k<<<(size_t)RR2*DD/256, blk, 0, stream>>>(CV2, Abuf, XR2, p.a_param);
  scan1_k<<<8*NCH*DD/256, blk,0,stream>>>(Abuf, XR2, CSA, CSB);
  scan2_k<<<8*DD/256, blk,0,stream>>>(CSA, CSB);
  scan3_k<<<8*NCH*DD/256, blk,0,stream>>>(Abuf, XR2, CSB, Yh, HYh, HYl);
  gemm_mfma<128,9,0,0,3><<<g2m,blk,0,stream>>>(HYh,HYl, w.lo_h,w.lo_l, USN,USN,
      p.lo_b,nullptr, XB2, CV2, USN,USN, DD,DD,DD);
  rms_k<<<RR2/4,blk,0,stream>>>(CV2, p.rn0_c, NPh, NPl);
  gemm_mfma<64,1,1,5,2><<<gdual,blk,0,stream>>>(NPh,USN, w.up0a_h,w.up0a_l,
      w.up0b_h,w.up0b_l, p.mlp0_up_b, p.mlp0_up_b+EE, nullptr, nullptr,
      ACTh, USN, DD,DD,EE);
  gemm_mfma<128,9,0,0,2><<<g2m,blk,0,stream>>>(ACTh,USN, w.dn0_h,w.dn0_l, USN,USN,
      p.mlp0_dn_b,nullptr, CV2, XB2, USN,USN, EE,EE,DD);

  // ---- residual block 1: local attention (merged) ----
  rms_k<<<RR2/4,blk,0,stream>>>(XB2, p.rn1_t, NPh, NPl);
  gemm_mfma<128,0,0,2,3><<<g2m,blk,0,stream>>>(NPh,NPl, w.q_h,w.q_l, USN,USN,
      nullptr,nullptr,nullptr, nullptr, Qph, Qpl, DD,DD,DD);
  gemm_mfma<64,0,0,3,3><<<g64m,blk,0,stream>>>(NPh,NPl, w.k_h,w.k_l, USN,USN,
      nullptr,nullptr,nullptr, nullptr, KPh, KPl, DD,DD,HDIM);
  gemm_mfma<64,0,0,4,3><<<g64m,blk,0,stream>>>(NPh,NPl, w.v_h,w.v_l, USN,USN,
      nullptr,nullptr,nullptr, nullptr, Vt, USN, DD,DD,HDIM);
  attn_k<<<dim3(64,4,8),blk,0,stream>>>(Qph, Qpl, KPh, KPl, Vt, P2h, P2l);
  gemm_mfma<128,9,0,0,3><<<g2m,blk,0,stream>>>(P2h,P2l, w.o_h,w.o_l, USN,USN,
      p.o_b,nullptr, XB2, CV2, USN,USN, DD,DD,DD);
  rms_k<<<RR2/4,blk,0,stream>>>(CV2, p.rn1_c, NPh, NPl);
  gemm_mfma<64,1,1,5,2><<<gdual,blk,0,stream>>>(NPh,USN, w.up1a_h,w.up1a_l,
      w.up1b_h,w.up1b_l, p.mlp1_up_b, p.mlp1_up_b+EE, nullptr, nullptr,
      ACTh, USN, DD,DD,EE);
  gemm_mfma<128,9,0,0,2><<<g2m,blk,0,stream>>>(ACTh,USN, w.dn1_h,w.dn1_l, USN,USN,
      p.mlp1_dn_b,nullptr, CV2, OUT2, USN,USN, EE,EE,DD);

  // ---- combine ----
  comb_k<<<RR*DD/256, blk, 0, stream>>>(OUT2, OUT2 + RD, Z, skip, (float*)d_out);
}

// Round 9
// 820.267 us; speedup vs baseline: 2.8803x; 1.2155x over previous
//
#include <hip/hip_runtime.h>
#include <math.h>
#include <stddef.h>

// ---------------------------------------------------------------------------
// BiDiGemma forward. Round 9: R8 + reduced split terms where precision
// allows: dual-up = pure bf16 (TERMS=1); ly/lx/lo/q/o = 2-term; proj/fconv/
// bconv/k/v stay 3-term; dn stays 2-term. Cuts MFMA + LDS-read traffic in
// the binding dual-up K-loop by 2x.
// ---------------------------------------------------------------------------

#define BB   4
#define SS   4096
#define DD   256
#define HH   4
#define HDIM 64
#define EE   768
#define RR   (BB*SS)        // rows per branch
#define RR2  (2*RR)         // merged rows
#define WNN  256
#define CH   64
#define NCH  (SS/CH)

typedef __attribute__((ext_vector_type(8))) short bfrag;
typedef __attribute__((ext_vector_type(4))) float f4acc;

__device__ __forceinline__ float geluf(float x){
  float u = 1.5957691216f*(x + 0.044715f*x*x*x);
  float e = __expf(u);
  float t = 1.f - 2.f/(e+1.f);
  return 0.5f*x*(1.f+t);
}
__device__ __forceinline__ float sigm(float x){ return 1.0f/(1.0f+expf(-x)); }

__device__ __forceinline__ unsigned short f2bf(float x){
  unsigned u = __float_as_uint(x);
  return (unsigned short)((u + 0x7FFFu + ((u>>16)&1u)) >> 16);
}
__device__ __forceinline__ float bf2f(unsigned short h){
  return __uint_as_float(((unsigned)h) << 16);
}
__device__ __forceinline__ void split2(float v, unsigned short* h, unsigned short* l){
  unsigned short hb = f2bf(v);
  *h = hb; *l = f2bf(v - bf2f(hb));
}

__device__ __forceinline__ float wredSum(float v){
#pragma unroll
  for(int o=32;o>0;o>>=1) v += __shfl_xor(v,o,64);
  return v;
}

// ---------------------------------------------------------------------------
__global__ __launch_bounds__(256) void ln_z_k(const float* __restrict__ skip,
    const float* __restrict__ g, const float* __restrict__ b,
    unsigned short* __restrict__ oh, unsigned short* __restrict__ ol,
    float* __restrict__ z)
{
  int row  = blockIdx.x*4 + (threadIdx.x>>6);
  int lane = threadIdx.x & 63;
  float4 v = ((const float4*)(skip + (size_t)row*DD))[lane];
  float s  = v.x+v.y+v.z+v.w;
  float sq = v.x*v.x+v.y*v.y+v.z*v.z+v.w*v.w;
  float si = v.x*sigm(v.x)+v.y*sigm(v.y)+v.z*sigm(v.z)+v.w*sigm(v.w);
  s = wredSum(s); sq = wredSum(sq); si = wredSum(si);
  float mean = s*(1.0f/DD);
  float var  = sq*(1.0f/DD) - mean*mean;
  float inv  = rsqrtf(var + 1e-5f);
  float4 gv = ((const float4*)g)[lane];
  float4 bv = ((const float4*)b)[lane];
  float o0 = (v.x-mean)*inv*gv.x + bv.x;
  float o1 = (v.y-mean)*inv*gv.y + bv.y;
  float o2 = (v.z-mean)*inv*gv.z + bv.z;
  float o3 = (v.w-mean)*inv*gv.w + bv.w;
  ushort4 hi, lo;
  split2(o0,&hi.x,&lo.x); split2(o1,&hi.y,&lo.y);
  split2(o2,&hi.z,&lo.z); split2(o3,&hi.w,&lo.w);
  ((ushort4*)(oh + (size_t)row*DD))[lane] = hi;
  ((ushort4*)(ol + (size_t)row*DD))[lane] = lo;
  if(lane==0) z[row] = sigm(si*(1.0f/DD));
}

__global__ __launch_bounds__(256) void rms_k(const float* __restrict__ x,
    const float* __restrict__ t,
    unsigned short* __restrict__ oh, unsigned short* __restrict__ ol)
{
  int row  = blockIdx.x*4 + (threadIdx.x>>6);
  int lane = threadIdx.x & 63;
  float4 v = ((const float4*)(x + (size_t)row*DD))[lane];
  float sq = v.x*v.x+v.y*v.y+v.z*v.z+v.w*v.w;
  sq = wredSum(sq);
  float inv = rsqrtf(sq*(1.0f/DD) + 1e-6f);
  float4 tv = ((const float4*)t)[lane];
  float o0 = v.x*inv*(1.0f+tv.x);
  float o1 = v.y*inv*(1.0f+tv.y);
  float o2 = v.z*inv*(1.0f+tv.z);
  float o3 = v.w*inv*(1.0f+tv.w);
  ushort4 hi, lo;
  split2(o0,&hi.x,&lo.x); split2(o1,&hi.y,&lo.y);
  split2(o2,&hi.z,&lo.z); split2(o3,&hi.w,&lo.w);
  ((ushort4*)(oh + (size_t)row*DD))[lane] = hi;
  ((ushort4*)(ol + (size_t)row*DD))[lane] = lo;
}

// ---------------------------------------------------------------------------
struct TS  { const float* s; unsigned short* h; unsigned short* l; int K; int N; };
struct TS8 { TS t[8]; };

__global__ __launch_bounds__(256) void tsplit8_k(TS8 g){
  TS tt = g.t[blockIdx.y];
  int idx = blockIdx.x*256 + threadIdx.x;
  int tot = tt.K*tt.N;
  if(idx >= tot) return;
  int k = idx / tt.N;
  int n = idx - k*tt.N;
  float x = tt.s[idx];
  unsigned short hb = f2bf(x);
  unsigned short lb = f2bf(x - bf2f(hb));
  tt.h[(size_t)n*tt.K + k] = hb;
  tt.l[(size_t)n*tt.K + k] = lb;
}

// ---------------------------------------------------------------------------
// Split-bf16 MFMA GEMM.
// TERMS: 3 = AhBh+AhBl+AlBh ; 2 = AhBh+AhBl ; 1 = AhBh (pure bf16).
// MODE bits: 1=bias0, 2=gelu, 8=+Res. DUAL: gelu(A@B0+b0)*(A@B1+b1).
// OUT: 0 fp32; 1 hi/lo planes; 2 RoPE-q; 3 RoPE-k; 4 V^T bf16; 5 hi-only.
// ---------------------------------------------------------------------------
template<int BN, int MODE, int DUAL, int OUT, int TERMS>
__global__ __launch_bounds__(256) void gemm_mfma(
    const unsigned short* __restrict__ Ah_g, const unsigned short* __restrict__ Al_g,
    const unsigned short* __restrict__ B0h, const unsigned short* __restrict__ B0l,
    const unsigned short* __restrict__ B1h, const unsigned short* __restrict__ B1l,
    const float* __restrict__ bias0, const float* __restrict__ bias1,
    const float* __restrict__ Res, float* __restrict__ C,
    unsigned short* __restrict__ Ch, unsigned short* __restrict__ Cl,
    int K, int lda, int ldc)
{
  constexpr int NT = BN/32;
  constexpr int ST = 40;
  __shared__ unsigned short Ash[128*ST];
  __shared__ unsigned short Asl[TERMS==3 ? 128*ST : 8];
  __shared__ unsigned short Bsh[BN*ST];
  __shared__ unsigned short Bsl[TERMS>=2 ? BN*ST : 8];
  __shared__ unsigned short B2h[DUAL?BN*ST:8];
  __shared__ unsigned short B2l[(DUAL && TERMS>=2)?BN*ST:8];

  const int tid  = threadIdx.x;
  const int lane = tid & 63, wave = tid >> 6;
  const int wm = wave >> 1, wn = wave & 1;
  const int bm = blockIdx.y*128, bn = blockIdx.x*BN;
  const int m16 = lane & 15, q = lane >> 4;

  f4acc acc[4][NT];
  f4acc acc2[DUAL?4:1][DUAL?NT:1];
#pragma unroll
  for(int i=0;i<4;i++)
#pragma unroll
    for(int j=0;j<NT;j++){
      acc[i][j] = (f4acc)0.f;
      if constexpr(DUAL) acc2[i][j] = (f4acc)0.f;
    }

  // staging map: 4 lanes per row; r0 in [0,64), chunk c0 in [0,4)
  const int r0 = tid >> 2, c0 = tid & 3;
  const int coff = c0*8;
  const int d0 = r0*ST + coff, d1 = (r0+64)*ST + coff;

  const unsigned short* pAh0 = Ah_g + (size_t)(bm+r0)*lda + coff;
  const unsigned short* pAh1 = pAh0 + (size_t)64*lda;
  const unsigned short* pAl0 = (TERMS==3) ? (Al_g + (size_t)(bm+r0)*lda + coff)
                                          : (const unsigned short*)nullptr;
  const unsigned short* pAl1 = (TERMS==3) ? (pAl0 + (size_t)64*lda)
                                          : (const unsigned short*)nullptr;
  const unsigned short *pB0h0=nullptr,*pB0h1=nullptr,*pB0l0=nullptr,*pB0l1=nullptr;
  const unsigned short *pBa=nullptr,*pBb=nullptr,*pBc=nullptr,*pBd=nullptr;
  if constexpr(BN==128){
    pB0h0 = B0h + (size_t)(bn+r0)*K + coff;  pB0h1 = pB0h0 + (size_t)64*K;
    if constexpr(TERMS>=2){
      pB0l0 = B0l + (size_t)(bn+r0)*K + coff;  pB0l1 = pB0l0 + (size_t)64*K;
    }
  } else {
    pBa = B0h + (size_t)(bn+r0)*K + coff;
    if constexpr(TERMS>=2) pBb = B0l + (size_t)(bn+r0)*K + coff;
    if constexpr(DUAL){
      pBc = B1h + (size_t)(bn+r0)*K + coff;
      if constexpr(TERMS>=2) pBd = B1l + (size_t)(bn+r0)*K + coff;
    }
  }

  for(int k0 = 0; k0 < K; k0 += 32){
    // ---- A stage ----
    *(float4*)&Ash[d0] = *(const float4*)(pAh0 + k0);
    *(float4*)&Ash[d1] = *(const float4*)(pAh1 + k0);
    if constexpr(TERMS==3){
      *(float4*)&Asl[d0] = *(const float4*)(pAl0 + k0);
      *(float4*)&Asl[d1] = *(const float4*)(pAl1 + k0);
    }
    // ---- B stage ----
    if constexpr(BN==128){
      *(float4*)&Bsh[d0] = *(const float4*)(pB0h0 + k0);
      *(float4*)&Bsh[d1] = *(const float4*)(pB0h1 + k0);
      if constexpr(TERMS>=2){
        *(float4*)&Bsl[d0] = *(const float4*)(pB0l0 + k0);
        *(float4*)&Bsl[d1] = *(const float4*)(pB0l1 + k0);
      }
    } else {
      *(float4*)&Bsh[d0] = *(const float4*)(pBa + k0);
      if constexpr(TERMS>=2) *(float4*)&Bsl[d0] = *(const float4*)(pBb + k0);
      if constexpr(DUAL){
        *(float4*)&B2h[d0] = *(const float4*)(pBc + k0);
        if constexpr(TERMS>=2) *(float4*)&B2l[d0] = *(const float4*)(pBd + k0);
      }
    }
    __syncthreads();

    bfrag ah[4], al[TERMS==3?4:1], b0hf[NT], b0lf[TERMS>=2?NT:1];
    bfrag b1hf[DUAL?NT:1], b1lf[(DUAL&&TERMS>=2)?NT:1];
#pragma unroll
    for(int mi=0;mi<4;mi++){
      int row = wm*64 + mi*16 + m16;
      ah[mi] = *(const bfrag*)&Ash[row*ST + q*8];
      if constexpr(TERMS==3) al[mi] = *(const bfrag*)&Asl[row*ST + q*8];
    }
#pragma unroll
    for(int ni=0;ni<NT;ni++){
      int n = wn*(BN/2) + ni*16 + m16;
      b0hf[ni] = *(const bfrag*)&Bsh[n*ST + q*8];
      if constexpr(TERMS>=2) b0lf[ni] = *(const bfrag*)&Bsl[n*ST + q*8];
      if constexpr(DUAL){
        b1hf[ni] = *(const bfrag*)&B2h[n*ST + q*8];
        if constexpr(TERMS>=2) b1lf[ni] = *(const bfrag*)&B2l[n*ST + q*8];
      }
    }
#pragma unroll
    for(int mi=0;mi<4;mi++)
#pragma unroll
      for(int ni=0;ni<NT;ni++){
        acc[mi][ni] = __builtin_amdgcn_mfma_f32_16x16x32_bf16(ah[mi], b0hf[ni], acc[mi][ni],0,0,0);
        if constexpr(TERMS>=2)
          acc[mi][ni] = __builtin_amdgcn_mfma_f32_16x16x32_bf16(ah[mi], b0lf[ni], acc[mi][ni],0,0,0);
        if constexpr(TERMS==3)
          acc[mi][ni] = __builtin_amdgcn_mfma_f32_16x16x32_bf16(al[mi], b0hf[ni], acc[mi][ni],0,0,0);
        if constexpr(DUAL){
          acc2[mi][ni] = __builtin_amdgcn_mfma_f32_16x16x32_bf16(ah[mi], b1hf[ni], acc2[mi][ni],0,0,0);
          if constexpr(TERMS>=2)
            acc2[mi][ni] = __builtin_amdgcn_mfma_f32_16x16x32_bf16(ah[mi], b1lf[ni], acc2[mi][ni],0,0,0);
          if constexpr(TERMS==3)
            acc2[mi][ni] = __builtin_amdgcn_mfma_f32_16x16x32_bf16(al[mi], b1hf[ni], acc2[mi][ni],0,0,0);
        }
      }
    __syncthreads();
  }

  // ---- epilogue ----
  if constexpr(OUT==0 || OUT==1 || OUT==5){
#pragma unroll
    for(int ni=0;ni<NT;ni++){
      const int col = bn + wn*(BN/2) + ni*16 + m16;
      float bv0 = (MODE&1) ? bias0[col] : 0.f;
      float bv1 = DUAL ? bias1[col] : 0.f;
#pragma unroll
      for(int mi=0;mi<4;mi++){
#pragma unroll
        for(int r=0;r<4;r++){
          const int row = bm + wm*64 + mi*16 + q*4 + r;
          float v = acc[mi][ni][r] + bv0;
          if constexpr(DUAL){
            float v2 = acc2[mi][ni][r] + bv1;
            v = geluf(v) * v2;
          } else if(MODE&2){
            v = geluf(v);
          }
          if(MODE&8) v += Res[(size_t)row*ldc + col];
          if constexpr(OUT==0){
            C[(size_t)row*ldc + col] = v;
          } else if constexpr(OUT==1){
            unsigned short hb = f2bf(v);
            Ch[(size_t)row*ldc + col] = hb;
            Cl[(size_t)row*ldc + col] = f2bf(v - bf2f(hb));
          } else {
            Ch[(size_t)row*ldc + col] = f2bf(v);
          }
        }
      }
    }
  } else if constexpr(OUT==2){
    const int hb = bn + wn*64;
    const float p = (float)m16;
    const float invf = __expf(-p * 0.575646273248511f);
#pragma unroll
    for(int mi=0;mi<4;mi++){
#pragma unroll
      for(int r=0;r<4;r++){
        const int row = bm + wm*64 + mi*16 + q*4 + r;
        const int s = row & (SS-1);
        float t = (float)s * invf;
        float sn, cs; __sincosf(t, &sn, &cs);
        float x1 = acc[mi][0][r], x2 = acc[mi][1][r];
        float v0 = (x1*cs - x2*sn)*0.125f;
        float v1 = (x2*cs + x1*sn)*0.125f;
        float v2 = acc[mi][2][r]*0.125f;
        float v3 = acc[mi][3][r]*0.125f;
        size_t base = (size_t)row*ldc + hb;
        unsigned short hh;
        hh=f2bf(v0); Ch[base+m16]=hh;    Cl[base+m16]   =f2bf(v0-bf2f(hh));
        hh=f2bf(v1); Ch[base+16+m16]=hh; Cl[base+16+m16]=f2bf(v1-bf2f(hh));
        hh=f2bf(v2); Ch[base+32+m16]=hh; Cl[base+32+m16]=f2bf(v2-bf2f(hh));
        hh=f2bf(v3); Ch[base+48+m16]=hh; Cl[base+48+m16]=f2bf(v3-bf2f(hh));
      }
    }
  } else if constexpr(OUT==3){
    const float p = (float)m16;
    const float invf = __expf(-p * 0.575646273248511f);
#pragma unroll
    for(int mi=0;mi<4;mi++){
#pragma unroll
      for(int r=0;r<4;r++){
        const int row = bm + wm*64 + mi*16 + q*4 + r;
        const int s = row & (SS-1);
        float v0, v1;
        if(wn==0){
          float t = (float)s * invf;
          float sn, cs; __sincosf(t, &sn, &cs);
          float x1 = acc[mi][0][r], x2 = acc[mi][1][r];
          v0 = x1*cs - x2*sn;
          v1 = x2*cs + x1*sn;
        } else {
          v0 = acc[mi][0][r]; v1 = acc[mi][1][r];
        }
        size_t base = (size_t)row*ldc + wn*32;
        unsigned short hh;
        hh=f2bf(v0); Ch[base+m16]=hh;    Cl[base+m16]   =f2bf(v0-bf2f(hh));
        hh=f2bf(v1); Ch[base+16+m16]=hh; Cl[base+16+m16]=f2bf(v1-bf2f(hh));
      }
    }
  } else if constexpr(OUT==4){
#pragma unroll
    for(int ni=0;ni<NT;ni++){
      const int col = wn*32 + ni*16 + m16;
#pragma unroll
      for(int mi=0;mi<4;mi++){
        const int rowb = bm + wm*64 + mi*16 + q*4;
        const int b = rowb >> 12, sl = rowb & (SS-1);
        ushort4 hv;
        hv.x = f2bf(acc[mi][ni][0]); hv.y = f2bf(acc[mi][ni][1]);
        hv.z = f2bf(acc[mi][ni][2]); hv.w = f2bf(acc[mi][ni][3]);
        *(ushort4*)(Ch + ((size_t)(b*64 + col))*SS + sl) = hv;
      }
    }
  }
}

// fp32 GEMM for block-diagonal gate linears.
template<int BN, int MODE>
__global__ __launch_bounds__(256) void gemm_k(
    const float* __restrict__ A,
    const float* __restrict__ B0,
    const float* __restrict__ bias0,
    float* __restrict__ C,
    int M, int N, int K, int lda, int ldb, int ldc,
    int batA, int batB, int batC, int batBias)
{
  constexpr int BK = 16;
  constexpr int TN = BN/16;
  constexpr int NH = BN/64;
  __shared__ float Ask[BK][132];
  __shared__ float Bs [BK][BN+4];

  const int bz = blockIdx.z;
  const float* Ab  = A  + (size_t)bz*batA;
  const float* Bb  = B0 + (size_t)bz*batB;
  float* Cb = C + (size_t)bz*batC;

  const int bm = blockIdx.y*128, bn = blockIdx.x*BN;
  const int tid = threadIdx.x;
  const int tx = tid & 15, ty = tid >> 4;
  const int r0 = tid >> 2, c0 = (tid & 3)*4;
  const int br = tid >> 4;

  float acc[8][TN];
#pragma unroll
  for(int i=0;i<8;i++)
#pragma unroll
    for(int j=0;j<TN;j++) acc[i][j]=0.f;

  for(int k0=0;k0<K;k0+=BK){
#pragma unroll
    for(int hf=0;hf<2;hf++){
      float4 av = *(const float4*)(Ab + (size_t)(bm+r0+hf*64)*lda + (k0+c0));
      Ask[c0+0][r0+hf*64]=av.x; Ask[c0+1][r0+hf*64]=av.y;
      Ask[c0+2][r0+hf*64]=av.z; Ask[c0+3][r0+hf*64]=av.w;
    }
    {
      const int bc = (tid&15)*4;
      *(float4*)&Bs[br][bc] = *(const float4*)(Bb + (size_t)(k0+br)*ldb + (bn+bc));
    }
    __syncthreads();
#pragma unroll
    for(int k=0;k<BK;k++){
      float a[8];
      *(float4*)&a[0] = *(const float4*)&Ask[k][ty*8];
      *(float4*)&a[4] = *(const float4*)&Ask[k][ty*8+4];
      float bv[TN];
#pragma unroll
      for(int hh=0;hh<NH;hh++)
        *(float4*)&bv[hh*4] = *(const float4*)&Bs[k][hh*64 + tx*4];
#pragma unroll
      for(int i=0;i<8;i++)
#pragma unroll
        for(int j=0;j<TN;j++)
          acc[i][j] = fmaf(a[i], bv[j], acc[i][j]);
    }
    __syncthreads();
  }

#pragma unroll
  for(int i=0;i<8;i++){
    const int row = bm + ty*8 + i;
#pragma unroll
    for(int hh=0;hh<NH;hh++){
      const int col = bn + hh*64 + tx*4;
      float v0=acc[i][hh*4+0], v1=acc[i][hh*4+1], v2=acc[i][hh*4+2], v3=acc[i][hh*4+3];
      if(MODE&1){
        float4 bbv = *(const float4*)(bias0 + (size_t)bz*batBias + col);
        v0+=bbv.x; v1+=bbv.y; v2+=bbv.z; v3+=bbv.w;
      }
      float4 ov; ov.x=v0; ov.y=v1; ov.z=v2; ov.w=v3;
      *(float4*)(Cb + (size_t)row*ldc + col) = ov;
    }
  }
}

__global__ __launch_bounds__(256) void conv_k(const float* __restrict__ x,
    const float* __restrict__ w, const float* __restrict__ b, float* __restrict__ out)
{
  int idx = blockIdx.x*256 + threadIdx.x;
  int d = idx & (DD-1);
  int r = idx >> 8;
  int s = r & (SS-1);
  float acc = b[d];
#pragma unroll
  for(int i=0;i<4;i++){
    int t = s - 3 + i;
    if(t >= 0) acc += w[i*DD + d] * x[(size_t)(r-3+i)*DD + d];
  }
  out[idx] = acc;
}

__global__ __launch_bounds__(256) void gate_k(const float* __restrict__ x,
    float* __restrict__ ig, float* __restrict__ ag, const float* __restrict__ ap)
{
  int idx = blockIdx.x*256 + threadIdx.x;
  int d = idx & (DD-1);
  int r = idx >> 8;
  int s = r & (SS-1);
  float gx = sigm(ig[idx]);
  float ga = sigm(ag[idx]);
  float a_ = ap[d];
  float sp = (a_ > 20.f) ? a_ : log1pf(expf(a_));
  float la = -8.f * ga * sp;
  float a  = expf(la);
  float mult = (s==0) ? 1.f : sqrtf(fmaxf(-expm1f(2.f*la), 0.f));
  float bt = x[idx] * gx * mult;
  ig[idx] = a;
  ag[idx] = bt;
}

__global__ __launch_bounds__(256) void scan1_k(const float* __restrict__ A,
    const float* __restrict__ Bv, float* __restrict__ csa, float* __restrict__ csb)
{
  int idx = blockIdx.x*256 + threadIdx.x;
  int d = idx & (DD-1);
  int c = (idx >> 8) & (NCH-1);
  int b = idx >> 14;
  size_t base = ((size_t)b*SS + (size_t)c*CH)*DD + d;
  float Aa = 1.f, Bb_ = 0.f;
  for(int t=0;t<CH;t++){
    float a  = A [base + (size_t)t*DD];
    float bb = Bv[base + (size_t)t*DD];
    Aa  = a*Aa;
    Bb_ = a*Bb_ + bb;
  }
  csa[idx] = Aa; csb[idx] = Bb_;
}

__global__ __launch_bounds__(256) void scan2_k(const float* __restrict__ csa,
    float* __restrict__ csb)
{
  int idx = blockIdx.x*256 + threadIdx.x;
  int d = idx & (DD-1);
  int b = idx >> 8;
  float h = 0.f;
  for(int c=0;c<NCH;c++){
    size_t i = ((size_t)b*NCH + c)*DD + d;
    float Aa = csa[i], Bb_ = csb[i];
    csb[i] = h;
    h = Aa*h + Bb_;
  }
}

__global__ __launch_bounds__(256) void scan3_k(const float* __restrict__ A,
    const float* __restrict__ Bv, const float* __restrict__ csb,
    const unsigned short* __restrict__ Yh,
    unsigned short* __restrict__ Hh, unsigned short* __restrict__ Hl)
{
  int idx = blockIdx.x*256 + threadIdx.x;
  int d = idx & (DD-1);
  int c = (idx >> 8) & (NCH-1);
  int b = idx >> 14;
  size_t base = ((size_t)b*SS + (size_t)c*CH)*DD + d;
  float h = csb[idx];
  for(int t=0;t<CH;t++){
    float a  = A [base + (size_t)t*DD];
    float bb = Bv[base + (size_t)t*DD];
    h = a*h + bb;
    float v = h * bf2f(Yh[base + (size_t)t*DD]);
    unsigned short hb = f2bf(v);
    Hh[base + (size_t)t*DD] = hb;
    Hl[base + (size_t)t*DD] = f2bf(v - bf2f(hb));
  }
}

// ---------------------------------------------------------------------------
#define AST 72
__global__ __launch_bounds__(256) void attn_k(
    const unsigned short* __restrict__ Qh, const unsigned short* __restrict__ Ql,
    const unsigned short* __restrict__ Kh, const unsigned short* __restrict__ Kl,
    const unsigned short* __restrict__ Vt,
    unsigned short* __restrict__ Oh, unsigned short* __restrict__ Ol)
{
  __shared__ unsigned short Ksh[64*AST], Ksl[64*AST], Vsh[64*AST];
  __shared__ unsigned short Ps[4*16*AST];

  const int qt = blockIdx.x & 3, n = blockIdx.x >> 2;
  const int h = blockIdx.y, b = blockIdx.z;
  const int tid = threadIdx.x;
  const int lane = tid & 63, w = tid >> 6;
  const int m16 = lane & 15, q = lane >> 4;
  const int s0 = n*WNN + qt*64;

  const size_t qro = ((size_t)(b*SS + s0 + w*16 + m16))*DD + h*HDIM + q*8;
  bfrag qh0 = *(const bfrag*)(Qh + qro);
  bfrag qh1 = *(const bfrag*)(Qh + qro + 32);
  bfrag ql0 = *(const bfrag*)(Ql + qro);
  bfrag ql1 = *(const bfrag*)(Ql + qro + 32);

  float mrow[4], lrow[4];
  f4acc oacc[4];
#pragma unroll
  for(int i=0;i<4;i++){ mrow[i]=-3.0e38f; lrow[i]=0.f; oacc[i]=(f4acc)0.f; }

  const int ktlo = (n==0) ? 4 : qt;
  const int kthi = qt + 4;
  const int sr = tid >> 2, sc = tid & 3;

  for(int kt=ktlo; kt<=kthi; kt++){
    const int kbase = (n-1)*WNN + kt*64;
#pragma unroll
    for(int cc=0; cc<2; cc++){
      int g = sc + cc*4;
      *(float4*)&Ksh[sr*AST + g*8] =
        *(const float4*)(Kh + (size_t)(b*SS + kbase + sr)*HDIM + g*8);
      *(float4*)&Ksl[sr*AST + g*8] =
        *(const float4*)(Kl + (size_t)(b*SS + kbase + sr)*HDIM + g*8);
      *(float4*)&Vsh[sr*AST + g*8] =
        *(const float4*)(Vt + ((size_t)(b*64 + sr))*SS + kbase + g*8);
    }
    __syncthreads();

    f4acc sacc[4];
#pragma unroll
    for(int nt=0;nt<4;nt++) sacc[nt] = (f4acc)0.f;
#pragma unroll
    for(int nt=0;nt<4;nt++){
      const int kr = (nt*16+m16)*AST;
      bfrag kh0 = *(const bfrag*)&Ksh[kr + q*8];
      bfrag kh1 = *(const bfrag*)&Ksh[kr + 32 + q*8];
      bfrag kl0 = *(const bfrag*)&Ksl[kr + q*8];
      bfrag kl1 = *(const bfrag*)&Ksl[kr + 32 + q*8];
      sacc[nt] = __builtin_amdgcn_mfma_f32_16x16x32_bf16(qh0, kh0, sacc[nt],0,0,0);
      sacc[nt] = __builtin_amdgcn_mfma_f32_16x16x32_bf16(qh0, kl0, sacc[nt],0,0,0);
      sacc[nt] = __builtin_amdgcn_mfma_f32_16x16x32_bf16(ql0, kh0, sacc[nt],0,0,0);
      sacc[nt] = __builtin_amdgcn_mfma_f32_16x16x32_bf16(qh1, kh1, sacc[nt],0,0,0);
      sacc[nt] = __builtin_amdgcn_mfma_f32_16x16x32_bf16(qh1, kl1, sacc[nt],0,0,0);
      sacc[nt] = __builtin_amdgcn_mfma_f32_16x16x32_bf16(ql1, kh1, sacc[nt],0,0,0);
    }

    const bool needlo = (kt == qt+4);
    const bool needhi = (kt == qt);
#pragma unroll
    for(int r=0;r<4;r++){
      int qp = qt*64 + w*16 + q*4 + r;
      float sv[4];
      float tm = -3.0e38f;
#pragma unroll
      for(int nt=0;nt<4;nt++){
        float scv = sacc[nt][r];
        if(needlo || needhi){
          int kj = kt*64 + nt*16 + m16;
          int diff = qp + WNN - kj;
          bool ok = (!needlo || diff >= 0) && (!needhi || diff <= WNN);
          scv = ok ? scv : -3.0e38f;
        }
        sv[nt] = scv;
        tm = fmaxf(tm, scv);
      }
#pragma unroll
      for(int off=1; off<16; off<<=1) tm = fmaxf(tm, __shfl_xor(tm, off, 64));
      float mn = fmaxf(mrow[r], tm);
      float alpha = __expf(mrow[r]-mn);
      float rs = 0.f;
#pragma unroll
      for(int nt=0;nt<4;nt++){
        float pp = __expf(sv[nt]-mn);
        rs += pp;
        Ps[w*16*AST + (q*4+r)*AST + nt*16 + m16] = f2bf(pp);
      }
#pragma unroll
      for(int off=1; off<16; off<<=1) rs += __shfl_xor(rs, off, 64);
      lrow[r] = lrow[r]*alpha + rs;
      mrow[r] = mn;
#pragma unroll
      for(int nt=0;nt<4;nt++) oacc[nt][r] *= alpha;
    }

#pragma unroll
    for(int s=0;s<2;s++){
      bfrag pa = *(const bfrag*)&Ps[w*16*AST + m16*AST + s*32 + q*8];
#pragma unroll
      for(int nt=0;nt<4;nt++){
        bfrag vh_ = *(const bfrag*)&Vsh[(nt*16+m16)*AST + s*32 + q*8];
        oacc[nt] = __builtin_amdgcn_mfma_f32_16x16x32_bf16(pa, vh_, oacc[nt],0,0,0);
      }
    }
    __syncthreads();
  }

#pragma unroll
  for(int r=0;r<4;r++){
    float invl = 1.f/lrow[r];
    const size_t rowbase = ((size_t)(b*SS + s0 + w*16 + q*4 + r))*DD + h*HDIM;
#pragma unroll
    for(int nt=0;nt<4;nt++){
      float v = oacc[nt][r]*invl;
      unsigned short hb = f2bf(v);
      Oh[rowbase + nt*16 + m16] = hb;
      Ol[rowbase + nt*16 + m16] = f2bf(v - bf2f(hb));
    }
  }
}

__global__ __launch_bounds__(256) void comb_k(const float* __restrict__ of,
    const float* __restrict__ ob, const float* __restrict__ z,
    const float* __restrict__ skip, float* __restrict__ out)
{
  int idx = blockIdx.x*256 + threadIdx.x;
  int r = idx >> 8;
  out[idx] = z[r]*(of[idx]+ob[idx]) + skip[idx];
}

// ---------------------------------------------------------------------------
struct Params {
  const float *ln_gamma,*ln_beta,*proj_w,*proj_b,*fconv_w,*fconv_b,*bconv_w,*bconv_b,
    *rn0_t,*rn0_c,*ly_w,*ly_b,*lx_w,*lx_b,*lo_w,*lo_b,*c1d_w,*c1d_b,*a_param,
    *ig_w,*ig_b,*ag_w,*ag_b,*mlp0_up_w,*mlp0_up_b,*mlp0_dn_w,*mlp0_dn_b,
    *rn1_t,*rn1_c,*q_w,*k_w,*v_w,*o_w,*o_b,*mlp1_up_w,*mlp1_up_b,*mlp1_dn_w,*mlp1_dn_b;
};

struct WSplit {
  unsigned short *proj_h,*proj_l,*fconv_h,*fconv_l,*bconv_h,*bconv_l,
    *ly_h,*ly_l,*lx_h,*lx_l,*lo_h,*lo_l,*q_h,*q_l,*o_h,*o_l,
    *k_h,*k_l,*v_h,*v_l,
    *up0a_h,*up0a_l,*up0b_h,*up0b_l,*up1a_h,*up1a_l,*up1b_h,*up1b_l,
    *dn0_h,*dn0_l,*dn1_h,*dn1_l;
};

#define USN ((unsigned short*)nullptr)

extern "C" void kernel_launch(void* const* d_in, const int* in_sizes, int n_in,
                              void* d_out, int out_size, void* d_ws, size_t ws_size,
                              hipStream_t stream)
{
  (void)in_sizes; (void)n_in; (void)out_size; (void)ws_size;
  const float* skip = (const float*)d_in[0];
  Params p;
  p.ln_gamma  =(const float*)d_in[1];  p.ln_beta  =(const float*)d_in[2];
  p.proj_w    =(const float*)d_in[3];  p.proj_b   =(const float*)d_in[4];
  p.fconv_w   =(const float*)d_in[5];  p.fconv_b  =(const float*)d_in[6];
  p.bconv_w   =(const float*)d_in[7];  p.bconv_b  =(const float*)d_in[8];
  p.rn0_t     =(const float*)d_in[9];  p.rn0_c    =(const float*)d_in[10];
  p.ly_w      =(const float*)d_in[11]; p.ly_b     =(const float*)d_in[12];
  p.lx_w      =(const float*)d_in[13]; p.lx_b     =(const float*)d_in[14];
  p.lo_w      =(const float*)d_in[15]; p.lo_b     =(const float*)d_in[16];
  p.c1d_w     =(const float*)d_in[17]; p.c1d_b    =(const float*)d_in[18];
  p.a_param   =(const float*)d_in[19];
  p.ig_w      =(const float*)d_in[20]; p.ig_b     =(const float*)d_in[21];
  p.ag_w      =(const float*)d_in[22]; p.ag_b     =(const float*)d_in[23];
  p.mlp0_up_w =(const float*)d_in[24]; p.mlp0_up_b=(const float*)d_in[25];
  p.mlp0_dn_w =(const float*)d_in[26]; p.mlp0_dn_b=(const float*)d_in[27];
  p.rn1_t     =(const float*)d_in[28]; p.rn1_c    =(const float*)d_in[29];
  p.q_w       =(const float*)d_in[30]; p.k_w      =(const float*)d_in[31];
  p.v_w       =(const float*)d_in[32]; p.o_w      =(const float*)d_in[33];
  p.o_b       =(const float*)d_in[34];
  p.mlp1_up_w =(const float*)d_in[35]; p.mlp1_up_b=(const float*)d_in[36];
  p.mlp1_dn_w =(const float*)d_in[37]; p.mlp1_dn_b=(const float*)d_in[38];

  float* ws = (float*)d_ws;
  const size_t RD  = (size_t)RR*DD;
  const size_t PD2 = (size_t)RR2*DD;
  size_t off = 0;
  float* Z   = ws + off; off += 16384;
  float* XB2 = ws + off; off += 2*RD;
  float* CV2 = ws + off; off += 2*RD;
  float* W1  = ws + off; off += 2*RD;
  float* W2  = ws + off; off += 2*RD;
  float* W3  = ws + off; off += RD;
  float* W4  = ws + off; off += 2*RD;

  float* CSA = CV2;
  float* CSB = CV2 + 8*NCH*DD;

  unsigned short* NPh = (unsigned short*)W4;  unsigned short* NPl = NPh + PD2;
  unsigned short* HYh = NPh;                  unsigned short* HYl = NPl;
  unsigned short* X0h = (unsigned short*)W1;  unsigned short* X0l = X0h + (size_t)RR*DD;
  float* XR2 = W1;
  unsigned short* Qph = (unsigned short*)W1;  unsigned short* Qpl = Qph + PD2;
  float* Abuf = W2;
  unsigned short* P2h = (unsigned short*)W2;  unsigned short* P2l = P2h + PD2;
  unsigned short* Yh  = (unsigned short*)W3;
  unsigned short* KPh = (unsigned short*)W3;  unsigned short* KPl = KPh + (size_t)RR2*HDIM;
  unsigned short* Vt  = KPl + (size_t)RR2*HDIM;
  unsigned short* ACTh = (unsigned short*)W1;
  float* OUT2 = XB2;

  unsigned short* sp = (unsigned short*)(ws + off);
  WSplit w;
  auto alloc_s = [&](size_t n){ unsigned short* r = sp; sp += n; return r; };
  const size_t SDD = (size_t)DD*DD, SKV = (size_t)DD*HDIM, SUP = (size_t)DD*EE;
  w.proj_h=alloc_s(SDD);  w.proj_l=alloc_s(SDD);
  w.fconv_h=alloc_s(SDD); w.fconv_l=alloc_s(SDD);
  w.bconv_h=alloc_s(SDD); w.bconv_l=alloc_s(SDD);
  w.ly_h=alloc_s(SDD);    w.ly_l=alloc_s(SDD);
  w.lx_h=alloc_s(SDD);    w.lx_l=alloc_s(SDD);
  w.lo_h=alloc_s(SDD);    w.lo_l=alloc_s(SDD);
  w.q_h=alloc_s(SDD);     w.q_l=alloc_s(SDD);
  w.o_h=alloc_s(SDD);     w.o_l=alloc_s(SDD);
  w.k_h=alloc_s(SKV);     w.k_l=alloc_s(SKV);
  w.v_h=alloc_s(SKV);     w.v_l=alloc_s(SKV);
  w.up0a_h=alloc_s(SUP);  w.up0a_l=alloc_s(SUP);
  w.up0b_h=alloc_s(SUP);  w.up0b_l=alloc_s(SUP);
  w.up1a_h=alloc_s(SUP);  w.up1a_l=alloc_s(SUP);
  w.up1b_h=alloc_s(SUP);  w.up1b_l=alloc_s(SUP);
  w.dn0_h=alloc_s(SUP);   w.dn0_l=alloc_s(SUP);
  w.dn1_h=alloc_s(SUP);   w.dn1_l=alloc_s(SUP);

  dim3 blk(256);
  dim3 g2(2,128,1);
  dim3 g2m(2,256,1), g64m(1,256,1), gbd(1,256,4), gdual(12,256,1);

  {
    TS8 ga;
    ga.t[0] = {p.proj_w,  w.proj_h,  w.proj_l,  DD, DD};
    ga.t[1] = {p.fconv_w, w.fconv_h, w.fconv_l, DD, DD};
    ga.t[2] = {p.bconv_w, w.bconv_h, w.bconv_l, DD, DD};
    ga.t[3] = {p.ly_w,    w.ly_h,    w.ly_l,    DD, DD};
    ga.t[4] = {p.lx_w,    w.lx_h,    w.lx_l,    DD, DD};
    ga.t[5] = {p.lo_w,    w.lo_h,    w.lo_l,    DD, DD};
    ga.t[6] = {p.q_w,     w.q_h,     w.q_l,     DD, DD};
    ga.t[7] = {p.o_w,     w.o_h,     w.o_l,     DD, DD};
    tsplit8_k<<<dim3(DD*DD/256, 8), blk, 0, stream>>>(ga);
    TS8 gb;
    gb.t[0] = {p.k_w,              w.k_h,    w.k_l,    DD, HDIM};
    gb.t[1] = {p.v_w,              w.v_h,    w.v_l,    DD, HDIM};
    gb.t[2] = {p.mlp0_up_w,        w.up0a_h, w.up0a_l, DD, EE};
    gb.t[3] = {p.mlp0_up_w+(size_t)DD*EE, w.up0b_h, w.up0b_l, DD, EE};
    gb.t[4] = {p.mlp1_up_w,        w.up1a_h, w.up1a_l, DD, EE};
    gb.t[5] = {p.mlp1_up_w+(size_t)DD*EE, w.up1b_h, w.up1b_l, DD, EE};
    gb.t[6] = {p.mlp0_dn_w,        w.dn0_h,  w.dn0_l,  EE, DD};
    gb.t[7] = {p.mlp1_dn_w,        w.dn1_h,  w.dn1_l,  EE, DD};
    tsplit8_k<<<dim3(DD*EE/256, 8), blk, 0, stream>>>(gb);
  }

  // ---- prologue ----
  ln_z_k<<<RR/4, blk, 0, stream>>>(skip, p.ln_gamma, p.ln_beta, NPh, NPl, Z);
  gemm_mfma<128,1,0,1,3><<<g2,blk,0,stream>>>(NPh,NPl, w.proj_h,w.proj_l, USN,USN,
      p.proj_b,nullptr,nullptr, nullptr, X0h, X0l, DD,DD,DD);
  gemm_mfma<128,1,0,0,3><<<g2,blk,0,stream>>>(X0h,X0l, w.fconv_h,w.fconv_l, USN,USN,
      p.fconv_b,nullptr,nullptr, XB2, USN,USN, DD,DD,DD);
  gemm_mfma<128,1,0,0,3><<<g2,blk,0,stream>>>(X0h,X0l, w.bconv_h,w.bconv_l, USN,USN,
      p.bconv_b,nullptr,nullptr, XB2 + RD, USN,USN, DD,DD,DD);

  // ---- residual block 0: recurrent (merged, M=32768) ----
  rms_k<<<RR2/4, blk, 0, stream>>>(XB2, p.rn0_t, NPh, NPl);
  gemm_mfma<128,3,0,5,2><<<g2m,blk,0,stream>>>(NPh,USN, w.ly_h,w.ly_l, USN,USN,
      p.ly_b,nullptr,nullptr, nullptr, Yh, USN, DD,DD,DD);
  gemm_mfma<128,1,0,0,2><<<g2m,blk,0,stream>>>(NPh,USN, w.lx_h,w.lx_l, USN,USN,
      p.lx_b,nullptr,nullptr, XR2, USN,USN, DD,DD,DD);
  conv_k<<<(size_t)RR2*DD/256, blk, 0, stream>>>(XR2, p.c1d_w, p.c1d_b, CV2);
  gemm_k<64,1><<<gbd,blk,0,stream>>>(CV2,p.ig_w,p.ig_b,Abuf,
      RR2,HDIM,HDIM, DD,HDIM,DD, HDIM, HDIM*HDIM, HDIM, HDIM);
  gemm_k<64,1><<<gbd,blk,0,stream>>>(CV2,p.ag_w,p.ag_b,XR2,
      RR2,HDIM,HDIM, DD,HDIM,DD, HDIM, HDIM*HDIM, HDIM, HDIM);
  gate_k<<<(size_t)RR2*DD/256, blk, 0, stream>>>(CV2, Abuf, XR2, p.a_param);
  scan1_k<<<8*NCH*DD/256, blk,0,stream>>>(Abuf, XR2, CSA, CSB);
  scan2_k<<<8*DD/256, blk,0,stream>>>(CSA, CSB);
  scan3_k<<<8*NCH*DD/256, blk,0,stream>>>(Abuf, XR2, CSB, Yh, HYh, HYl);
  gemm_mfma<128,9,0,0,2><<<g2m,blk,0,stream>>>(HYh,USN, w.lo_h,w.lo_l, USN,USN,
      p.lo_b,nullptr, XB2, CV2, USN,USN, DD,DD,DD);
  rms_k<<<RR2/4,blk,0,stream>>>(CV2, p.rn0_c, NPh, NPl);
  gemm_mfma<64,1,1,5,1><<<gdual,blk,0,stream>>>(NPh,USN, w.up0a_h,USN,
      w.up0b_h,USN, p.mlp0_up_b, p.mlp0_up_b+EE, nullptr, nullptr,
      ACTh, USN, DD,DD,EE);
  gemm_mfma<128,9,0,0,2><<<g2m,blk,0,stream>>>(ACTh,USN, w.dn0_h,w.dn0_l, USN,USN,
      p.mlp0_dn_b,nullptr, CV2, XB2, USN,USN, EE,EE,DD);

  // ---- residual block 1: local attention (merged) ----
  rms_k<<<RR2/4,blk,0,stream>>>(XB2, p.rn1_t, NPh, NPl);
  gemm_mfma<128,0,0,2,2><<<g2m,blk,0,stream>>>(NPh,USN, w.q_h,w.q_l, USN,USN,
      nullptr,nullptr,nullptr, nullptr, Qph, Qpl, DD,DD,DD);
  gemm_mfma<64,0,0,3,3><<<g64m,blk,0,stream>>>(NPh,NPl, w.k_h,w.k_l, USN,USN,
      nullptr,nullptr,nullptr, nullptr, KPh, KPl, DD,DD,HDIM);
  gemm_mfma<64,0,0,4,3><<<g64m,blk,0,stream>>>(NPh,NPl, w.v_h,w.v_l, USN,USN,
      nullptr,nullptr,nullptr, nullptr, Vt, USN, DD,DD,HDIM);
  attn_k<<<dim3(64,4,8),blk,0,stream>>>(Qph, Qpl, KPh, KPl, Vt, P2h, P2l);
  gemm_mfma<128,9,0,0,2><<<g2m,blk,0,stream>>>(P2h,USN, w.o_h,w.o_l, USN,USN,
      p.o_b,nullptr, XB2, CV2, USN,USN, DD,DD,DD);
  rms_k<<<RR2/4,blk,0,stream>>>(CV2, p.rn1_c, NPh, NPl);
  gemm_mfma<64,1,1,5,1><<<gdual,blk,0,stream>>>(NPh,USN, w.up1a_h,USN,
      w.up1b_h,USN, p.mlp1_up_b, p.mlp1_up_b+EE, nullptr, nullptr,
      ACTh, USN, DD,DD,EE);
  gemm_mfma<128,9,0,0,2><<<g2m,blk,0,stream>>>(ACTh,USN, w.dn1_h,w.dn1_l, USN,USN,
      p.mlp1_dn_b,nullptr, CV2, OUT2, USN,USN, EE,EE,DD);

  // ---- combine ----
  comb_k<<<RR*DD/256, blk, 0, stream>>>(OUT2, OUT2 + RD, Z, skip, (float*)d_out);
}